// Round 1
// baseline (764.457 us; speedup 1.0000x reference)
//
#include <hip/hip_runtime.h>
#include <hip/hip_bf16.h>

// ---------------------------------------------------------------------------
// GCN forward: 3x GCNConv(relu) + linear head.
// out[n] = dinv[n]*( sum_{(s,n) in E} xws[s] + xws[n] ) + b,  xws = dinv .* (H @ W)
// CSR (dst-bucketed src list) rebuilt each call (deterministic inputs).
// ---------------------------------------------------------------------------

static __global__ __launch_bounds__(256) void count_kernel(
    const int* __restrict__ dst, int* __restrict__ counts, int E) {
  int i = blockIdx.x * 256 + threadIdx.x;
  if (i < E) atomicAdd(&counts[dst[i]], 1);
}

// Block scans 1024 counts (256 thr x 4). local exclusive scan -> row_ptr, block sum -> partials.
static __global__ __launch_bounds__(256) void scan1_kernel(
    const int* __restrict__ counts, int* __restrict__ row_ptr,
    int* __restrict__ partials, int n) {
  __shared__ int sdata[256];
  int t = threadIdx.x;
  int base = blockIdx.x * 1024 + t * 4;
  int v[4];
#pragma unroll
  for (int j = 0; j < 4; ++j) v[j] = (base + j < n) ? counts[base + j] : 0;
  int s = v[0] + v[1] + v[2] + v[3];
  sdata[t] = s;
  __syncthreads();
  int incl = s;
  for (int off = 1; off < 256; off <<= 1) {
    int y = (t >= off) ? sdata[t - off] : 0;
    __syncthreads();
    incl += y;
    sdata[t] = incl;
    __syncthreads();
  }
  int run = incl - s;  // exclusive prefix for this thread's 4 elems
#pragma unroll
  for (int j = 0; j < 4; ++j) {
    if (base + j < n) row_ptr[base + j] = run;
    run += v[j];
  }
  if (t == 255) partials[blockIdx.x] = incl;
}

static __global__ void scan2_kernel(int* __restrict__ partials, int nb) {
  if (blockIdx.x == 0 && threadIdx.x == 0) {
    int acc = 0;
    for (int i = 0; i < nb; ++i) { int v = partials[i]; partials[i] = acc; acc += v; }
  }
}

static __global__ __launch_bounds__(256) void finalize_kernel(
    int* __restrict__ row_ptr, const int* __restrict__ partials,
    const int* __restrict__ counts, int* __restrict__ cursor,
    float* __restrict__ dinv, int n, int E) {
  int i = blockIdx.x * 256 + threadIdx.x;
  if (i < n) {
    int rp = row_ptr[i] + partials[i >> 10];
    row_ptr[i] = rp;
    cursor[i] = rp;
    dinv[i] = rsqrtf((float)(counts[i] + 1));  // +1 self loop
    if (i == 0) row_ptr[n] = E;
  }
}

static __global__ __launch_bounds__(256) void fill_kernel(
    const int* __restrict__ src, const int* __restrict__ dst,
    int* __restrict__ cursor, int* __restrict__ csr_src, int E) {
  int i = blockIdx.x * 256 + threadIdx.x;
  if (i < E) {
    int d = dst[i];
    int pos = atomicAdd(&cursor[d], 1);
    csr_src[pos] = src[i];
  }
}

// xws = dinv .* (H @ W).  PER_NODE = FOUT/4 threads per node, 4 outputs each.
template <int FIN, int FOUT>
static __global__ __launch_bounds__(256) void gemm_scale_kernel(
    const float* __restrict__ H, const float* __restrict__ W,
    const float* __restrict__ dinv, float* __restrict__ out, int n) {
  constexpr int PER_NODE = FOUT / 4;
  constexpr int NODES = 256 / PER_NODE;
  __shared__ float ws[FIN * FOUT];
  __shared__ float hrow[NODES][FIN + 1];
  int t = threadIdx.x;
  for (int i = t; i < FIN * FOUT; i += 256) ws[i] = W[i];
  int nodeBase = blockIdx.x * NODES;
  for (int i = t; i < NODES * FIN; i += 256) {
    int nl = i / FIN, k = i - nl * FIN;
    int node = nodeBase + nl;
    hrow[nl][k] = (node < n) ? H[node * FIN + k] : 0.f;
  }
  __syncthreads();
  int nl = t / PER_NODE;
  int c = t - nl * PER_NODE;
  float4 acc = {0.f, 0.f, 0.f, 0.f};
#pragma unroll 4
  for (int k = 0; k < FIN; ++k) {
    float hv = hrow[nl][k];
    const float4 w4 = *(const float4*)&ws[k * FOUT + c * 4];
    acc.x += hv * w4.x; acc.y += hv * w4.y; acc.z += hv * w4.z; acc.w += hv * w4.w;
  }
  int node = nodeBase + nl;
  if (node < n) {
    float dv = dinv[node];
    float4 r = {dv * acc.x, dv * acc.y, dv * acc.z, dv * acc.w};
    *(float4*)&out[node * FOUT + c * 4] = r;
  }
}

// h[n] = relu(dinv[n]*(sum_{e in(n)} xws[src_e] + xws[n]) + b).
// FINAL: additionally out[n] = h[n] . w_out + b_out (16->1), no relu on head.
template <int F, bool FINAL>
static __global__ __launch_bounds__(256) void agg_kernel(
    const float* __restrict__ xws, const int* __restrict__ row_ptr,
    const int* __restrict__ csr_src, const float* __restrict__ dinv,
    const float* __restrict__ bias, float* __restrict__ out,
    const float* __restrict__ w_out, const float* __restrict__ b_out, int n) {
  constexpr int G = F / 4;           // threads per node
  constexpr int NODES = 256 / G;
  int t = threadIdx.x;
  int nl = t / G;
  int c = t - nl * G;
  int node = blockIdx.x * NODES + nl;
  if (node >= n) return;
  int start = row_ptr[node], end = row_ptr[node + 1];
  float4 acc = {0.f, 0.f, 0.f, 0.f};
  for (int e = start; e < end; ++e) {
    int s = csr_src[e];  // same addr across G lanes -> broadcast
    float4 v = *(const float4*)&xws[s * F + c * 4];
    acc.x += v.x; acc.y += v.y; acc.z += v.z; acc.w += v.w;
  }
  float4 self4 = *(const float4*)&xws[node * F + c * 4];
  float dv = dinv[node];
  float4 r;
  r.x = fmaxf(dv * (acc.x + self4.x) + bias[c * 4 + 0], 0.f);
  r.y = fmaxf(dv * (acc.y + self4.y) + bias[c * 4 + 1], 0.f);
  r.z = fmaxf(dv * (acc.z + self4.z) + bias[c * 4 + 2], 0.f);
  r.w = fmaxf(dv * (acc.w + self4.w) + bias[c * 4 + 3], 0.f);
  if (!FINAL) {
    *(float4*)&out[node * F + c * 4] = r;
  } else {
    float p = r.x * w_out[c * 4 + 0] + r.y * w_out[c * 4 + 1] +
              r.z * w_out[c * 4 + 2] + r.w * w_out[c * 4 + 3];
    p += __shfl_xor(p, 1);
    p += __shfl_xor(p, 2);
    if (c == 0) out[node] = p + b_out[0];
  }
}

extern "C" void kernel_launch(void* const* d_in, const int* in_sizes, int n_in,
                              void* d_out, int out_size, void* d_ws, size_t ws_size,
                              hipStream_t stream) {
  const float* x     = (const float*)d_in[0];
  const int*   ei    = (const int*)d_in[1];
  const float* w1    = (const float*)d_in[2];
  const float* b1    = (const float*)d_in[3];
  const float* w2    = (const float*)d_in[4];
  const float* b2    = (const float*)d_in[5];
  const float* w3    = (const float*)d_in[6];
  const float* b3    = (const float*)d_in[7];
  const float* w_out = (const float*)d_in[8];
  const float* b_out = (const float*)d_in[9];
  float* out = (float*)d_out;

  const int n = in_sizes[0] / 128;   // 100000
  const int E = in_sizes[1] / 2;     // 3200000
  const int* srcA = ei;
  const int* dstA = ei + E;

  // workspace carve (256B aligned)
  char* p = (char*)d_ws;
  auto carve = [&](size_t bytes) {
    void* r = (void*)p;
    p += (bytes + 255) & ~(size_t)255;
    return r;
  };
  int*   counts   = (int*)carve((size_t)n * 4);
  int*   row_ptr  = (int*)carve((size_t)(n + 1) * 4);
  int*   cursor   = (int*)carve((size_t)n * 4);
  float* dinv     = (float*)carve((size_t)n * 4);
  int*   partials = (int*)carve(1024 * 4);
  int*   csr_src  = (int*)carve((size_t)E * 4);
  float* bufA     = (float*)carve((size_t)n * 64 * 4);  // xws
  float* bufB     = (float*)carve((size_t)n * 64 * 4);  // h

  const int NB = (n + 1023) / 1024;

  hipMemsetAsync(counts, 0, (size_t)n * 4, stream);
  count_kernel<<<(E + 255) / 256, 256, 0, stream>>>(dstA, counts, E);
  scan1_kernel<<<NB, 256, 0, stream>>>(counts, row_ptr, partials, n);
  scan2_kernel<<<1, 64, 0, stream>>>(partials, NB);
  finalize_kernel<<<(n + 255) / 256, 256, 0, stream>>>(row_ptr, partials, counts,
                                                       cursor, dinv, n, E);
  fill_kernel<<<(E + 255) / 256, 256, 0, stream>>>(srcA, dstA, cursor, csr_src, E);

  // layer 1: 128 -> 64
  gemm_scale_kernel<128, 64><<<(n + 15) / 16, 256, 0, stream>>>(x, w1, dinv, bufA, n);
  agg_kernel<64, false><<<(n + 15) / 16, 256, 0, stream>>>(
      bufA, row_ptr, csr_src, dinv, b1, bufB, nullptr, nullptr, n);
  // layer 2: 64 -> 32
  gemm_scale_kernel<64, 32><<<(n + 31) / 32, 256, 0, stream>>>(bufB, w2, dinv, bufA, n);
  agg_kernel<32, false><<<(n + 31) / 32, 256, 0, stream>>>(
      bufA, row_ptr, csr_src, dinv, b2, bufB, nullptr, nullptr, n);
  // layer 3: 32 -> 16, fused 16->1 head
  gemm_scale_kernel<32, 16><<<(n + 63) / 64, 256, 0, stream>>>(bufB, w3, dinv, bufA, n);
  agg_kernel<16, true><<<(n + 63) / 64, 256, 0, stream>>>(
      bufA, row_ptr, csr_src, dinv, b3, out, w_out, b_out, n);
}

// Round 2
// 423.257 us; speedup vs baseline: 1.8061x; 1.8061x over previous
//
#include <hip/hip_runtime.h>
#include <hip/hip_bf16.h>

// ---------------------------------------------------------------------------
// GCN forward: 3x GCNConv(relu) + linear head.
// out[n] = dinv[n]*( sum_{(s,n) in E} xws[s] + xws[n] ) + b,  xws = dinv .* (H @ W)
// CSR build = bucketed partition (196 buckets x 512 dst nodes) to avoid the
// 16x write amplification of a fully-scattered atomic fill (R1: 194MB writes
// for a 12.8MB array, 290us).
// ---------------------------------------------------------------------------

#define NBUCK 196    // ceil(100000 / 512)
#define BSHIFT 9     // 512 nodes per bucket
#define CAP 18432    // per-bucket edge capacity; mean 16384, +16 sigma

// Partition edges into dst-buckets, packed as ((dst&511)<<17)|src (src<2^17).
// Block = 256 thr x 32 edges. LDS histogram -> 1 global atomic per bucket per
// block -> writes land in ~42-entry contiguous runs.
static __global__ __launch_bounds__(256) void partition_kernel(
    const int* __restrict__ src, const int* __restrict__ dst,
    int* __restrict__ bucket_cnt, int* __restrict__ part, int E) {
  __shared__ int hist[NBUCK];
  __shared__ int bbase[NBUCK];
  __shared__ int cur[NBUCK];
  const int t = threadIdx.x;
  for (int j = t; j < NBUCK; j += 256) { hist[j] = 0; cur[j] = 0; }
  __syncthreads();
  const int base = blockIdx.x * 8192;
  for (int k = 0; k < 32; ++k) {
    int i = base + k * 256 + t;
    if (i < E) atomicAdd(&hist[dst[i] >> BSHIFT], 1);
  }
  __syncthreads();
  for (int j = t; j < NBUCK; j += 256) {
    int h = hist[j];
    bbase[j] = h ? atomicAdd(&bucket_cnt[j], h) : 0;
  }
  __syncthreads();
  for (int k = 0; k < 32; ++k) {
    int i = base + k * 256 + t;
    if (i < E) {
      int d = dst[i];
      int b = d >> BSHIFT;
      int r = bbase[b] + atomicAdd(&cur[b], 1);
      if (r < CAP) part[b * CAP + r] = ((d & 511) << 17) | src[i];
    }
  }
}

// One block per bucket: local 512-histogram -> scan -> row_start/row_end/dinv
// (coalesced), then counting-sort scatter of src into csr_src. Scatter target
// is an 80KB window -> L2 absorbs, lines fully populated.
static __global__ __launch_bounds__(256) void bucket2csr_kernel(
    const int* __restrict__ bucket_cnt, const int* __restrict__ part,
    int* __restrict__ csr_src, int* __restrict__ row_start,
    int* __restrict__ row_end, float* __restrict__ dinv, int n) {
  __shared__ int hist[512];
  __shared__ int cursor[512];
  __shared__ int sdata[256];
  const int b = blockIdx.x;
  const int t = threadIdx.x;
  const int base = b * CAP;
  int cnt = bucket_cnt[b];
  if (cnt > CAP) cnt = CAP;
  hist[t] = 0;
  hist[t + 256] = 0;
  __syncthreads();
  for (int i = t; i < cnt; i += 256)
    atomicAdd(&hist[part[base + i] >> 17], 1);
  __syncthreads();
  int v0 = hist[2 * t], v1 = hist[2 * t + 1];
  int s = v0 + v1;
  sdata[t] = s;
  __syncthreads();
  int incl = s;
  for (int off = 1; off < 256; off <<= 1) {
    int y = (t >= off) ? sdata[t - off] : 0;
    __syncthreads();
    incl += y;
    sdata[t] = incl;
    __syncthreads();
  }
  int excl = incl - s;  // exclusive prefix over pairs
  cursor[2 * t] = excl;
  cursor[2 * t + 1] = excl + v0;
  int node0 = b * 512 + 2 * t;
  if (node0 < n) {
    row_start[node0] = base + excl;
    row_end[node0] = base + excl + v0;
    dinv[node0] = rsqrtf((float)(v0 + 1));  // +1 self loop
  }
  if (node0 + 1 < n) {
    row_start[node0 + 1] = base + excl + v0;
    row_end[node0 + 1] = base + excl + v0 + v1;
    dinv[node0 + 1] = rsqrtf((float)(v1 + 1));
  }
  __syncthreads();
  for (int i = t; i < cnt; i += 256) {
    int p = part[base + i];
    int pos = atomicAdd(&cursor[p >> 17], 1);
    csr_src[base + pos] = p & 0x1FFFF;
  }
}

// xws = dinv .* (H @ W).  PER_NODE = FOUT/4 threads per node, 4 outputs each.
template <int FIN, int FOUT>
static __global__ __launch_bounds__(256) void gemm_scale_kernel(
    const float* __restrict__ H, const float* __restrict__ W,
    const float* __restrict__ dinv, float* __restrict__ out, int n) {
  constexpr int PER_NODE = FOUT / 4;
  constexpr int NODES = 256 / PER_NODE;
  __shared__ float ws[FIN * FOUT];
  __shared__ float hrow[NODES][FIN + 1];
  int t = threadIdx.x;
  for (int i = t; i < FIN * FOUT; i += 256) ws[i] = W[i];
  int nodeBase = blockIdx.x * NODES;
  for (int i = t; i < NODES * FIN; i += 256) {
    int nl = i / FIN, k = i - nl * FIN;
    int node = nodeBase + nl;
    hrow[nl][k] = (node < n) ? H[node * FIN + k] : 0.f;
  }
  __syncthreads();
  int nl = t / PER_NODE;
  int c = t - nl * PER_NODE;
  float4 acc = {0.f, 0.f, 0.f, 0.f};
#pragma unroll 4
  for (int k = 0; k < FIN; ++k) {
    float hv = hrow[nl][k];
    const float4 w4 = *(const float4*)&ws[k * FOUT + c * 4];
    acc.x += hv * w4.x; acc.y += hv * w4.y; acc.z += hv * w4.z; acc.w += hv * w4.w;
  }
  int node = nodeBase + nl;
  if (node < n) {
    float dv = dinv[node];
    float4 r = {dv * acc.x, dv * acc.y, dv * acc.z, dv * acc.w};
    *(float4*)&out[node * FOUT + c * 4] = r;
  }
}

// h[n] = relu(dinv[n]*(sum_{e in(n)} xws[src_e] + xws[n]) + b).
// FINAL: additionally out[n] = h[n] . w_out + b_out (16->1), no relu on head.
template <int F, bool FINAL>
static __global__ __launch_bounds__(256) void agg_kernel(
    const float* __restrict__ xws, const int* __restrict__ row_start,
    const int* __restrict__ row_end, const int* __restrict__ csr_src,
    const float* __restrict__ dinv, const float* __restrict__ bias,
    float* __restrict__ out, const float* __restrict__ w_out,
    const float* __restrict__ b_out, int n) {
  constexpr int G = F / 4;  // threads per node
  constexpr int NODES = 256 / G;
  int t = threadIdx.x;
  int nl = t / G;
  int c = t - nl * G;
  int node = blockIdx.x * NODES + nl;
  if (node >= n) return;
  int start = row_start[node], end = row_end[node];
  float4 acc = {0.f, 0.f, 0.f, 0.f};
  for (int e = start; e < end; ++e) {
    int s = csr_src[e];  // same addr across G lanes -> broadcast
    float4 v = *(const float4*)&xws[s * F + c * 4];
    acc.x += v.x; acc.y += v.y; acc.z += v.z; acc.w += v.w;
  }
  float4 self4 = *(const float4*)&xws[node * F + c * 4];
  float dv = dinv[node];
  float4 r;
  r.x = fmaxf(dv * (acc.x + self4.x) + bias[c * 4 + 0], 0.f);
  r.y = fmaxf(dv * (acc.y + self4.y) + bias[c * 4 + 1], 0.f);
  r.z = fmaxf(dv * (acc.z + self4.z) + bias[c * 4 + 2], 0.f);
  r.w = fmaxf(dv * (acc.w + self4.w) + bias[c * 4 + 3], 0.f);
  if (!FINAL) {
    *(float4*)&out[node * F + c * 4] = r;
  } else {
    float p = r.x * w_out[c * 4 + 0] + r.y * w_out[c * 4 + 1] +
              r.z * w_out[c * 4 + 2] + r.w * w_out[c * 4 + 3];
    p += __shfl_xor(p, 1);
    p += __shfl_xor(p, 2);
    if (c == 0) out[node] = p + b_out[0];
  }
}

extern "C" void kernel_launch(void* const* d_in, const int* in_sizes, int n_in,
                              void* d_out, int out_size, void* d_ws, size_t ws_size,
                              hipStream_t stream) {
  const float* x     = (const float*)d_in[0];
  const int*   ei    = (const int*)d_in[1];
  const float* w1    = (const float*)d_in[2];
  const float* b1    = (const float*)d_in[3];
  const float* w2    = (const float*)d_in[4];
  const float* b2    = (const float*)d_in[5];
  const float* w3    = (const float*)d_in[6];
  const float* b3    = (const float*)d_in[7];
  const float* w_out = (const float*)d_in[8];
  const float* b_out = (const float*)d_in[9];
  float* out = (float*)d_out;

  const int n = in_sizes[0] / 128;   // 100000
  const int E = in_sizes[1] / 2;     // 3200000
  const int* srcA = ei;
  const int* dstA = ei + E;

  char* p = (char*)d_ws;
  auto carve = [&](size_t bytes) {
    void* r = (void*)p;
    p += (bytes + 255) & ~(size_t)255;
    return r;
  };
  const size_t partBytes = (size_t)NBUCK * CAP * 4;   // 14.45 MB
  const size_t bufBytes  = (size_t)n * 64 * 4;        // 25.6 MB
  // part aliases bufA: part is dead after bucket2csr; bufA written after.
  char* regionA  = (char*)carve(bufBytes);
  int*   part     = (int*)regionA;
  float* bufA     = (float*)regionA;
  int*   csr_src  = (int*)carve(partBytes);
  int*   bucket_cnt = (int*)carve((size_t)NBUCK * 4);
  int*   row_start  = (int*)carve((size_t)n * 4);
  int*   row_end    = (int*)carve((size_t)n * 4);
  float* dinv       = (float*)carve((size_t)n * 4);
  float* bufB       = (float*)carve(bufBytes);

  hipMemsetAsync(bucket_cnt, 0, (size_t)NBUCK * 4, stream);
  partition_kernel<<<(E + 8191) / 8192, 256, 0, stream>>>(srcA, dstA, bucket_cnt,
                                                          part, E);
  bucket2csr_kernel<<<NBUCK, 256, 0, stream>>>(bucket_cnt, part, csr_src,
                                               row_start, row_end, dinv, n);

  // layer 1: 128 -> 64
  gemm_scale_kernel<128, 64><<<(n + 15) / 16, 256, 0, stream>>>(x, w1, dinv, bufA, n);
  agg_kernel<64, false><<<(n + 15) / 16, 256, 0, stream>>>(
      bufA, row_start, row_end, csr_src, dinv, b1, bufB, nullptr, nullptr, n);
  // layer 2: 64 -> 32
  gemm_scale_kernel<64, 32><<<(n + 31) / 32, 256, 0, stream>>>(bufB, w2, dinv, bufA, n);
  agg_kernel<32, false><<<(n + 31) / 32, 256, 0, stream>>>(
      bufA, row_start, row_end, csr_src, dinv, b2, bufB, nullptr, nullptr, n);
  // layer 3: 32 -> 16, fused 16->1 head
  gemm_scale_kernel<32, 16><<<(n + 63) / 64, 256, 0, stream>>>(bufB, w3, dinv, bufA, n);
  agg_kernel<16, true><<<(n + 63) / 64, 256, 0, stream>>>(
      bufA, row_start, row_end, csr_src, dinv, b3, out, w_out, b_out, n);
}

// Round 3
// 331.747 us; speedup vs baseline: 2.3043x; 1.2758x over previous
//
#include <hip/hip_runtime.h>
#include <hip/hip_bf16.h>

// ---------------------------------------------------------------------------
// GCN forward: 3x GCNConv(relu) + linear head.
// out[n] = dinv[n]*( sum_{(s,n) in E} xws[s] + xws[n] ) + b,  xws = dinv .* (H @ W)
// R2->R3: gather tables xws stored bf16 (halves the per-edge row read that
// dominated R2: agg<64> FETCH_SIZE 365MB @ 127us). Accumulation/h/GEMM fp32.
// CSR build = bucketed partition (196 buckets x 512 dst) from R2.
// ---------------------------------------------------------------------------

#define NBUCK 196    // ceil(100000 / 512)
#define BSHIFT 9     // 512 nodes per bucket
#define CAP 18432    // per-bucket edge capacity; mean 16384, +16 sigma

typedef __attribute__((ext_vector_type(4))) unsigned short ushort4v;
typedef __attribute__((ext_vector_type(8))) unsigned short ushort8v;

__device__ __forceinline__ float bf2f(unsigned short u) {
  union { unsigned int i; float f; } v;
  v.i = ((unsigned int)u) << 16;
  return v.f;
}
__device__ __forceinline__ unsigned short f2bf(float f) {
  union { float f; unsigned int i; } v;
  v.f = f;
  unsigned int r = v.i + 0x7FFF + ((v.i >> 16) & 1);  // RNE
  return (unsigned short)(r >> 16);
}

// Partition edges into dst-buckets, packed as ((dst&511)<<17)|src (src<2^17).
static __global__ __launch_bounds__(256) void partition_kernel(
    const int* __restrict__ src, const int* __restrict__ dst,
    int* __restrict__ bucket_cnt, int* __restrict__ part, int E) {
  __shared__ int hist[NBUCK];
  __shared__ int bbase[NBUCK];
  __shared__ int cur[NBUCK];
  const int t = threadIdx.x;
  for (int j = t; j < NBUCK; j += 256) { hist[j] = 0; cur[j] = 0; }
  __syncthreads();
  const int base = blockIdx.x * 8192;
  for (int k = 0; k < 32; ++k) {
    int i = base + k * 256 + t;
    if (i < E) atomicAdd(&hist[dst[i] >> BSHIFT], 1);
  }
  __syncthreads();
  for (int j = t; j < NBUCK; j += 256) {
    int h = hist[j];
    bbase[j] = h ? atomicAdd(&bucket_cnt[j], h) : 0;
  }
  __syncthreads();
  for (int k = 0; k < 32; ++k) {
    int i = base + k * 256 + t;
    if (i < E) {
      int d = dst[i];
      int b = d >> BSHIFT;
      int r = bbase[b] + atomicAdd(&cur[b], 1);
      if (r < CAP) part[b * CAP + r] = ((d & 511) << 17) | src[i];
    }
  }
}

// One block per bucket: local 512-histogram -> scan -> row_start/row_end/dinv,
// then counting-sort scatter of src into csr_src (80KB window, L2-resident).
static __global__ __launch_bounds__(256) void bucket2csr_kernel(
    const int* __restrict__ bucket_cnt, const int* __restrict__ part,
    int* __restrict__ csr_src, int* __restrict__ row_start,
    int* __restrict__ row_end, float* __restrict__ dinv, int n) {
  __shared__ int hist[512];
  __shared__ int cursor[512];
  __shared__ int sdata[256];
  const int b = blockIdx.x;
  const int t = threadIdx.x;
  const int base = b * CAP;
  int cnt = bucket_cnt[b];
  if (cnt > CAP) cnt = CAP;
  hist[t] = 0;
  hist[t + 256] = 0;
  __syncthreads();
  for (int i = t; i < cnt; i += 256)
    atomicAdd(&hist[part[base + i] >> 17], 1);
  __syncthreads();
  int v0 = hist[2 * t], v1 = hist[2 * t + 1];
  int s = v0 + v1;
  sdata[t] = s;
  __syncthreads();
  int incl = s;
  for (int off = 1; off < 256; off <<= 1) {
    int y = (t >= off) ? sdata[t - off] : 0;
    __syncthreads();
    incl += y;
    sdata[t] = incl;
    __syncthreads();
  }
  int excl = incl - s;
  cursor[2 * t] = excl;
  cursor[2 * t + 1] = excl + v0;
  int node0 = b * 512 + 2 * t;
  if (node0 < n) {
    row_start[node0] = base + excl;
    row_end[node0] = base + excl + v0;
    dinv[node0] = rsqrtf((float)(v0 + 1));  // +1 self loop
  }
  if (node0 + 1 < n) {
    row_start[node0 + 1] = base + excl + v0;
    row_end[node0 + 1] = base + excl + v0 + v1;
    dinv[node0 + 1] = rsqrtf((float)(v1 + 1));
  }
  __syncthreads();
  for (int i = t; i < cnt; i += 256) {
    int p = part[base + i];
    int pos = atomicAdd(&cursor[p >> 17], 1);
    csr_src[base + pos] = p & 0x1FFFF;
  }
}

// xws(bf16) = dinv .* (H @ W).  H fp32. PER_NODE = FOUT/4 threads per node.
template <int FIN, int FOUT>
static __global__ __launch_bounds__(256) void gemm_scale_kernel(
    const float* __restrict__ H, const float* __restrict__ W,
    const float* __restrict__ dinv, unsigned short* __restrict__ out, int n) {
  constexpr int PER_NODE = FOUT / 4;
  constexpr int NODES = 256 / PER_NODE;
  __shared__ float ws[FIN * FOUT];
  __shared__ float hrow[NODES][FIN + 1];
  int t = threadIdx.x;
  for (int i = t; i < FIN * FOUT / 4; i += 256)
    *(float4*)&ws[i * 4] = *(const float4*)&W[i * 4];
  int nodeBase = blockIdx.x * NODES;
  for (int i = t; i < NODES * FIN / 4; i += 256) {
    int nl = (i * 4) / FIN, k = (i * 4) % FIN;
    int node = nodeBase + nl;
    float4 v = {0.f, 0.f, 0.f, 0.f};
    if (node < n) v = *(const float4*)&H[(size_t)node * FIN + k];
    *(float4*)&hrow[nl][k] = v;
  }
  __syncthreads();
  int nl = t / PER_NODE;
  int c = t - nl * PER_NODE;
  float4 acc = {0.f, 0.f, 0.f, 0.f};
#pragma unroll 4
  for (int k = 0; k < FIN; ++k) {
    float hv = hrow[nl][k];
    const float4 w4 = *(const float4*)&ws[k * FOUT + c * 4];
    acc.x += hv * w4.x; acc.y += hv * w4.y; acc.z += hv * w4.z; acc.w += hv * w4.w;
  }
  int node = nodeBase + nl;
  if (node < n) {
    float dv = dinv[node];
    ushort4v r = {f2bf(dv * acc.x), f2bf(dv * acc.y), f2bf(dv * acc.z),
                  f2bf(dv * acc.w)};
    *(ushort4v*)&out[(size_t)node * FOUT + c * 4] = r;
  }
}

// h[n](fp32) = relu(dinv[n]*(sum_{e in(n)} xws[src_e] + xws[n]) + b), xws bf16.
// FINAL: out[n] = h[n] . w_out + b_out (16->1), no relu on head, out fp32.
template <int F, bool FINAL>
static __global__ __launch_bounds__(256) void agg_kernel(
    const unsigned short* __restrict__ xws, const int* __restrict__ row_start,
    const int* __restrict__ row_end, const int* __restrict__ csr_src,
    const float* __restrict__ dinv, const float* __restrict__ bias,
    float* __restrict__ out, const float* __restrict__ w_out,
    const float* __restrict__ b_out, int n) {
  constexpr int G = F / 8;  // threads per node, 8 feats (16B bf16) each
  constexpr int NODES = 256 / G;
  int t = threadIdx.x;
  int nl = t / G;
  int c = t - nl * G;
  int node = blockIdx.x * NODES + nl;
  if (node >= n) return;
  int start = row_start[node], end = row_end[node];
  float acc[8] = {0.f, 0.f, 0.f, 0.f, 0.f, 0.f, 0.f, 0.f};
  for (int e = start; e < end; ++e) {
    int s = csr_src[e];  // broadcast across G lanes
    ushort8v v = *(const ushort8v*)&xws[(size_t)s * F + c * 8];
#pragma unroll
    for (int j = 0; j < 8; ++j) acc[j] += bf2f(v[j]);
  }
  ushort8v sv = *(const ushort8v*)&xws[(size_t)node * F + c * 8];
  float dv = dinv[node];
  float r[8];
#pragma unroll
  for (int j = 0; j < 8; ++j)
    r[j] = fmaxf(dv * (acc[j] + bf2f(sv[j])) + bias[c * 8 + j], 0.f);
  if (!FINAL) {
    float4 o0 = {r[0], r[1], r[2], r[3]};
    float4 o1 = {r[4], r[5], r[6], r[7]};
    *(float4*)&out[(size_t)node * F + c * 8] = o0;
    *(float4*)&out[(size_t)node * F + c * 8 + 4] = o1;
  } else {
    float p = 0.f;
#pragma unroll
    for (int j = 0; j < 8; ++j) p += r[j] * w_out[c * 8 + j];
    p += __shfl_xor(p, 1);  // G==2: pair lanes
    if (c == 0) out[node] = p + b_out[0];
  }
}

extern "C" void kernel_launch(void* const* d_in, const int* in_sizes, int n_in,
                              void* d_out, int out_size, void* d_ws, size_t ws_size,
                              hipStream_t stream) {
  const float* x     = (const float*)d_in[0];
  const int*   ei    = (const int*)d_in[1];
  const float* w1    = (const float*)d_in[2];
  const float* b1    = (const float*)d_in[3];
  const float* w2    = (const float*)d_in[4];
  const float* b2    = (const float*)d_in[5];
  const float* w3    = (const float*)d_in[6];
  const float* b3    = (const float*)d_in[7];
  const float* w_out = (const float*)d_in[8];
  const float* b_out = (const float*)d_in[9];
  float* out = (float*)d_out;

  const int n = in_sizes[0] / 128;   // 100000
  const int E = in_sizes[1] / 2;     // 3200000
  const int* srcA = ei;
  const int* dstA = ei + E;

  char* p = (char*)d_ws;
  auto carve = [&](size_t bytes) {
    void* r = (void*)p;
    p += (bytes + 255) & ~(size_t)255;
    return r;
  };
  const size_t partBytes = (size_t)NBUCK * CAP * 4;       // 14.45 MB
  int*   csr_src    = (int*)carve(partBytes);
  int*   bucket_cnt = (int*)carve((size_t)NBUCK * 4);
  int*   row_start  = (int*)carve((size_t)n * 4);
  int*   row_end    = (int*)carve((size_t)n * 4);
  float* dinv       = (float*)carve((size_t)n * 4);
  unsigned short* xws = (unsigned short*)carve((size_t)n * 64 * 2);  // 12.8 MB
  float* hbuf       = (float*)carve((size_t)n * 64 * 4);             // 25.6 MB
  // part aliases hbuf: part is dead after bucket2csr; hbuf written after.
  int*   part       = (int*)hbuf;

  hipMemsetAsync(bucket_cnt, 0, (size_t)NBUCK * 4, stream);
  partition_kernel<<<(E + 8191) / 8192, 256, 0, stream>>>(srcA, dstA, bucket_cnt,
                                                          part, E);
  bucket2csr_kernel<<<NBUCK, 256, 0, stream>>>(bucket_cnt, part, csr_src,
                                               row_start, row_end, dinv, n);

  // layer 1: 128 -> 64
  gemm_scale_kernel<128, 64><<<(n + 15) / 16, 256, 0, stream>>>(x, w1, dinv, xws, n);
  agg_kernel<64, false><<<(n + 31) / 32, 256, 0, stream>>>(
      xws, row_start, row_end, csr_src, dinv, b1, hbuf, nullptr, nullptr, n);
  // layer 2: 64 -> 32
  gemm_scale_kernel<64, 32><<<(n + 31) / 32, 256, 0, stream>>>(hbuf, w2, dinv, xws, n);
  agg_kernel<32, false><<<(n + 63) / 64, 256, 0, stream>>>(
      xws, row_start, row_end, csr_src, dinv, b2, hbuf, nullptr, nullptr, n);
  // layer 3: 32 -> 16, fused 16->1 head
  gemm_scale_kernel<32, 16><<<(n + 63) / 64, 256, 0, stream>>>(hbuf, w3, dinv, xws, n);
  agg_kernel<16, true><<<(n + 127) / 128, 256, 0, stream>>>(
      xws, row_start, row_end, csr_src, dinv, b3, out, w_out, b_out, n);
}

// Round 4
// 266.904 us; speedup vs baseline: 2.8642x; 1.2429x over previous
//
#include <hip/hip_runtime.h>
#include <hip/hip_bf16.h>

// ---------------------------------------------------------------------------
// GCN forward: 3x GCNConv(relu) + linear head.
// out[n] = dinv[n]*( sum_{(s,n) in E} xws[s] + xws[n] ) + b,  xws = dinv .* (H @ W)
// R3->R4: (a) gather loop unrolled x8 for memory ILP (R3: agg<64> 73us,
// FETCH 164MB @ 2.26TB/s, latency-suspect); (b) next-layer GEMM fused into
// each aggregation epilogue via LDS h-staging (kills hbuf: ~100MB traffic
// + 2 dispatches). Gather tables bf16; all accumulation fp32.
// ---------------------------------------------------------------------------

#define NBUCK 196    // ceil(100000 / 512)
#define BSHIFT 9     // 512 nodes per bucket
#define CAP 18432    // per-bucket edge capacity; mean 16384, +16 sigma

typedef __attribute__((ext_vector_type(4))) unsigned short ushort4v;
typedef __attribute__((ext_vector_type(8))) unsigned short ushort8v;

__device__ __forceinline__ float bf2f(unsigned short u) {
  union { unsigned int i; float f; } v;
  v.i = ((unsigned int)u) << 16;
  return v.f;
}
__device__ __forceinline__ unsigned short f2bf(float f) {
  union { float f; unsigned int i; } v;
  v.f = f;
  unsigned int r = v.i + 0x7FFF + ((v.i >> 16) & 1);  // RNE
  return (unsigned short)(r >> 16);
}

// Partition edges into dst-buckets, packed as ((dst&511)<<17)|src (src<2^17).
static __global__ __launch_bounds__(256) void partition_kernel(
    const int* __restrict__ src, const int* __restrict__ dst,
    int* __restrict__ bucket_cnt, int* __restrict__ part, int E) {
  __shared__ int hist[NBUCK];
  __shared__ int bbase[NBUCK];
  __shared__ int cur[NBUCK];
  const int t = threadIdx.x;
  for (int j = t; j < NBUCK; j += 256) { hist[j] = 0; cur[j] = 0; }
  __syncthreads();
  const int base = blockIdx.x * 8192;
  for (int k = 0; k < 32; ++k) {
    int i = base + k * 256 + t;
    if (i < E) atomicAdd(&hist[dst[i] >> BSHIFT], 1);
  }
  __syncthreads();
  for (int j = t; j < NBUCK; j += 256) {
    int h = hist[j];
    bbase[j] = h ? atomicAdd(&bucket_cnt[j], h) : 0;
  }
  __syncthreads();
  for (int k = 0; k < 32; ++k) {
    int i = base + k * 256 + t;
    if (i < E) {
      int d = dst[i];
      int b = d >> BSHIFT;
      int r = bbase[b] + atomicAdd(&cur[b], 1);
      if (r < CAP) part[b * CAP + r] = ((d & 511) << 17) | src[i];
    }
  }
}

// One block per bucket: local 512-histogram -> scan -> row_start/row_end/dinv,
// then counting-sort scatter of src into csr_src (80KB window, L2-resident).
static __global__ __launch_bounds__(256) void bucket2csr_kernel(
    const int* __restrict__ bucket_cnt, const int* __restrict__ part,
    int* __restrict__ csr_src, int* __restrict__ row_start,
    int* __restrict__ row_end, float* __restrict__ dinv, int n) {
  __shared__ int hist[512];
  __shared__ int cursor[512];
  __shared__ int sdata[256];
  const int b = blockIdx.x;
  const int t = threadIdx.x;
  const int base = b * CAP;
  int cnt = bucket_cnt[b];
  if (cnt > CAP) cnt = CAP;
  hist[t] = 0;
  hist[t + 256] = 0;
  __syncthreads();
  for (int i = t; i < cnt; i += 256)
    atomicAdd(&hist[part[base + i] >> 17], 1);
  __syncthreads();
  int v0 = hist[2 * t], v1 = hist[2 * t + 1];
  int s = v0 + v1;
  sdata[t] = s;
  __syncthreads();
  int incl = s;
  for (int off = 1; off < 256; off <<= 1) {
    int y = (t >= off) ? sdata[t - off] : 0;
    __syncthreads();
    incl += y;
    sdata[t] = incl;
    __syncthreads();
  }
  int excl = incl - s;
  cursor[2 * t] = excl;
  cursor[2 * t + 1] = excl + v0;
  int node0 = b * 512 + 2 * t;
  if (node0 < n) {
    row_start[node0] = base + excl;
    row_end[node0] = base + excl + v0;
    dinv[node0] = rsqrtf((float)(v0 + 1));  // +1 self loop
  }
  if (node0 + 1 < n) {
    row_start[node0 + 1] = base + excl + v0;
    row_end[node0 + 1] = base + excl + v0 + v1;
    dinv[node0 + 1] = rsqrtf((float)(v1 + 1));
  }
  __syncthreads();
  for (int i = t; i < cnt; i += 256) {
    int p = part[base + i];
    int pos = atomicAdd(&cursor[p >> 17], 1);
    csr_src[base + pos] = p & 0x1FFFF;
  }
}

// xws(bf16) = dinv .* (H @ W).  H fp32. PER_NODE = FOUT/4 threads per node.
template <int FIN, int FOUT>
static __global__ __launch_bounds__(256) void gemm_scale_kernel(
    const float* __restrict__ H, const float* __restrict__ W,
    const float* __restrict__ dinv, unsigned short* __restrict__ out, int n) {
  constexpr int PER_NODE = FOUT / 4;
  constexpr int NODES = 256 / PER_NODE;
  __shared__ float ws[FIN * FOUT];
  __shared__ float hrow[NODES][FIN + 1];
  int t = threadIdx.x;
  for (int i = t; i < FIN * FOUT / 4; i += 256)
    *(float4*)&ws[i * 4] = *(const float4*)&W[i * 4];
  int nodeBase = blockIdx.x * NODES;
  for (int i = t; i < NODES * FIN / 4; i += 256) {
    int nl = (i * 4) / FIN, k = (i * 4) % FIN;
    int node = nodeBase + nl;
    float4 v = {0.f, 0.f, 0.f, 0.f};
    if (node < n) v = *(const float4*)&H[(size_t)node * FIN + k];
    *(float4*)&hrow[nl][k] = v;
  }
  __syncthreads();
  int nl = t / PER_NODE;
  int c = t - nl * PER_NODE;
  float4 acc = {0.f, 0.f, 0.f, 0.f};
#pragma unroll 4
  for (int k = 0; k < FIN; ++k) {
    float hv = hrow[nl][k];
    const float4 w4 = *(const float4*)&ws[k * FOUT + c * 4];
    acc.x += hv * w4.x; acc.y += hv * w4.y; acc.z += hv * w4.z; acc.w += hv * w4.w;
  }
  int node = nodeBase + nl;
  if (node < n) {
    float dv = dinv[node];
    ushort4v r = {f2bf(dv * acc.x), f2bf(dv * acc.y), f2bf(dv * acc.z),
                  f2bf(dv * acc.w)};
    *(ushort4v*)&out[(size_t)node * FOUT + c * 4] = r;
  }
}

// Fused: h = relu(dinv*(gather-sum + self) + bias); xws_next = bf16(dinv*(h@W)).
// G = F/8 threads per node; h staged in LDS for the epilogue GEMM.
template <int F, int FOUT>
static __global__ __launch_bounds__(256) void agg_gemm_kernel(
    const unsigned short* __restrict__ xws, const int* __restrict__ row_start,
    const int* __restrict__ row_end, const int* __restrict__ csr_src,
    const float* __restrict__ dinv, const float* __restrict__ bias,
    const float* __restrict__ W, unsigned short* __restrict__ xws_next, int n) {
  constexpr int G = F / 8;
  constexpr int NODES = 256 / G;
  constexpr int OUTS = FOUT / G;  // outputs per thread in epilogue (=4)
  __shared__ float ws[F * FOUT];
  __shared__ float hs[NODES][F + 1];
  const int t = threadIdx.x;
  for (int i = t; i < F * FOUT / 4; i += 256)
    *(float4*)&ws[i * 4] = *(const float4*)&W[i * 4];
  const int nl = t / G;
  const int c = t - nl * G;
  const int node = blockIdx.x * NODES + nl;
  const bool valid = node < n;
  const int safe = valid ? node : 0;
  int start = valid ? row_start[safe] : 0;
  int end = valid ? row_end[safe] : 0;
  float acc[8] = {0.f, 0.f, 0.f, 0.f, 0.f, 0.f, 0.f, 0.f};
  int e = start;
  // 8-deep unroll: 8 independent row loads in flight per group.
  for (; e + 8 <= end; e += 8) {
    int s0 = csr_src[e + 0], s1 = csr_src[e + 1];
    int s2 = csr_src[e + 2], s3 = csr_src[e + 3];
    int s4 = csr_src[e + 4], s5 = csr_src[e + 5];
    int s6 = csr_src[e + 6], s7 = csr_src[e + 7];
    ushort8v v0 = *(const ushort8v*)&xws[s0 * F + c * 8];
    ushort8v v1 = *(const ushort8v*)&xws[s1 * F + c * 8];
    ushort8v v2 = *(const ushort8v*)&xws[s2 * F + c * 8];
    ushort8v v3 = *(const ushort8v*)&xws[s3 * F + c * 8];
    ushort8v v4 = *(const ushort8v*)&xws[s4 * F + c * 8];
    ushort8v v5 = *(const ushort8v*)&xws[s5 * F + c * 8];
    ushort8v v6 = *(const ushort8v*)&xws[s6 * F + c * 8];
    ushort8v v7 = *(const ushort8v*)&xws[s7 * F + c * 8];
#pragma unroll
    for (int j = 0; j < 8; ++j)
      acc[j] += ((bf2f(v0[j]) + bf2f(v1[j])) + (bf2f(v2[j]) + bf2f(v3[j]))) +
                ((bf2f(v4[j]) + bf2f(v5[j])) + (bf2f(v6[j]) + bf2f(v7[j])));
  }
  for (; e + 4 <= end; e += 4) {
    int s0 = csr_src[e + 0], s1 = csr_src[e + 1];
    int s2 = csr_src[e + 2], s3 = csr_src[e + 3];
    ushort8v v0 = *(const ushort8v*)&xws[s0 * F + c * 8];
    ushort8v v1 = *(const ushort8v*)&xws[s1 * F + c * 8];
    ushort8v v2 = *(const ushort8v*)&xws[s2 * F + c * 8];
    ushort8v v3 = *(const ushort8v*)&xws[s3 * F + c * 8];
#pragma unroll
    for (int j = 0; j < 8; ++j)
      acc[j] += (bf2f(v0[j]) + bf2f(v1[j])) + (bf2f(v2[j]) + bf2f(v3[j]));
  }
  for (; e < end; ++e) {
    int s = csr_src[e];
    ushort8v v = *(const ushort8v*)&xws[s * F + c * 8];
#pragma unroll
    for (int j = 0; j < 8; ++j) acc[j] += bf2f(v[j]);
  }
  ushort8v sv = *(const ushort8v*)&xws[safe * F + c * 8];
  const float dv = dinv[safe];
#pragma unroll
  for (int j = 0; j < 8; ++j)
    hs[nl][c * 8 + j] = fmaxf(dv * (acc[j] + bf2f(sv[j])) + bias[c * 8 + j], 0.f);
  __syncthreads();
  // epilogue GEMM: each thread computes OUTS outputs of its node
  float o[OUTS] = {0.f, 0.f, 0.f, 0.f};
#pragma unroll 4
  for (int k = 0; k < F; ++k) {
    float hv = hs[nl][k];
#pragma unroll
    for (int j = 0; j < OUTS; ++j) o[j] += hv * ws[k * FOUT + c * OUTS + j];
  }
  if (valid) {
    ushort4v r = {f2bf(dv * o[0]), f2bf(dv * o[1]), f2bf(dv * o[2]),
                  f2bf(dv * o[3])};
    *(ushort4v*)&xws_next[node * FOUT + c * OUTS] = r;
  }
}

// Final layer: h = relu(dinv*(gather+self)+b3); out[n] = h . w_out + b_out.
static __global__ __launch_bounds__(256) void agg_head_kernel(
    const unsigned short* __restrict__ xws, const int* __restrict__ row_start,
    const int* __restrict__ row_end, const int* __restrict__ csr_src,
    const float* __restrict__ dinv, const float* __restrict__ bias,
    float* __restrict__ out, const float* __restrict__ w_out,
    const float* __restrict__ b_out, int n) {
  constexpr int F = 16, G = 2, NODES = 128;
  int t = threadIdx.x;
  int nl = t / G;
  int c = t - nl * G;
  int node = blockIdx.x * NODES + nl;
  if (node >= n) return;
  int start = row_start[node], end = row_end[node];
  float acc[8] = {0.f, 0.f, 0.f, 0.f, 0.f, 0.f, 0.f, 0.f};
  int e = start;
  for (; e + 8 <= end; e += 8) {
    int s0 = csr_src[e + 0], s1 = csr_src[e + 1];
    int s2 = csr_src[e + 2], s3 = csr_src[e + 3];
    int s4 = csr_src[e + 4], s5 = csr_src[e + 5];
    int s6 = csr_src[e + 6], s7 = csr_src[e + 7];
    ushort8v v0 = *(const ushort8v*)&xws[s0 * F + c * 8];
    ushort8v v1 = *(const ushort8v*)&xws[s1 * F + c * 8];
    ushort8v v2 = *(const ushort8v*)&xws[s2 * F + c * 8];
    ushort8v v3 = *(const ushort8v*)&xws[s3 * F + c * 8];
    ushort8v v4 = *(const ushort8v*)&xws[s4 * F + c * 8];
    ushort8v v5 = *(const ushort8v*)&xws[s5 * F + c * 8];
    ushort8v v6 = *(const ushort8v*)&xws[s6 * F + c * 8];
    ushort8v v7 = *(const ushort8v*)&xws[s7 * F + c * 8];
#pragma unroll
    for (int j = 0; j < 8; ++j)
      acc[j] += ((bf2f(v0[j]) + bf2f(v1[j])) + (bf2f(v2[j]) + bf2f(v3[j]))) +
                ((bf2f(v4[j]) + bf2f(v5[j])) + (bf2f(v6[j]) + bf2f(v7[j])));
  }
  for (; e < end; ++e) {
    int s = csr_src[e];
    ushort8v v = *(const ushort8v*)&xws[s * F + c * 8];
#pragma unroll
    for (int j = 0; j < 8; ++j) acc[j] += bf2f(v[j]);
  }
  ushort8v sv = *(const ushort8v*)&xws[node * F + c * 8];
  float dv = dinv[node];
  float p = 0.f;
#pragma unroll
  for (int j = 0; j < 8; ++j) {
    float r = fmaxf(dv * (acc[j] + bf2f(sv[j])) + bias[c * 8 + j], 0.f);
    p += r * w_out[c * 8 + j];
  }
  p += __shfl_xor(p, 1);  // pair lanes (G==2)
  if (c == 0) out[node] = p + b_out[0];
}

extern "C" void kernel_launch(void* const* d_in, const int* in_sizes, int n_in,
                              void* d_out, int out_size, void* d_ws, size_t ws_size,
                              hipStream_t stream) {
  const float* x     = (const float*)d_in[0];
  const int*   ei    = (const int*)d_in[1];
  const float* w1    = (const float*)d_in[2];
  const float* b1    = (const float*)d_in[3];
  const float* w2    = (const float*)d_in[4];
  const float* b2    = (const float*)d_in[5];
  const float* w3    = (const float*)d_in[6];
  const float* b3    = (const float*)d_in[7];
  const float* w_out = (const float*)d_in[8];
  const float* b_out = (const float*)d_in[9];
  float* out = (float*)d_out;

  const int n = in_sizes[0] / 128;   // 100000
  const int E = in_sizes[1] / 2;     // 3200000
  const int* srcA = ei;
  const int* dstA = ei + E;

  char* p = (char*)d_ws;
  auto carve = [&](size_t bytes) {
    void* r = (void*)p;
    p += (bytes + 255) & ~(size_t)255;
    return r;
  };
  const size_t partBytes = (size_t)NBUCK * CAP * 4;  // 14.45 MB
  int*   csr_src    = (int*)carve(partBytes);
  int*   bucket_cnt = (int*)carve((size_t)NBUCK * 4);
  int*   row_start  = (int*)carve((size_t)n * 4);
  int*   row_end    = (int*)carve((size_t)n * 4);
  float* dinv       = (float*)carve((size_t)n * 4);
  // part (14.45MB, dead after bucket2csr) aliases xws1 (12.8MB, written after)
  char*  regionP    = (char*)carve(partBytes);
  int*   part       = (int*)regionP;
  unsigned short* xws1 = (unsigned short*)regionP;
  unsigned short* xws2 = (unsigned short*)carve((size_t)n * 32 * 2);  // 6.4 MB
  unsigned short* xws3 = (unsigned short*)carve((size_t)n * 16 * 2);  // 3.2 MB

  hipMemsetAsync(bucket_cnt, 0, (size_t)NBUCK * 4, stream);
  partition_kernel<<<(E + 8191) / 8192, 256, 0, stream>>>(srcA, dstA, bucket_cnt,
                                                          part, E);
  bucket2csr_kernel<<<NBUCK, 256, 0, stream>>>(bucket_cnt, part, csr_src,
                                               row_start, row_end, dinv, n);

  // layer 1 GEMM: xws1 = dinv .* (x @ w1)   [128 -> 64]
  gemm_scale_kernel<128, 64><<<(n + 15) / 16, 256, 0, stream>>>(x, w1, dinv, xws1, n);
  // layer 1 agg + layer 2 GEMM fused: h1 -> xws2   [agg 64, gemm 64->32]
  agg_gemm_kernel<64, 32><<<(n + 31) / 32, 256, 0, stream>>>(
      xws1, row_start, row_end, csr_src, dinv, b1, w2, xws2, n);
  // layer 2 agg + layer 3 GEMM fused: h2 -> xws3   [agg 32, gemm 32->16]
  agg_gemm_kernel<32, 16><<<(n + 63) / 64, 256, 0, stream>>>(
      xws2, row_start, row_end, csr_src, dinv, b2, w3, xws3, n);
  // layer 3 agg + head fused
  agg_head_kernel<<<(n + 127) / 128, 256, 0, stream>>>(
      xws3, row_start, row_end, csr_src, dinv, b3, out, w_out, b_out, n);
}

// Round 5
// 242.572 us; speedup vs baseline: 3.1515x; 1.1003x over previous
//
#include <hip/hip_runtime.h>
#include <hip/hip_bf16.h>

// ---------------------------------------------------------------------------
// GCN forward: 3x GCNConv(relu) + linear head.
// R4->R5: (a) layer-1 GEMM moved to fp16 MFMA (R4: fp32 vector version was
// LDS-throughput-bound at 62us, 6x over its ALU floor); (b) agg gather
// concurrency doubled via SPLIT=2 sub-groups per node (R4: 2.8TB/s,
// latency-suspect). Gather tables bf16, accumulation fp32.
// ---------------------------------------------------------------------------

#define NBUCK 196    // ceil(100000 / 512)
#define BSHIFT 9     // 512 nodes per bucket
#define CAP 18432    // per-bucket edge capacity; mean 16384, +16 sigma

typedef __attribute__((ext_vector_type(4))) unsigned short ushort4v;
typedef __attribute__((ext_vector_type(8))) unsigned short ushort8v;
typedef __attribute__((ext_vector_type(2))) unsigned short ushort2v;
typedef __attribute__((ext_vector_type(8))) _Float16 half8;
typedef __attribute__((ext_vector_type(4))) float f32x4;

__device__ __forceinline__ float bf2f(unsigned short u) {
  union { unsigned int i; float f; } v;
  v.i = ((unsigned int)u) << 16;
  return v.f;
}
__device__ __forceinline__ unsigned short f2bf(float f) {
  union { float f; unsigned int i; } v;
  v.f = f;
  unsigned int r = v.i + 0x7FFF + ((v.i >> 16) & 1);  // RNE
  return (unsigned short)(r >> 16);
}

// Partition edges into dst-buckets, packed as ((dst&511)<<17)|src (src<2^17).
static __global__ __launch_bounds__(256) void partition_kernel(
    const int* __restrict__ src, const int* __restrict__ dst,
    int* __restrict__ bucket_cnt, int* __restrict__ part, int E) {
  __shared__ int hist[NBUCK];
  __shared__ int bbase[NBUCK];
  __shared__ int cur[NBUCK];
  const int t = threadIdx.x;
  for (int j = t; j < NBUCK; j += 256) { hist[j] = 0; cur[j] = 0; }
  __syncthreads();
  const int base = blockIdx.x * 8192;
  for (int k = 0; k < 32; ++k) {
    int i = base + k * 256 + t;
    if (i < E) atomicAdd(&hist[dst[i] >> BSHIFT], 1);
  }
  __syncthreads();
  for (int j = t; j < NBUCK; j += 256) {
    int h = hist[j];
    bbase[j] = h ? atomicAdd(&bucket_cnt[j], h) : 0;
  }
  __syncthreads();
  for (int k = 0; k < 32; ++k) {
    int i = base + k * 256 + t;
    if (i < E) {
      int d = dst[i];
      int b = d >> BSHIFT;
      int r = bbase[b] + atomicAdd(&cur[b], 1);
      if (r < CAP) part[b * CAP + r] = ((d & 511) << 17) | src[i];
    }
  }
}

// One block per bucket: local 512-histogram -> scan -> row_start/row_end/dinv,
// then counting-sort scatter of src into csr_src (80KB window, L2-resident).
static __global__ __launch_bounds__(256) void bucket2csr_kernel(
    const int* __restrict__ bucket_cnt, const int* __restrict__ part,
    int* __restrict__ csr_src, int* __restrict__ row_start,
    int* __restrict__ row_end, float* __restrict__ dinv, int n) {
  __shared__ int hist[512];
  __shared__ int cursor[512];
  __shared__ int sdata[256];
  const int b = blockIdx.x;
  const int t = threadIdx.x;
  const int base = b * CAP;
  int cnt = bucket_cnt[b];
  if (cnt > CAP) cnt = CAP;
  hist[t] = 0;
  hist[t + 256] = 0;
  __syncthreads();
  for (int i = t; i < cnt; i += 256)
    atomicAdd(&hist[part[base + i] >> 17], 1);
  __syncthreads();
  int v0 = hist[2 * t], v1 = hist[2 * t + 1];
  int s = v0 + v1;
  sdata[t] = s;
  __syncthreads();
  int incl = s;
  for (int off = 1; off < 256; off <<= 1) {
    int y = (t >= off) ? sdata[t - off] : 0;
    __syncthreads();
    incl += y;
    sdata[t] = incl;
    __syncthreads();
  }
  int excl = incl - s;
  cursor[2 * t] = excl;
  cursor[2 * t + 1] = excl + v0;
  int node0 = b * 512 + 2 * t;
  if (node0 < n) {
    row_start[node0] = base + excl;
    row_end[node0] = base + excl + v0;
    dinv[node0] = rsqrtf((float)(v0 + 1));  // +1 self loop
  }
  if (node0 + 1 < n) {
    row_start[node0 + 1] = base + excl + v0;
    row_end[node0 + 1] = base + excl + v0 + v1;
    dinv[node0 + 1] = rsqrtf((float)(v1 + 1));
  }
  __syncthreads();
  for (int i = t; i < cnt; i += 256) {
    int p = part[base + i];
    int pos = atomicAdd(&cursor[p >> 17], 1);
    csr_src[base + pos] = p & 0x1FFFF;
  }
}

// Layer-1 GEMM via fp16 MFMA: xws1(bf16) = dinv .* (x @ w1), fp32 accum.
// Block = 64 nodes x 64 outs, 4 waves (wave w -> rows 16w..16w+15).
// LDS tiles XOR-swizzled (T2): byte ^= (row&7)<<4 within each 256B row.
static __global__ __launch_bounds__(256) void gemm1_mfma_kernel(
    const float* __restrict__ x, const float* __restrict__ w1,
    const float* __restrict__ dinv, unsigned short* __restrict__ xws, int n) {
  __shared__ _Float16 xa[64 * 128];  // x tile   [node][k]
  __shared__ _Float16 wt[64 * 128];  // w1^T     [o][k]
  const int t = threadIdx.x;
  const int base = blockIdx.x * 64;
  // stage x: 64 rows x 128 k, fp32 -> fp16, 8 halfs per iteration.
  for (int i = t; i < 64 * 16; i += 256) {
    int r = i >> 4, k8 = i & 15;
    int node = base + r;
    float4 a = {0.f, 0.f, 0.f, 0.f}, b = {0.f, 0.f, 0.f, 0.f};
    if (node < n) {
      a = *(const float4*)&x[(size_t)node * 128 + k8 * 8];
      b = *(const float4*)&x[(size_t)node * 128 + k8 * 8 + 4];
    }
    half8 h = {(_Float16)a.x, (_Float16)a.y, (_Float16)a.z, (_Float16)a.w,
               (_Float16)b.x, (_Float16)b.y, (_Float16)b.z, (_Float16)b.w};
    int byte = (r * 256 + k8 * 16) ^ ((r & 7) << 4);
    *(half8*)((char*)xa + byte) = h;
  }
  // stage w1^T: w1[k][o] fp32 -> wt[o][k] fp16 (8K elems, once per block).
  for (int i = t; i < 128 * 64; i += 256) {
    int k = i >> 6, o = i & 63;
    _Float16 v = (_Float16)w1[i];
    int byte = (o * 256 + k * 2) ^ ((o & 7) << 4);
    *(_Float16*)((char*)wt + byte) = v;
  }
  __syncthreads();
  const int wv = t >> 6;
  const int lane = t & 63;
  const int m = lane & 15;   // A row / D col
  const int kg = lane >> 4;  // k-group
  const int arow = wv * 16 + m;
  f32x4 acc[4] = {{0.f, 0.f, 0.f, 0.f}, {0.f, 0.f, 0.f, 0.f},
                  {0.f, 0.f, 0.f, 0.f}, {0.f, 0.f, 0.f, 0.f}};
#pragma unroll
  for (int ks = 0; ks < 4; ++ks) {  // K steps of 32
    int k0 = ks * 32 + kg * 8;
    int abyte = (arow * 256 + k0 * 2) ^ ((arow & 7) << 4);
    half8 af = *(const half8*)((const char*)xa + abyte);
#pragma unroll
    for (int nt = 0; nt < 4; ++nt) {
      int o = nt * 16 + m;
      int bbyte = (o * 256 + k0 * 2) ^ ((o & 7) << 4);
      half8 bf = *(const half8*)((const char*)wt + bbyte);
      acc[nt] = __builtin_amdgcn_mfma_f32_16x16x32_f16(af, bf, acc[nt], 0, 0, 0);
    }
  }
  // D: col = lane&15 (=m), row = kg*4 + r
#pragma unroll
  for (int r = 0; r < 4; ++r) {
    int node = base + wv * 16 + kg * 4 + r;
    if (node < n) {
      float dv = dinv[node];
#pragma unroll
      for (int nt = 0; nt < 4; ++nt)
        xws[(size_t)node * 64 + nt * 16 + m] = f2bf(dv * acc[nt][r]);
    }
  }
}

// Fused: h = relu(dinv*(gather-sum + self) + bias); xws_next = bf16(dinv*(h@W)).
// SPLIT=2: LPN = F/4 lanes per node; two F/8-lane sub-groups take even/odd
// edges, combined with one shfl_xor. h staged in LDS for the epilogue GEMM.
template <int F, int FOUT>
static __global__ __launch_bounds__(256) void agg_gemm_kernel(
    const unsigned short* __restrict__ xws, const int* __restrict__ row_start,
    const int* __restrict__ row_end, const int* __restrict__ csr_src,
    const float* __restrict__ dinv, const float* __restrict__ bias,
    const float* __restrict__ W, unsigned short* __restrict__ xws_next, int n) {
  constexpr int GC = F / 8;        // feat-groups (8 feats each)
  constexpr int LPN = F / 4;       // lanes per node (2 sub-groups)
  constexpr int NODES = 256 / LPN;
  constexpr int OUTS = FOUT / LPN; // epilogue outputs per thread (=2)
  __shared__ float ws[F * FOUT];
  __shared__ float hs[NODES][F + 1];
  const int t = threadIdx.x;
  for (int i = t; i < F * FOUT / 4; i += 256)
    *(float4*)&ws[i * 4] = *(const float4*)&W[i * 4];
  const int nl = t / LPN;
  const int l = t % LPN;
  const int c = l % GC;
  const int sub = l / GC;
  const int node = blockIdx.x * NODES + nl;
  const bool valid = node < n;
  const int safe = valid ? node : 0;
  const int start = valid ? row_start[safe] : 0;
  const int end = valid ? row_end[safe] : 0;
  float acc[8] = {0.f, 0.f, 0.f, 0.f, 0.f, 0.f, 0.f, 0.f};
  int e = start + sub;
  // 8-deep unroll over this sub-group's edges (stride 2): 8 loads in flight.
  for (; e + 14 < end; e += 16) {
    int s0 = csr_src[e + 0],  s1 = csr_src[e + 2];
    int s2 = csr_src[e + 4],  s3 = csr_src[e + 6];
    int s4 = csr_src[e + 8],  s5 = csr_src[e + 10];
    int s6 = csr_src[e + 12], s7 = csr_src[e + 14];
    ushort8v v0 = *(const ushort8v*)&xws[(size_t)s0 * F + c * 8];
    ushort8v v1 = *(const ushort8v*)&xws[(size_t)s1 * F + c * 8];
    ushort8v v2 = *(const ushort8v*)&xws[(size_t)s2 * F + c * 8];
    ushort8v v3 = *(const ushort8v*)&xws[(size_t)s3 * F + c * 8];
    ushort8v v4 = *(const ushort8v*)&xws[(size_t)s4 * F + c * 8];
    ushort8v v5 = *(const ushort8v*)&xws[(size_t)s5 * F + c * 8];
    ushort8v v6 = *(const ushort8v*)&xws[(size_t)s6 * F + c * 8];
    ushort8v v7 = *(const ushort8v*)&xws[(size_t)s7 * F + c * 8];
#pragma unroll
    for (int j = 0; j < 8; ++j)
      acc[j] += ((bf2f(v0[j]) + bf2f(v1[j])) + (bf2f(v2[j]) + bf2f(v3[j]))) +
                ((bf2f(v4[j]) + bf2f(v5[j])) + (bf2f(v6[j]) + bf2f(v7[j])));
  }
  for (; e < end; e += 2) {
    int s = csr_src[e];
    ushort8v v = *(const ushort8v*)&xws[(size_t)s * F + c * 8];
#pragma unroll
    for (int j = 0; j < 8; ++j) acc[j] += bf2f(v[j]);
  }
  // combine the two sub-groups (lane ^ GC within the node's LPN lanes)
#pragma unroll
  for (int j = 0; j < 8; ++j) acc[j] += __shfl_xor(acc[j], GC);
  const float dv = dinv[safe];
  if (sub == 0) {
    ushort8v sv = *(const ushort8v*)&xws[(size_t)safe * F + c * 8];
#pragma unroll
    for (int j = 0; j < 8; ++j)
      hs[nl][c * 8 + j] =
          fmaxf(dv * (acc[j] + bf2f(sv[j])) + bias[c * 8 + j], 0.f);
  }
  __syncthreads();
  // epilogue GEMM: all LPN lanes, OUTS outputs each
  float o[OUTS];
#pragma unroll
  for (int j = 0; j < OUTS; ++j) o[j] = 0.f;
#pragma unroll 4
  for (int k = 0; k < F; ++k) {
    float hv = hs[nl][k];
#pragma unroll
    for (int j = 0; j < OUTS; ++j) o[j] += hv * ws[k * FOUT + l * OUTS + j];
  }
  if (valid) {
    ushort2v r = {f2bf(dv * o[0]), f2bf(dv * o[1])};
    *(ushort2v*)&xws_next[(size_t)node * FOUT + l * OUTS] = r;
  }
}

// Final layer: h = relu(dinv*(gather+self)+b3); out[n] = h . w_out + b_out.
// F=16: 4 lanes per node (2 feat-groups x 2 sub-groups).
static __global__ __launch_bounds__(256) void agg_head_kernel(
    const unsigned short* __restrict__ xws, const int* __restrict__ row_start,
    const int* __restrict__ row_end, const int* __restrict__ csr_src,
    const float* __restrict__ dinv, const float* __restrict__ bias,
    float* __restrict__ out, const float* __restrict__ w_out,
    const float* __restrict__ b_out, int n) {
  constexpr int F = 16, NODES = 64;
  const int t = threadIdx.x;
  const int nl = t >> 2;
  const int l = t & 3;
  const int c = l & 1;
  const int sub = l >> 1;
  const int node = blockIdx.x * NODES + nl;
  if (node >= n) return;
  const int start = row_start[node], end = row_end[node];
  float acc[8] = {0.f, 0.f, 0.f, 0.f, 0.f, 0.f, 0.f, 0.f};
  int e = start + sub;
  for (; e + 14 < end; e += 16) {
    int s0 = csr_src[e + 0],  s1 = csr_src[e + 2];
    int s2 = csr_src[e + 4],  s3 = csr_src[e + 6];
    int s4 = csr_src[e + 8],  s5 = csr_src[e + 10];
    int s6 = csr_src[e + 12], s7 = csr_src[e + 14];
    ushort8v v0 = *(const ushort8v*)&xws[(size_t)s0 * F + c * 8];
    ushort8v v1 = *(const ushort8v*)&xws[(size_t)s1 * F + c * 8];
    ushort8v v2 = *(const ushort8v*)&xws[(size_t)s2 * F + c * 8];
    ushort8v v3 = *(const ushort8v*)&xws[(size_t)s3 * F + c * 8];
    ushort8v v4 = *(const ushort8v*)&xws[(size_t)s4 * F + c * 8];
    ushort8v v5 = *(const ushort8v*)&xws[(size_t)s5 * F + c * 8];
    ushort8v v6 = *(const ushort8v*)&xws[(size_t)s6 * F + c * 8];
    ushort8v v7 = *(const ushort8v*)&xws[(size_t)s7 * F + c * 8];
#pragma unroll
    for (int j = 0; j < 8; ++j)
      acc[j] += ((bf2f(v0[j]) + bf2f(v1[j])) + (bf2f(v2[j]) + bf2f(v3[j]))) +
                ((bf2f(v4[j]) + bf2f(v5[j])) + (bf2f(v6[j]) + bf2f(v7[j])));
  }
  for (; e < end; e += 2) {
    int s = csr_src[e];
    ushort8v v = *(const ushort8v*)&xws[(size_t)s * F + c * 8];
#pragma unroll
    for (int j = 0; j < 8; ++j) acc[j] += bf2f(v[j]);
  }
#pragma unroll
  for (int j = 0; j < 8; ++j) acc[j] += __shfl_xor(acc[j], 2);
  ushort8v sv = *(const ushort8v*)&xws[(size_t)node * F + c * 8];
  float dv = dinv[node];
  float p = 0.f;
#pragma unroll
  for (int j = 0; j < 8; ++j) {
    float r = fmaxf(dv * (acc[j] + bf2f(sv[j])) + bias[c * 8 + j], 0.f);
    p += r * w_out[c * 8 + j];
  }
  p += __shfl_xor(p, 1);  // combine the two feat-groups
  if (l == 0) out[node] = p + b_out[0];
}

extern "C" void kernel_launch(void* const* d_in, const int* in_sizes, int n_in,
                              void* d_out, int out_size, void* d_ws, size_t ws_size,
                              hipStream_t stream) {
  const float* x     = (const float*)d_in[0];
  const int*   ei    = (const int*)d_in[1];
  const float* w1    = (const float*)d_in[2];
  const float* b1    = (const float*)d_in[3];
  const float* w2    = (const float*)d_in[4];
  const float* b2    = (const float*)d_in[5];
  const float* w3    = (const float*)d_in[6];
  const float* b3    = (const float*)d_in[7];
  const float* w_out = (const float*)d_in[8];
  const float* b_out = (const float*)d_in[9];
  float* out = (float*)d_out;

  const int n = in_sizes[0] / 128;   // 100000
  const int E = in_sizes[1] / 2;     // 3200000
  const int* srcA = ei;
  const int* dstA = ei + E;

  char* p = (char*)d_ws;
  auto carve = [&](size_t bytes) {
    void* r = (void*)p;
    p += (bytes + 255) & ~(size_t)255;
    return r;
  };
  const size_t partBytes = (size_t)NBUCK * CAP * 4;  // 14.45 MB
  int*   csr_src    = (int*)carve(partBytes);
  int*   bucket_cnt = (int*)carve((size_t)NBUCK * 4);
  int*   row_start  = (int*)carve((size_t)n * 4);
  int*   row_end    = (int*)carve((size_t)n * 4);
  float* dinv       = (float*)carve((size_t)n * 4);
  // part (14.45MB, dead after bucket2csr) aliases xws1 (12.8MB, written after)
  char*  regionP    = (char*)carve(partBytes);
  int*   part       = (int*)regionP;
  unsigned short* xws1 = (unsigned short*)regionP;
  unsigned short* xws2 = (unsigned short*)carve((size_t)n * 32 * 2);  // 6.4 MB
  unsigned short* xws3 = (unsigned short*)carve((size_t)n * 16 * 2);  // 3.2 MB

  hipMemsetAsync(bucket_cnt, 0, (size_t)NBUCK * 4, stream);
  partition_kernel<<<(E + 8191) / 8192, 256, 0, stream>>>(srcA, dstA, bucket_cnt,
                                                          part, E);
  bucket2csr_kernel<<<NBUCK, 256, 0, stream>>>(bucket_cnt, part, csr_src,
                                               row_start, row_end, dinv, n);

  // layer 1 GEMM (fp16 MFMA): xws1 = dinv .* (x @ w1)   [128 -> 64]
  gemm1_mfma_kernel<<<(n + 63) / 64, 256, 0, stream>>>(x, w1, dinv, xws1, n);
  // layer 1 agg + layer 2 GEMM fused: h1 -> xws2   [agg 64, gemm 64->32]
  agg_gemm_kernel<64, 32><<<(n + 15) / 16, 256, 0, stream>>>(
      xws1, row_start, row_end, csr_src, dinv, b1, w2, xws2, n);
  // layer 2 agg + layer 3 GEMM fused: h2 -> xws3   [agg 32, gemm 32->16]
  agg_gemm_kernel<32, 16><<<(n + 31) / 32, 256, 0, stream>>>(
      xws2, row_start, row_end, csr_src, dinv, b2, w3, xws3, n);
  // layer 3 agg + head fused
  agg_head_kernel<<<(n + 63) / 64, 256, 0, stream>>>(
      xws3, row_start, row_end, csr_src, dinv, b3, out, w_out, b_out, n);
}

// Round 6
// 235.411 us; speedup vs baseline: 3.2473x; 1.0304x over previous
//
#include <hip/hip_runtime.h>
#include <hip/hip_bf16.h>

// ---------------------------------------------------------------------------
// GCN forward: 3x GCNConv(relu) + linear head.
// R5->R6: SPLIT=2 reverted (tail-dominance regression: P(sub-deg<16)=46% ran
// fully serial). Instead, CSR segments padded to multiple-of-8 with sentinel
// src=n pointing at a zeroed row -> agg loops are pure branch-free 8-deep
// unrolled, zero tail. Gather tables bf16, accumulation fp32.
// ---------------------------------------------------------------------------

#define NBUCK 196    // ceil(100000 / 512)
#define BSHIFT 9     // 512 nodes per bucket
#define CAP 20480    // per-bucket capacity; padded mean ~18.2K, +15 sigma

typedef __attribute__((ext_vector_type(4))) unsigned short ushort4v;
typedef __attribute__((ext_vector_type(8))) unsigned short ushort8v;
typedef __attribute__((ext_vector_type(8))) _Float16 half8;
typedef __attribute__((ext_vector_type(4))) float f32x4;

__device__ __forceinline__ float bf2f(unsigned short u) {
  union { unsigned int i; float f; } v;
  v.i = ((unsigned int)u) << 16;
  return v.f;
}
__device__ __forceinline__ unsigned short f2bf(float f) {
  union { float f; unsigned int i; } v;
  v.f = f;
  unsigned int r = v.i + 0x7FFF + ((v.i >> 16) & 1);  // RNE
  return (unsigned short)(r >> 16);
}

// Partition edges into dst-buckets, packed as ((dst&511)<<17)|src (src<2^17).
static __global__ __launch_bounds__(256) void partition_kernel(
    const int* __restrict__ src, const int* __restrict__ dst,
    int* __restrict__ bucket_cnt, int* __restrict__ part, int E) {
  __shared__ int hist[NBUCK];
  __shared__ int bbase[NBUCK];
  __shared__ int cur[NBUCK];
  const int t = threadIdx.x;
  for (int j = t; j < NBUCK; j += 256) { hist[j] = 0; cur[j] = 0; }
  __syncthreads();
  const int base = blockIdx.x * 8192;
  for (int k = 0; k < 32; ++k) {
    int i = base + k * 256 + t;
    if (i < E) atomicAdd(&hist[dst[i] >> BSHIFT], 1);
  }
  __syncthreads();
  for (int j = t; j < NBUCK; j += 256) {
    int h = hist[j];
    bbase[j] = h ? atomicAdd(&bucket_cnt[j], h) : 0;
  }
  __syncthreads();
  for (int k = 0; k < 32; ++k) {
    int i = base + k * 256 + t;
    if (i < E) {
      int d = dst[i];
      int b = d >> BSHIFT;
      int r = bbase[b] + atomicAdd(&cur[b], 1);
      if (r < CAP) part[b * CAP + r] = ((d & 511) << 17) | src[i];
    }
  }
}

// One block per bucket: local 512-histogram -> scan over PADDED (mult-of-8)
// lengths -> row_start/row_end/dinv, counting-sort scatter, pad slots <- n.
static __global__ __launch_bounds__(256) void bucket2csr_kernel(
    const int* __restrict__ bucket_cnt, const int* __restrict__ part,
    int* __restrict__ csr_src, int* __restrict__ row_start,
    int* __restrict__ row_end, float* __restrict__ dinv, int n) {
  __shared__ int hist[512];
  __shared__ int cursor[512];
  __shared__ int sdata[256];
  const int b = blockIdx.x;
  const int t = threadIdx.x;
  const int base = b * CAP;
  int cnt = bucket_cnt[b];
  if (cnt > CAP) cnt = CAP;
  hist[t] = 0;
  hist[t + 256] = 0;
  __syncthreads();
  for (int i = t; i < cnt; i += 256)
    atomicAdd(&hist[part[base + i] >> 17], 1);
  __syncthreads();
  int v0 = hist[2 * t], v1 = hist[2 * t + 1];
  int p0 = (v0 + 7) & ~7;   // padded lengths
  int p1 = (v1 + 7) & ~7;
  int s = p0 + p1;
  sdata[t] = s;
  __syncthreads();
  int incl = s;
  for (int off = 1; off < 256; off <<= 1) {
    int y = (t >= off) ? sdata[t - off] : 0;
    __syncthreads();
    incl += y;
    sdata[t] = incl;
    __syncthreads();
  }
  int excl = incl - s;
  cursor[2 * t] = excl;
  cursor[2 * t + 1] = excl + p0;
  int node0 = b * 512 + 2 * t;
  if (node0 < n) {
    row_start[node0] = base + excl;
    row_end[node0] = base + excl + p0;
    dinv[node0] = rsqrtf((float)(v0 + 1));  // true degree +1 self loop
  }
  if (node0 + 1 < n) {
    row_start[node0 + 1] = base + excl + p0;
    row_end[node0 + 1] = base + excl + p0 + p1;
    dinv[node0 + 1] = rsqrtf((float)(v1 + 1));
  }
  __syncthreads();
  for (int i = t; i < cnt; i += 256) {
    int p = part[base + i];
    int pos = atomicAdd(&cursor[p >> 17], 1);
    csr_src[base + pos] = p & 0x1FFFF;
  }
  // fill pad slots with the zero-row sentinel (disjoint from scattered slots)
  int ps0 = base + excl;
  for (int i = v0; i < p0; ++i) csr_src[ps0 + i] = n;
  int ps1 = ps0 + p0;
  for (int i = v1; i < p1; ++i) csr_src[ps1 + i] = n;
}

// Layer-1 GEMM via fp16 MFMA: xws1(bf16) = dinv .* (x @ w1), fp32 accum.
// Block = 64 nodes x 64 outs, 4 waves. LDS XOR-swizzled: byte ^= (row&7)<<4.
static __global__ __launch_bounds__(256) void gemm1_mfma_kernel(
    const float* __restrict__ x, const float* __restrict__ w1,
    const float* __restrict__ dinv, unsigned short* __restrict__ xws, int n) {
  __shared__ _Float16 xa[64 * 128];  // x tile [node][k]
  __shared__ _Float16 wt[64 * 128];  // w1^T   [o][k]
  const int t = threadIdx.x;
  const int base = blockIdx.x * 64;
  for (int i = t; i < 64 * 16; i += 256) {
    int r = i >> 4, k8 = i & 15;
    int node = base + r;
    float4 a = {0.f, 0.f, 0.f, 0.f}, b = {0.f, 0.f, 0.f, 0.f};
    if (node < n) {
      a = *(const float4*)&x[(size_t)node * 128 + k8 * 8];
      b = *(const float4*)&x[(size_t)node * 128 + k8 * 8 + 4];
    }
    half8 h = {(_Float16)a.x, (_Float16)a.y, (_Float16)a.z, (_Float16)a.w,
               (_Float16)b.x, (_Float16)b.y, (_Float16)b.z, (_Float16)b.w};
    int byte = (r * 256 + k8 * 16) ^ ((r & 7) << 4);
    *(half8*)((char*)xa + byte) = h;
  }
  for (int i = t; i < 128 * 64; i += 256) {
    int k = i >> 6, o = i & 63;
    _Float16 v = (_Float16)w1[i];
    int byte = (o * 256 + k * 2) ^ ((o & 7) << 4);
    *(_Float16*)((char*)wt + byte) = v;
  }
  __syncthreads();
  const int wv = t >> 6;
  const int lane = t & 63;
  const int m = lane & 15;
  const int kg = lane >> 4;
  const int arow = wv * 16 + m;
  f32x4 acc[4] = {{0.f, 0.f, 0.f, 0.f}, {0.f, 0.f, 0.f, 0.f},
                  {0.f, 0.f, 0.f, 0.f}, {0.f, 0.f, 0.f, 0.f}};
#pragma unroll
  for (int ks = 0; ks < 4; ++ks) {
    int k0 = ks * 32 + kg * 8;
    int abyte = (arow * 256 + k0 * 2) ^ ((arow & 7) << 4);
    half8 af = *(const half8*)((const char*)xa + abyte);
#pragma unroll
    for (int nt = 0; nt < 4; ++nt) {
      int o = nt * 16 + m;
      int bbyte = (o * 256 + k0 * 2) ^ ((o & 7) << 4);
      half8 bf = *(const half8*)((const char*)wt + bbyte);
      acc[nt] = __builtin_amdgcn_mfma_f32_16x16x32_f16(af, bf, acc[nt], 0, 0, 0);
    }
  }
#pragma unroll
  for (int r = 0; r < 4; ++r) {
    int node = base + wv * 16 + kg * 4 + r;
    if (node < n) {
      float dv = dinv[node];
#pragma unroll
      for (int nt = 0; nt < 4; ++nt)
        xws[(size_t)node * 64 + nt * 16 + m] = f2bf(dv * acc[nt][r]);
    }
  }
}

// Fused: h = relu(dinv*(gather-sum + self) + bias); xws_next = bf16(dinv*(h@W)).
// G = F/8 lanes per node. Edge segments padded to mult-of-8 -> single pure
// 8-deep unrolled loop, no tails, no branches.
template <int F, int FOUT>
static __global__ __launch_bounds__(256) void agg_gemm_kernel(
    const unsigned short* __restrict__ xws, const int* __restrict__ row_start,
    const int* __restrict__ row_end, const int* __restrict__ csr_src,
    const float* __restrict__ dinv, const float* __restrict__ bias,
    const float* __restrict__ W, unsigned short* __restrict__ xws_next, int n) {
  constexpr int G = F / 8;
  constexpr int NODES = 256 / G;
  constexpr int OUTS = FOUT / G;  // epilogue outputs per thread (=4)
  __shared__ float ws[F * FOUT];
  __shared__ float hs[NODES][F + 1];
  const int t = threadIdx.x;
  for (int i = t; i < F * FOUT / 4; i += 256)
    *(float4*)&ws[i * 4] = *(const float4*)&W[i * 4];
  const int nl = t / G;
  const int c = t - nl * G;
  const int node = blockIdx.x * NODES + nl;
  const bool valid = node < n;
  const int safe = valid ? node : 0;
  const int start = valid ? row_start[safe] : 0;
  const int end = valid ? row_end[safe] : 0;
  float acc[8] = {0.f, 0.f, 0.f, 0.f, 0.f, 0.f, 0.f, 0.f};
  for (int e = start; e < end; e += 8) {  // end-start is a multiple of 8
    int4 sa = *(const int4*)&csr_src[e];
    int4 sb = *(const int4*)&csr_src[e + 4];
    ushort8v v0 = *(const ushort8v*)&xws[(size_t)sa.x * F + c * 8];
    ushort8v v1 = *(const ushort8v*)&xws[(size_t)sa.y * F + c * 8];
    ushort8v v2 = *(const ushort8v*)&xws[(size_t)sa.z * F + c * 8];
    ushort8v v3 = *(const ushort8v*)&xws[(size_t)sa.w * F + c * 8];
    ushort8v v4 = *(const ushort8v*)&xws[(size_t)sb.x * F + c * 8];
    ushort8v v5 = *(const ushort8v*)&xws[(size_t)sb.y * F + c * 8];
    ushort8v v6 = *(const ushort8v*)&xws[(size_t)sb.z * F + c * 8];
    ushort8v v7 = *(const ushort8v*)&xws[(size_t)sb.w * F + c * 8];
#pragma unroll
    for (int j = 0; j < 8; ++j)
      acc[j] += ((bf2f(v0[j]) + bf2f(v1[j])) + (bf2f(v2[j]) + bf2f(v3[j]))) +
                ((bf2f(v4[j]) + bf2f(v5[j])) + (bf2f(v6[j]) + bf2f(v7[j])));
  }
  ushort8v sv = *(const ushort8v*)&xws[(size_t)safe * F + c * 8];
  const float dv = dinv[safe];
#pragma unroll
  for (int j = 0; j < 8; ++j)
    hs[nl][c * 8 + j] = fmaxf(dv * (acc[j] + bf2f(sv[j])) + bias[c * 8 + j], 0.f);
  __syncthreads();
  float o[OUTS];
#pragma unroll
  for (int j = 0; j < OUTS; ++j) o[j] = 0.f;
#pragma unroll 4
  for (int k = 0; k < F; ++k) {
    float hv = hs[nl][k];
#pragma unroll
    for (int j = 0; j < OUTS; ++j) o[j] += hv * ws[k * FOUT + c * OUTS + j];
  }
  if (valid) {
    ushort4v r = {f2bf(dv * o[0]), f2bf(dv * o[1]), f2bf(dv * o[2]),
                  f2bf(dv * o[3])};
    *(ushort4v*)&xws_next[(size_t)node * FOUT + c * OUTS] = r;
  }
}

// Final layer: h = relu(dinv*(gather+self)+b3); out[n] = h . w_out + b_out.
static __global__ __launch_bounds__(256) void agg_head_kernel(
    const unsigned short* __restrict__ xws, const int* __restrict__ row_start,
    const int* __restrict__ row_end, const int* __restrict__ csr_src,
    const float* __restrict__ dinv, const float* __restrict__ bias,
    float* __restrict__ out, const float* __restrict__ w_out,
    const float* __restrict__ b_out, int n) {
  constexpr int F = 16, NODES = 128;
  const int t = threadIdx.x;
  const int nl = t >> 1;
  const int c = t & 1;
  const int node = blockIdx.x * NODES + nl;
  if (node >= n) return;
  const int start = row_start[node], end = row_end[node];
  float acc[8] = {0.f, 0.f, 0.f, 0.f, 0.f, 0.f, 0.f, 0.f};
  for (int e = start; e < end; e += 8) {
    int4 sa = *(const int4*)&csr_src[e];
    int4 sb = *(const int4*)&csr_src[e + 4];
    ushort8v v0 = *(const ushort8v*)&xws[(size_t)sa.x * F + c * 8];
    ushort8v v1 = *(const ushort8v*)&xws[(size_t)sa.y * F + c * 8];
    ushort8v v2 = *(const ushort8v*)&xws[(size_t)sa.z * F + c * 8];
    ushort8v v3 = *(const ushort8v*)&xws[(size_t)sa.w * F + c * 8];
    ushort8v v4 = *(const ushort8v*)&xws[(size_t)sb.x * F + c * 8];
    ushort8v v5 = *(const ushort8v*)&xws[(size_t)sb.y * F + c * 8];
    ushort8v v6 = *(const ushort8v*)&xws[(size_t)sb.z * F + c * 8];
    ushort8v v7 = *(const ushort8v*)&xws[(size_t)sb.w * F + c * 8];
#pragma unroll
    for (int j = 0; j < 8; ++j)
      acc[j] += ((bf2f(v0[j]) + bf2f(v1[j])) + (bf2f(v2[j]) + bf2f(v3[j]))) +
                ((bf2f(v4[j]) + bf2f(v5[j])) + (bf2f(v6[j]) + bf2f(v7[j])));
  }
  ushort8v sv = *(const ushort8v*)&xws[(size_t)node * F + c * 8];
  float dv = dinv[node];
  float p = 0.f;
#pragma unroll
  for (int j = 0; j < 8; ++j) {
    float r = fmaxf(dv * (acc[j] + bf2f(sv[j])) + bias[c * 8 + j], 0.f);
    p += r * w_out[c * 8 + j];
  }
  p += __shfl_xor(p, 1);  // combine the two feat-groups
  if (c == 0) out[node] = p + b_out[0];
}

extern "C" void kernel_launch(void* const* d_in, const int* in_sizes, int n_in,
                              void* d_out, int out_size, void* d_ws, size_t ws_size,
                              hipStream_t stream) {
  const float* x     = (const float*)d_in[0];
  const int*   ei    = (const int*)d_in[1];
  const float* w1    = (const float*)d_in[2];
  const float* b1    = (const float*)d_in[3];
  const float* w2    = (const float*)d_in[4];
  const float* b2    = (const float*)d_in[5];
  const float* w3    = (const float*)d_in[6];
  const float* b3    = (const float*)d_in[7];
  const float* w_out = (const float*)d_in[8];
  const float* b_out = (const float*)d_in[9];
  float* out = (float*)d_out;

  const int n = in_sizes[0] / 128;   // 100000
  const int E = in_sizes[1] / 2;     // 3200000
  const int* srcA = ei;
  const int* dstA = ei + E;

  char* p = (char*)d_ws;
  auto carve = [&](size_t bytes) {
    void* r = (void*)p;
    p += (bytes + 255) & ~(size_t)255;
    return r;
  };
  const size_t partBytes = (size_t)NBUCK * CAP * 4;  // 16.06 MB
  int*   csr_src    = (int*)carve(partBytes);
  int*   bucket_cnt = (int*)carve((size_t)NBUCK * 4);
  int*   row_start  = (int*)carve((size_t)n * 4);
  int*   row_end    = (int*)carve((size_t)n * 4);
  float* dinv       = (float*)carve((size_t)n * 4);
  // part (dead after bucket2csr) aliases xws1 ((n+1)*64*2 = 12.8MB < partBytes)
  char*  regionP    = (char*)carve(partBytes);
  int*   part       = (int*)regionP;
  unsigned short* xws1 = (unsigned short*)regionP;
  unsigned short* xws2 = (unsigned short*)carve((size_t)(n + 1) * 32 * 2);
  unsigned short* xws3 = (unsigned short*)carve((size_t)(n + 1) * 16 * 2);

  hipMemsetAsync(bucket_cnt, 0, (size_t)NBUCK * 4, stream);
  partition_kernel<<<(E + 8191) / 8192, 256, 0, stream>>>(srcA, dstA, bucket_cnt,
                                                          part, E);
  bucket2csr_kernel<<<NBUCK, 256, 0, stream>>>(bucket_cnt, part, csr_src,
                                               row_start, row_end, dinv, n);
  // zero-row sentinels (row n of each gather table)
  hipMemsetAsync(xws1 + (size_t)n * 64, 0, 64 * 2, stream);
  hipMemsetAsync(xws2 + (size_t)n * 32, 0, 32 * 2, stream);
  hipMemsetAsync(xws3 + (size_t)n * 16, 0, 16 * 2, stream);

  // layer 1 GEMM (fp16 MFMA): xws1 = dinv .* (x @ w1)   [128 -> 64]
  gemm1_mfma_kernel<<<(n + 63) / 64, 256, 0, stream>>>(x, w1, dinv, xws1, n);
  // layer 1 agg + layer 2 GEMM fused: h1 -> xws2   [agg 64, gemm 64->32]
  agg_gemm_kernel<64, 32><<<(n + 31) / 32, 256, 0, stream>>>(
      xws1, row_start, row_end, csr_src, dinv, b1, w2, xws2, n);
  // layer 2 agg + layer 3 GEMM fused: h2 -> xws3   [agg 32, gemm 32->16]
  agg_gemm_kernel<32, 16><<<(n + 63) / 64, 256, 0, stream>>>(
      xws2, row_start, row_end, csr_src, dinv, b2, w3, xws3, n);
  // layer 3 agg + head fused
  agg_head_kernel<<<(n + 127) / 128, 256, 0, stream>>>(
      xws3, row_start, row_end, csr_src, dinv, b3, out, w_out, b_out, n);
}

// Round 7
// 228.881 us; speedup vs baseline: 3.3400x; 1.0285x over previous
//
#include <hip/hip_runtime.h>
#include <hip/hip_bf16.h>

// ---------------------------------------------------------------------------
// GCN forward: 3x GCNConv(relu) + linear head.
// R6->R7: CSR-build overhaul. partition: single-pass (edges held in regs,
// read once), 2048 edges/block -> 1563 blocks (R6: 391 blocks, occ 14%,
// latency-bound at 56.7us). Buckets refined to 391 x 256 nodes -> bucket2csr
// gets 2x grid and int4 packed loads. Agg/GEMM pipeline unchanged from R6.
// ---------------------------------------------------------------------------

#define NBUCK 391    // ceil(100000 / 256)
#define BSHIFT 8     // 256 nodes per bucket
#define CAP 10240    // per-bucket capacity; padded mean ~9.1K
#define EPB 2048     // edges per partition block

typedef __attribute__((ext_vector_type(4))) unsigned short ushort4v;
typedef __attribute__((ext_vector_type(8))) unsigned short ushort8v;
typedef __attribute__((ext_vector_type(8))) _Float16 half8;
typedef __attribute__((ext_vector_type(4))) float f32x4;

__device__ __forceinline__ float bf2f(unsigned short u) {
  union { unsigned int i; float f; } v;
  v.i = ((unsigned int)u) << 16;
  return v.f;
}
__device__ __forceinline__ unsigned short f2bf(float f) {
  union { float f; unsigned int i; } v;
  v.f = f;
  unsigned int r = v.i + 0x7FFF + ((v.i >> 16) & 1);  // RNE
  return (unsigned short)(r >> 16);
}

// Single-pass partition: 8 edges/thread held in registers.
// packed value = ((dst&255)<<17) | src   (src < 2^17).
static __global__ __launch_bounds__(256) void partition_kernel(
    const int* __restrict__ src, const int* __restrict__ dst,
    int* __restrict__ bucket_cnt, int* __restrict__ part, int E) {
  __shared__ int hist[NBUCK];
  __shared__ int bbase[NBUCK];
  const int t = threadIdx.x;
  for (int j = t; j < NBUCK; j += 256) hist[j] = 0;
  __syncthreads();
  const int base = blockIdx.x * EPB + t * 8;
  int ss[8], dd[8];
  if (base + 8 <= E) {
    int4 s0 = *(const int4*)&src[base], s1 = *(const int4*)&src[base + 4];
    int4 d0 = *(const int4*)&dst[base], d1 = *(const int4*)&dst[base + 4];
    ss[0] = s0.x; ss[1] = s0.y; ss[2] = s0.z; ss[3] = s0.w;
    ss[4] = s1.x; ss[5] = s1.y; ss[6] = s1.z; ss[7] = s1.w;
    dd[0] = d0.x; dd[1] = d0.y; dd[2] = d0.z; dd[3] = d0.w;
    dd[4] = d1.x; dd[5] = d1.y; dd[6] = d1.z; dd[7] = d1.w;
  } else {
#pragma unroll
    for (int j = 0; j < 8; ++j) {
      int i = base + j;
      ss[j] = (i < E) ? src[i] : -1;
      dd[j] = (i < E) ? dst[i] : 0;
    }
  }
#pragma unroll
  for (int j = 0; j < 8; ++j)
    if (ss[j] >= 0) atomicAdd(&hist[dd[j] >> BSHIFT], 1);
  __syncthreads();
  for (int j = t; j < NBUCK; j += 256) {
    int h = hist[j];
    bbase[j] = h ? atomicAdd(&bucket_cnt[j], h) : 0;
    hist[j] = 0;  // reuse as cursor
  }
  __syncthreads();
#pragma unroll
  for (int j = 0; j < 8; ++j) {
    if (ss[j] >= 0) {
      int b = dd[j] >> BSHIFT;
      int r = bbase[b] + atomicAdd(&hist[b], 1);
      if (r < CAP) part[(size_t)b * CAP + r] = ((dd[j] & 255) << 17) | ss[j];
    }
  }
}

// One block per bucket (256 nodes, 1 node/thread): histogram (int4 packed
// loads) -> scan over padded lengths -> row_start/row_end/dinv -> counting-
// sort scatter -> sentinel pad fill. Scatter window 40KB, L2-resident.
static __global__ __launch_bounds__(256) void bucket2csr_kernel(
    const int* __restrict__ bucket_cnt, const int* __restrict__ part,
    int* __restrict__ csr_src, int* __restrict__ row_start,
    int* __restrict__ row_end, float* __restrict__ dinv, int n) {
  __shared__ int hist[256];
  __shared__ int cursor[256];
  __shared__ int sdata[256];
  const int b = blockIdx.x;
  const int t = threadIdx.x;
  const int base = b * CAP;
  int cnt = bucket_cnt[b];
  if (cnt > CAP) cnt = CAP;
  hist[t] = 0;
  __syncthreads();
  int i = t * 4;
  for (; i + 4 <= cnt; i += 1024) {
    int4 v = *(const int4*)&part[base + i];
    atomicAdd(&hist[v.x >> 17], 1);
    atomicAdd(&hist[v.y >> 17], 1);
    atomicAdd(&hist[v.z >> 17], 1);
    atomicAdd(&hist[v.w >> 17], 1);
  }
  for (int k = i; k < cnt && k < i + 4; ++k)
    atomicAdd(&hist[part[base + k] >> 17], 1);
  __syncthreads();
  const int v = hist[t];
  const int pd = (v + 7) & ~7;  // padded length
  sdata[t] = pd;
  __syncthreads();
  int incl = pd;
  for (int off = 1; off < 256; off <<= 1) {
    int y = (t >= off) ? sdata[t - off] : 0;
    __syncthreads();
    incl += y;
    sdata[t] = incl;
    __syncthreads();
  }
  const int excl = incl - pd;
  cursor[t] = excl;
  const int node = b * 256 + t;
  if (node < n) {
    row_start[node] = base + excl;
    row_end[node] = base + excl + pd;
    dinv[node] = rsqrtf((float)(v + 1));  // true degree +1 self loop
  }
  __syncthreads();
  i = t * 4;
  for (; i + 4 <= cnt; i += 1024) {
    int4 pv = *(const int4*)&part[base + i];
    int p0 = atomicAdd(&cursor[pv.x >> 17], 1);
    csr_src[base + p0] = pv.x & 0x1FFFF;
    int p1 = atomicAdd(&cursor[pv.y >> 17], 1);
    csr_src[base + p1] = pv.y & 0x1FFFF;
    int p2 = atomicAdd(&cursor[pv.z >> 17], 1);
    csr_src[base + p2] = pv.z & 0x1FFFF;
    int p3 = atomicAdd(&cursor[pv.w >> 17], 1);
    csr_src[base + p3] = pv.w & 0x1FFFF;
  }
  for (int k = i; k < cnt && k < i + 4; ++k) {
    int pv = part[base + k];
    int pos = atomicAdd(&cursor[pv >> 17], 1);
    csr_src[base + pos] = pv & 0x1FFFF;
  }
  // sentinel pad fill (slots [v, pd) of this thread's node; disjoint)
  for (int k = v; k < pd; ++k) csr_src[base + excl + k] = n;
}

// Layer-1 GEMM via fp16 MFMA: xws1(bf16) = dinv .* (x @ w1), fp32 accum.
// Block = 64 nodes x 64 outs, 4 waves. LDS XOR-swizzled: byte ^= (row&7)<<4.
static __global__ __launch_bounds__(256) void gemm1_mfma_kernel(
    const float* __restrict__ x, const float* __restrict__ w1,
    const float* __restrict__ dinv, unsigned short* __restrict__ xws, int n) {
  __shared__ _Float16 xa[64 * 128];  // x tile [node][k]
  __shared__ _Float16 wt[64 * 128];  // w1^T   [o][k]
  const int t = threadIdx.x;
  const int base = blockIdx.x * 64;
  for (int i = t; i < 64 * 16; i += 256) {
    int r = i >> 4, k8 = i & 15;
    int node = base + r;
    float4 a = {0.f, 0.f, 0.f, 0.f}, b = {0.f, 0.f, 0.f, 0.f};
    if (node < n) {
      a = *(const float4*)&x[(size_t)node * 128 + k8 * 8];
      b = *(const float4*)&x[(size_t)node * 128 + k8 * 8 + 4];
    }
    half8 h = {(_Float16)a.x, (_Float16)a.y, (_Float16)a.z, (_Float16)a.w,
               (_Float16)b.x, (_Float16)b.y, (_Float16)b.z, (_Float16)b.w};
    int byte = (r * 256 + k8 * 16) ^ ((r & 7) << 4);
    *(half8*)((char*)xa + byte) = h;
  }
  for (int i = t; i < 128 * 64; i += 256) {
    int k = i >> 6, o = i & 63;
    _Float16 v = (_Float16)w1[i];
    int byte = (o * 256 + k * 2) ^ ((o & 7) << 4);
    *(_Float16*)((char*)wt + byte) = v;
  }
  __syncthreads();
  const int wv = t >> 6;
  const int lane = t & 63;
  const int m = lane & 15;
  const int kg = lane >> 4;
  const int arow = wv * 16 + m;
  f32x4 acc[4] = {{0.f, 0.f, 0.f, 0.f}, {0.f, 0.f, 0.f, 0.f},
                  {0.f, 0.f, 0.f, 0.f}, {0.f, 0.f, 0.f, 0.f}};
#pragma unroll
  for (int ks = 0; ks < 4; ++ks) {
    int k0 = ks * 32 + kg * 8;
    int abyte = (arow * 256 + k0 * 2) ^ ((arow & 7) << 4);
    half8 af = *(const half8*)((const char*)xa + abyte);
#pragma unroll
    for (int nt = 0; nt < 4; ++nt) {
      int o = nt * 16 + m;
      int bbyte = (o * 256 + k0 * 2) ^ ((o & 7) << 4);
      half8 bf = *(const half8*)((const char*)wt + bbyte);
      acc[nt] = __builtin_amdgcn_mfma_f32_16x16x32_f16(af, bf, acc[nt], 0, 0, 0);
    }
  }
#pragma unroll
  for (int r = 0; r < 4; ++r) {
    int node = base + wv * 16 + kg * 4 + r;
    if (node < n) {
      float dv = dinv[node];
#pragma unroll
      for (int nt = 0; nt < 4; ++nt)
        xws[(size_t)node * 64 + nt * 16 + m] = f2bf(dv * acc[nt][r]);
    }
  }
}

// Fused: h = relu(dinv*(gather-sum + self) + bias); xws_next = bf16(dinv*(h@W)).
// G = F/8 lanes per node. Edge segments padded to mult-of-8 -> single pure
// 8-deep unrolled loop, no tails, no branches.
template <int F, int FOUT>
static __global__ __launch_bounds__(256) void agg_gemm_kernel(
    const unsigned short* __restrict__ xws, const int* __restrict__ row_start,
    const int* __restrict__ row_end, const int* __restrict__ csr_src,
    const float* __restrict__ dinv, const float* __restrict__ bias,
    const float* __restrict__ W, unsigned short* __restrict__ xws_next, int n) {
  constexpr int G = F / 8;
  constexpr int NODES = 256 / G;
  constexpr int OUTS = FOUT / G;  // epilogue outputs per thread (=4)
  __shared__ float ws[F * FOUT];
  __shared__ float hs[NODES][F + 1];
  const int t = threadIdx.x;
  for (int i = t; i < F * FOUT / 4; i += 256)
    *(float4*)&ws[i * 4] = *(const float4*)&W[i * 4];
  const int nl = t / G;
  const int c = t - nl * G;
  const int node = blockIdx.x * NODES + nl;
  const bool valid = node < n;
  const int safe = valid ? node : 0;
  const int start = valid ? row_start[safe] : 0;
  const int end = valid ? row_end[safe] : 0;
  float acc[8] = {0.f, 0.f, 0.f, 0.f, 0.f, 0.f, 0.f, 0.f};
  for (int e = start; e < end; e += 8) {  // end-start is a multiple of 8
    int4 sa = *(const int4*)&csr_src[e];
    int4 sb = *(const int4*)&csr_src[e + 4];
    ushort8v v0 = *(const ushort8v*)&xws[(size_t)sa.x * F + c * 8];
    ushort8v v1 = *(const ushort8v*)&xws[(size_t)sa.y * F + c * 8];
    ushort8v v2 = *(const ushort8v*)&xws[(size_t)sa.z * F + c * 8];
    ushort8v v3 = *(const ushort8v*)&xws[(size_t)sa.w * F + c * 8];
    ushort8v v4 = *(const ushort8v*)&xws[(size_t)sb.x * F + c * 8];
    ushort8v v5 = *(const ushort8v*)&xws[(size_t)sb.y * F + c * 8];
    ushort8v v6 = *(const ushort8v*)&xws[(size_t)sb.z * F + c * 8];
    ushort8v v7 = *(const ushort8v*)&xws[(size_t)sb.w * F + c * 8];
#pragma unroll
    for (int j = 0; j < 8; ++j)
      acc[j] += ((bf2f(v0[j]) + bf2f(v1[j])) + (bf2f(v2[j]) + bf2f(v3[j]))) +
                ((bf2f(v4[j]) + bf2f(v5[j])) + (bf2f(v6[j]) + bf2f(v7[j])));
  }
  ushort8v sv = *(const ushort8v*)&xws[(size_t)safe * F + c * 8];
  const float dv = dinv[safe];
#pragma unroll
  for (int j = 0; j < 8; ++j)
    hs[nl][c * 8 + j] = fmaxf(dv * (acc[j] + bf2f(sv[j])) + bias[c * 8 + j], 0.f);
  __syncthreads();
  float o[OUTS];
#pragma unroll
  for (int j = 0; j < OUTS; ++j) o[j] = 0.f;
#pragma unroll 4
  for (int k = 0; k < F; ++k) {
    float hv = hs[nl][k];
#pragma unroll
    for (int j = 0; j < OUTS; ++j) o[j] += hv * ws[k * FOUT + c * OUTS + j];
  }
  if (valid) {
    ushort4v r = {f2bf(dv * o[0]), f2bf(dv * o[1]), f2bf(dv * o[2]),
                  f2bf(dv * o[3])};
    *(ushort4v*)&xws_next[(size_t)node * FOUT + c * OUTS] = r;
  }
}

// Final layer: h = relu(dinv*(gather+self)+b3); out[n] = h . w_out + b_out.
static __global__ __launch_bounds__(256) void agg_head_kernel(
    const unsigned short* __restrict__ xws, const int* __restrict__ row_start,
    const int* __restrict__ row_end, const int* __restrict__ csr_src,
    const float* __restrict__ dinv, const float* __restrict__ bias,
    float* __restrict__ out, const float* __restrict__ w_out,
    const float* __restrict__ b_out, int n) {
  constexpr int F = 16, NODES = 128;
  const int t = threadIdx.x;
  const int nl = t >> 1;
  const int c = t & 1;
  const int node = blockIdx.x * NODES + nl;
  if (node >= n) return;
  const int start = row_start[node], end = row_end[node];
  float acc[8] = {0.f, 0.f, 0.f, 0.f, 0.f, 0.f, 0.f, 0.f};
  for (int e = start; e < end; e += 8) {
    int4 sa = *(const int4*)&csr_src[e];
    int4 sb = *(const int4*)&csr_src[e + 4];
    ushort8v v0 = *(const ushort8v*)&xws[(size_t)sa.x * F + c * 8];
    ushort8v v1 = *(const ushort8v*)&xws[(size_t)sa.y * F + c * 8];
    ushort8v v2 = *(const ushort8v*)&xws[(size_t)sa.z * F + c * 8];
    ushort8v v3 = *(const ushort8v*)&xws[(size_t)sa.w * F + c * 8];
    ushort8v v4 = *(const ushort8v*)&xws[(size_t)sb.x * F + c * 8];
    ushort8v v5 = *(const ushort8v*)&xws[(size_t)sb.y * F + c * 8];
    ushort8v v6 = *(const ushort8v*)&xws[(size_t)sb.z * F + c * 8];
    ushort8v v7 = *(const ushort8v*)&xws[(size_t)sb.w * F + c * 8];
#pragma unroll
    for (int j = 0; j < 8; ++j)
      acc[j] += ((bf2f(v0[j]) + bf2f(v1[j])) + (bf2f(v2[j]) + bf2f(v3[j]))) +
                ((bf2f(v4[j]) + bf2f(v5[j])) + (bf2f(v6[j]) + bf2f(v7[j])));
  }
  ushort8v sv = *(const ushort8v*)&xws[(size_t)node * F + c * 8];
  float dv = dinv[node];
  float p = 0.f;
#pragma unroll
  for (int j = 0; j < 8; ++j) {
    float r = fmaxf(dv * (acc[j] + bf2f(sv[j])) + bias[c * 8 + j], 0.f);
    p += r * w_out[c * 8 + j];
  }
  p += __shfl_xor(p, 1);  // combine the two feat-groups
  if (c == 0) out[node] = p + b_out[0];
}

extern "C" void kernel_launch(void* const* d_in, const int* in_sizes, int n_in,
                              void* d_out, int out_size, void* d_ws, size_t ws_size,
                              hipStream_t stream) {
  const float* x     = (const float*)d_in[0];
  const int*   ei    = (const int*)d_in[1];
  const float* w1    = (const float*)d_in[2];
  const float* b1    = (const float*)d_in[3];
  const float* w2    = (const float*)d_in[4];
  const float* b2    = (const float*)d_in[5];
  const float* w3    = (const float*)d_in[6];
  const float* b3    = (const float*)d_in[7];
  const float* w_out = (const float*)d_in[8];
  const float* b_out = (const float*)d_in[9];
  float* out = (float*)d_out;

  const int n = in_sizes[0] / 128;   // 100000
  const int E = in_sizes[1] / 2;     // 3200000
  const int* srcA = ei;
  const int* dstA = ei + E;

  char* p = (char*)d_ws;
  auto carve = [&](size_t bytes) {
    void* r = (void*)p;
    p += (bytes + 255) & ~(size_t)255;
    return r;
  };
  const size_t partBytes = (size_t)NBUCK * CAP * 4;  // 16.0 MB
  int*   csr_src    = (int*)carve(partBytes);
  int*   bucket_cnt = (int*)carve((size_t)NBUCK * 4);
  int*   row_start  = (int*)carve((size_t)n * 4);
  int*   row_end    = (int*)carve((size_t)n * 4);
  float* dinv       = (float*)carve((size_t)n * 4);
  // part (dead after bucket2csr) aliases xws1 ((n+1)*64*2 = 12.8MB < 16MB)
  char*  regionP    = (char*)carve(partBytes);
  int*   part       = (int*)regionP;
  unsigned short* xws1 = (unsigned short*)regionP;
  unsigned short* xws2 = (unsigned short*)carve((size_t)(n + 1) * 32 * 2);
  unsigned short* xws3 = (unsigned short*)carve((size_t)(n + 1) * 16 * 2);

  hipMemsetAsync(bucket_cnt, 0, (size_t)NBUCK * 4, stream);
  partition_kernel<<<(E + EPB - 1) / EPB, 256, 0, stream>>>(srcA, dstA,
                                                            bucket_cnt, part, E);
  bucket2csr_kernel<<<NBUCK, 256, 0, stream>>>(bucket_cnt, part, csr_src,
                                               row_start, row_end, dinv, n);
  // zero-row sentinels (row n of each gather table)
  hipMemsetAsync(xws1 + (size_t)n * 64, 0, 64 * 2, stream);
  hipMemsetAsync(xws2 + (size_t)n * 32, 0, 32 * 2, stream);
  hipMemsetAsync(xws3 + (size_t)n * 16, 0, 16 * 2, stream);

  // layer 1 GEMM (fp16 MFMA): xws1 = dinv .* (x @ w1)   [128 -> 64]
  gemm1_mfma_kernel<<<(n + 63) / 64, 256, 0, stream>>>(x, w1, dinv, xws1, n);
  // layer 1 agg + layer 2 GEMM fused: h1 -> xws2   [agg 64, gemm 64->32]
  agg_gemm_kernel<64, 32><<<(n + 31) / 32, 256, 0, stream>>>(
      xws1, row_start, row_end, csr_src, dinv, b1, w2, xws2, n);
  // layer 2 agg + layer 3 GEMM fused: h2 -> xws3   [agg 32, gemm 32->16]
  agg_gemm_kernel<32, 16><<<(n + 63) / 64, 256, 0, stream>>>(
      xws2, row_start, row_end, csr_src, dinv, b2, w3, xws3, n);
  // layer 3 agg + head fused
  agg_head_kernel<<<(n + 127) / 128, 256, 0, stream>>>(
      xws3, row_start, row_end, csr_src, dinv, b3, out, w_out, b_out, n);
}

// Round 8
// 215.514 us; speedup vs baseline: 3.5471x; 1.0620x over previous
//
#include <hip/hip_runtime.h>
#include <hip/hip_bf16.h>

// ---------------------------------------------------------------------------
// GCN forward: 3x GCNConv(relu) + linear head.
// R7->R8: (a) agg kernels use dual sub-groups per node on alternating 8-edge
// chunks -> 16 gathers in flight per node, no extra padding, every iteration
// fully unrolled (R5's stride-2 tail mistake avoided); (b) bucket2csr stages
// the bucket in LDS -> part read once. Gather tables bf16, accum fp32.
// ---------------------------------------------------------------------------

#define NBUCK 391    // ceil(100000 / 256)
#define BSHIFT 8     // 256 nodes per bucket
#define CAP 10240    // per-bucket capacity; padded mean ~9.1K
#define EPB 2048     // edges per partition block

typedef __attribute__((ext_vector_type(2))) unsigned short ushort2v;
typedef __attribute__((ext_vector_type(4))) unsigned short ushort4v;
typedef __attribute__((ext_vector_type(8))) unsigned short ushort8v;
typedef __attribute__((ext_vector_type(8))) _Float16 half8;
typedef __attribute__((ext_vector_type(4))) float f32x4;

__device__ __forceinline__ float bf2f(unsigned short u) {
  union { unsigned int i; float f; } v;
  v.i = ((unsigned int)u) << 16;
  return v.f;
}
__device__ __forceinline__ unsigned short f2bf(float f) {
  union { float f; unsigned int i; } v;
  v.f = f;
  unsigned int r = v.i + 0x7FFF + ((v.i >> 16) & 1);  // RNE
  return (unsigned short)(r >> 16);
}

// Single-pass partition: 8 edges/thread held in registers.
// packed value = ((dst&255)<<17) | src   (src < 2^17).
static __global__ __launch_bounds__(256) void partition_kernel(
    const int* __restrict__ src, const int* __restrict__ dst,
    int* __restrict__ bucket_cnt, int* __restrict__ part, int E) {
  __shared__ int hist[NBUCK];
  __shared__ int bbase[NBUCK];
  const int t = threadIdx.x;
  for (int j = t; j < NBUCK; j += 256) hist[j] = 0;
  __syncthreads();
  const int base = blockIdx.x * EPB + t * 8;
  int ss[8], dd[8];
  if (base + 8 <= E) {
    int4 s0 = *(const int4*)&src[base], s1 = *(const int4*)&src[base + 4];
    int4 d0 = *(const int4*)&dst[base], d1 = *(const int4*)&dst[base + 4];
    ss[0] = s0.x; ss[1] = s0.y; ss[2] = s0.z; ss[3] = s0.w;
    ss[4] = s1.x; ss[5] = s1.y; ss[6] = s1.z; ss[7] = s1.w;
    dd[0] = d0.x; dd[1] = d0.y; dd[2] = d0.z; dd[3] = d0.w;
    dd[4] = d1.x; dd[5] = d1.y; dd[6] = d1.z; dd[7] = d1.w;
  } else {
#pragma unroll
    for (int j = 0; j < 8; ++j) {
      int i = base + j;
      ss[j] = (i < E) ? src[i] : -1;
      dd[j] = (i < E) ? dst[i] : 0;
    }
  }
#pragma unroll
  for (int j = 0; j < 8; ++j)
    if (ss[j] >= 0) atomicAdd(&hist[dd[j] >> BSHIFT], 1);
  __syncthreads();
  for (int j = t; j < NBUCK; j += 256) {
    int h = hist[j];
    bbase[j] = h ? atomicAdd(&bucket_cnt[j], h) : 0;
    hist[j] = 0;  // reuse as cursor
  }
  __syncthreads();
#pragma unroll
  for (int j = 0; j < 8; ++j) {
    if (ss[j] >= 0) {
      int b = dd[j] >> BSHIFT;
      int r = bbase[b] + atomicAdd(&hist[b], 1);
      if (r < CAP) part[(size_t)b * CAP + r] = ((dd[j] & 255) << 17) | ss[j];
    }
  }
}

// One block per bucket (256 nodes, 1 node/thread). Bucket staged into LDS
// during the histogram pass (part read ONCE); scan over padded lengths ->
// row_start/row_end/dinv -> counting-sort scatter from LDS -> sentinel pads.
static __global__ __launch_bounds__(256) void bucket2csr_kernel(
    const int* __restrict__ bucket_cnt, const int* __restrict__ part,
    int* __restrict__ csr_src, int* __restrict__ row_start,
    int* __restrict__ row_end, float* __restrict__ dinv, int n) {
  __shared__ int plds[CAP];
  __shared__ int hist[256];
  __shared__ int cursor[256];
  __shared__ int sdata[256];
  const int b = blockIdx.x;
  const int t = threadIdx.x;
  const int base = b * CAP;
  int cnt = bucket_cnt[b];
  if (cnt > CAP) cnt = CAP;
  hist[t] = 0;
  __syncthreads();
  int i = t * 4;
  for (; i + 4 <= cnt; i += 1024) {
    int4 v = *(const int4*)&part[base + i];
    *(int4*)&plds[i] = v;
    atomicAdd(&hist[v.x >> 17], 1);
    atomicAdd(&hist[v.y >> 17], 1);
    atomicAdd(&hist[v.z >> 17], 1);
    atomicAdd(&hist[v.w >> 17], 1);
  }
  for (int k = i; k < cnt && k < i + 4; ++k) {
    int pv = part[base + k];
    plds[k] = pv;
    atomicAdd(&hist[pv >> 17], 1);
  }
  __syncthreads();
  const int v = hist[t];
  const int pd = (v + 7) & ~7;  // padded length
  sdata[t] = pd;
  __syncthreads();
  int incl = pd;
  for (int off = 1; off < 256; off <<= 1) {
    int y = (t >= off) ? sdata[t - off] : 0;
    __syncthreads();
    incl += y;
    sdata[t] = incl;
    __syncthreads();
  }
  const int excl = incl - pd;
  cursor[t] = excl;
  const int node = b * 256 + t;
  if (node < n) {
    row_start[node] = base + excl;
    row_end[node] = base + excl + pd;
    dinv[node] = rsqrtf((float)(v + 1));  // true degree +1 self loop
  }
  __syncthreads();
  for (int k = t; k < cnt; k += 256) {
    int pv = plds[k];
    int pos = atomicAdd(&cursor[pv >> 17], 1);
    csr_src[base + pos] = pv & 0x1FFFF;
  }
  // sentinel pad fill (slots [v, pd) of this thread's node; disjoint)
  for (int k = v; k < pd; ++k) csr_src[base + excl + k] = n;
}

// Layer-1 GEMM via fp16 MFMA: xws1(bf16) = dinv .* (x @ w1), fp32 accum.
// Block = 64 nodes x 64 outs, 4 waves. LDS XOR-swizzled: byte ^= (row&7)<<4.
static __global__ __launch_bounds__(256) void gemm1_mfma_kernel(
    const float* __restrict__ x, const float* __restrict__ w1,
    const float* __restrict__ dinv, unsigned short* __restrict__ xws, int n) {
  __shared__ _Float16 xa[64 * 128];  // x tile [node][k]
  __shared__ _Float16 wt[64 * 128];  // w1^T   [o][k]
  const int t = threadIdx.x;
  const int base = blockIdx.x * 64;
  for (int i = t; i < 64 * 16; i += 256) {
    int r = i >> 4, k8 = i & 15;
    int node = base + r;
    float4 a = {0.f, 0.f, 0.f, 0.f}, b = {0.f, 0.f, 0.f, 0.f};
    if (node < n) {
      a = *(const float4*)&x[(size_t)node * 128 + k8 * 8];
      b = *(const float4*)&x[(size_t)node * 128 + k8 * 8 + 4];
    }
    half8 h = {(_Float16)a.x, (_Float16)a.y, (_Float16)a.z, (_Float16)a.w,
               (_Float16)b.x, (_Float16)b.y, (_Float16)b.z, (_Float16)b.w};
    int byte = (r * 256 + k8 * 16) ^ ((r & 7) << 4);
    *(half8*)((char*)xa + byte) = h;
  }
  for (int i = t; i < 128 * 64; i += 256) {
    int k = i >> 6, o = i & 63;
    _Float16 v = (_Float16)w1[i];
    int byte = (o * 256 + k * 2) ^ ((o & 7) << 4);
    *(_Float16*)((char*)wt + byte) = v;
  }
  __syncthreads();
  const int wv = t >> 6;
  const int lane = t & 63;
  const int m = lane & 15;
  const int kg = lane >> 4;
  const int arow = wv * 16 + m;
  f32x4 acc[4] = {{0.f, 0.f, 0.f, 0.f}, {0.f, 0.f, 0.f, 0.f},
                  {0.f, 0.f, 0.f, 0.f}, {0.f, 0.f, 0.f, 0.f}};
#pragma unroll
  for (int ks = 0; ks < 4; ++ks) {
    int k0 = ks * 32 + kg * 8;
    int abyte = (arow * 256 + k0 * 2) ^ ((arow & 7) << 4);
    half8 af = *(const half8*)((const char*)xa + abyte);
#pragma unroll
    for (int nt = 0; nt < 4; ++nt) {
      int o = nt * 16 + m;
      int bbyte = (o * 256 + k0 * 2) ^ ((o & 7) << 4);
      half8 bf = *(const half8*)((const char*)wt + bbyte);
      acc[nt] = __builtin_amdgcn_mfma_f32_16x16x32_f16(af, bf, acc[nt], 0, 0, 0);
    }
  }
#pragma unroll
  for (int r = 0; r < 4; ++r) {
    int node = base + wv * 16 + kg * 4 + r;
    if (node < n) {
      float dv = dinv[node];
#pragma unroll
      for (int nt = 0; nt < 4; ++nt)
        xws[(size_t)node * 64 + nt * 16 + m] = f2bf(dv * acc[nt][r]);
    }
  }
}

// Fused: h = relu(dinv*(gather-sum + self) + bias); xws_next = bf16(dinv*(h@W)).
// LPN = F/4 lanes per node = 2 sub-groups x GC(=F/8) feat-lanes. Sub s takes
// 8-edge chunks s, s+2, s+4, ... -> 16 gathers in flight, every iteration
// fully 8-unrolled (segments padded to mult-of-8). Combine via shfl_xor(GC).
template <int F, int FOUT>
static __global__ __launch_bounds__(256) void agg_gemm_kernel(
    const unsigned short* __restrict__ xws, const int* __restrict__ row_start,
    const int* __restrict__ row_end, const int* __restrict__ csr_src,
    const float* __restrict__ dinv, const float* __restrict__ bias,
    const float* __restrict__ W, unsigned short* __restrict__ xws_next, int n) {
  constexpr int GC = F / 8;        // feat-lanes per sub-group
  constexpr int LPN = F / 4;       // lanes per node
  constexpr int NODES = 256 / LPN;
  constexpr int OUTS = FOUT / LPN; // epilogue outputs per thread (=2)
  __shared__ float ws[F * FOUT];
  __shared__ float hs[NODES][F + 1];
  const int t = threadIdx.x;
  for (int i = t; i < F * FOUT / 4; i += 256)
    *(float4*)&ws[i * 4] = *(const float4*)&W[i * 4];
  const int nl = t / LPN;
  const int l = t % LPN;
  const int c = l % GC;
  const int sub = l / GC;
  const int node = blockIdx.x * NODES + nl;
  const bool valid = node < n;
  const int safe = valid ? node : 0;
  const int start = valid ? row_start[safe] : 0;
  const int end = valid ? row_end[safe] : 0;
  float acc[8] = {0.f, 0.f, 0.f, 0.f, 0.f, 0.f, 0.f, 0.f};
  for (int e = start + sub * 8; e < end; e += 16) {
    int4 sa = *(const int4*)&csr_src[e];
    int4 sb = *(const int4*)&csr_src[e + 4];
    ushort8v v0 = *(const ushort8v*)&xws[(size_t)sa.x * F + c * 8];
    ushort8v v1 = *(const ushort8v*)&xws[(size_t)sa.y * F + c * 8];
    ushort8v v2 = *(const ushort8v*)&xws[(size_t)sa.z * F + c * 8];
    ushort8v v3 = *(const ushort8v*)&xws[(size_t)sa.w * F + c * 8];
    ushort8v v4 = *(const ushort8v*)&xws[(size_t)sb.x * F + c * 8];
    ushort8v v5 = *(const ushort8v*)&xws[(size_t)sb.y * F + c * 8];
    ushort8v v6 = *(const ushort8v*)&xws[(size_t)sb.z * F + c * 8];
    ushort8v v7 = *(const ushort8v*)&xws[(size_t)sb.w * F + c * 8];
#pragma unroll
    for (int j = 0; j < 8; ++j)
      acc[j] += ((bf2f(v0[j]) + bf2f(v1[j])) + (bf2f(v2[j]) + bf2f(v3[j]))) +
                ((bf2f(v4[j]) + bf2f(v5[j])) + (bf2f(v6[j]) + bf2f(v7[j])));
  }
  // combine the two sub-groups (partner lane = l ^ GC, within the node)
#pragma unroll
  for (int j = 0; j < 8; ++j) acc[j] += __shfl_xor(acc[j], GC);
  const float dv = dinv[safe];
  if (sub == 0) {
    ushort8v sv = *(const ushort8v*)&xws[(size_t)safe * F + c * 8];
#pragma unroll
    for (int j = 0; j < 8; ++j)
      hs[nl][c * 8 + j] =
          fmaxf(dv * (acc[j] + bf2f(sv[j])) + bias[c * 8 + j], 0.f);
  }
  __syncthreads();
  // epilogue GEMM: LPN lanes x OUTS outputs per node
  float o[OUTS];
#pragma unroll
  for (int j = 0; j < OUTS; ++j) o[j] = 0.f;
#pragma unroll 4
  for (int k = 0; k < F; ++k) {
    float hv = hs[nl][k];
#pragma unroll
    for (int j = 0; j < OUTS; ++j) o[j] += hv * ws[k * FOUT + l * OUTS + j];
  }
  if (valid) {
    ushort2v r = {f2bf(dv * o[0]), f2bf(dv * o[1])};
    *(ushort2v*)&xws_next[(size_t)node * FOUT + l * OUTS] = r;
  }
}

// Final layer: h = relu(dinv*(gather+self)+b3); out[n] = h . w_out + b_out.
// 4 lanes/node = 2 subs x 2 feat-lanes; chunk-interleaved like agg_gemm.
static __global__ __launch_bounds__(256) void agg_head_kernel(
    const unsigned short* __restrict__ xws, const int* __restrict__ row_start,
    const int* __restrict__ row_end, const int* __restrict__ csr_src,
    const float* __restrict__ dinv, const float* __restrict__ bias,
    float* __restrict__ out, const float* __restrict__ w_out,
    const float* __restrict__ b_out, int n) {
  constexpr int F = 16, NODES = 64;
  const int t = threadIdx.x;
  const int nl = t >> 2;
  const int l = t & 3;
  const int c = l & 1;
  const int sub = l >> 1;
  const int node = blockIdx.x * NODES + nl;
  if (node >= n) return;
  const int start = row_start[node], end = row_end[node];
  float acc[8] = {0.f, 0.f, 0.f, 0.f, 0.f, 0.f, 0.f, 0.f};
  for (int e = start + sub * 8; e < end; e += 16) {
    int4 sa = *(const int4*)&csr_src[e];
    int4 sb = *(const int4*)&csr_src[e + 4];
    ushort8v v0 = *(const ushort8v*)&xws[(size_t)sa.x * F + c * 8];
    ushort8v v1 = *(const ushort8v*)&xws[(size_t)sa.y * F + c * 8];
    ushort8v v2 = *(const ushort8v*)&xws[(size_t)sa.z * F + c * 8];
    ushort8v v3 = *(const ushort8v*)&xws[(size_t)sa.w * F + c * 8];
    ushort8v v4 = *(const ushort8v*)&xws[(size_t)sb.x * F + c * 8];
    ushort8v v5 = *(const ushort8v*)&xws[(size_t)sb.y * F + c * 8];
    ushort8v v6 = *(const ushort8v*)&xws[(size_t)sb.z * F + c * 8];
    ushort8v v7 = *(const ushort8v*)&xws[(size_t)sb.w * F + c * 8];
#pragma unroll
    for (int j = 0; j < 8; ++j)
      acc[j] += ((bf2f(v0[j]) + bf2f(v1[j])) + (bf2f(v2[j]) + bf2f(v3[j]))) +
                ((bf2f(v4[j]) + bf2f(v5[j])) + (bf2f(v6[j]) + bf2f(v7[j])));
  }
#pragma unroll
  for (int j = 0; j < 8; ++j) acc[j] += __shfl_xor(acc[j], 2);
  ushort8v sv = *(const ushort8v*)&xws[(size_t)node * F + c * 8];
  float dv = dinv[node];
  float p = 0.f;
#pragma unroll
  for (int j = 0; j < 8; ++j) {
    float r = fmaxf(dv * (acc[j] + bf2f(sv[j])) + bias[c * 8 + j], 0.f);
    p += r * w_out[c * 8 + j];
  }
  p += __shfl_xor(p, 1);  // combine the two feat-lanes
  if (l == 0) out[node] = p + b_out[0];
}

extern "C" void kernel_launch(void* const* d_in, const int* in_sizes, int n_in,
                              void* d_out, int out_size, void* d_ws, size_t ws_size,
                              hipStream_t stream) {
  const float* x     = (const float*)d_in[0];
  const int*   ei    = (const int*)d_in[1];
  const float* w1    = (const float*)d_in[2];
  const float* b1    = (const float*)d_in[3];
  const float* w2    = (const float*)d_in[4];
  const float* b2    = (const float*)d_in[5];
  const float* w3    = (const float*)d_in[6];
  const float* b3    = (const float*)d_in[7];
  const float* w_out = (const float*)d_in[8];
  const float* b_out = (const float*)d_in[9];
  float* out = (float*)d_out;

  const int n = in_sizes[0] / 128;   // 100000
  const int E = in_sizes[1] / 2;     // 3200000
  const int* srcA = ei;
  const int* dstA = ei + E;

  char* p = (char*)d_ws;
  auto carve = [&](size_t bytes) {
    void* r = (void*)p;
    p += (bytes + 255) & ~(size_t)255;
    return r;
  };
  const size_t partBytes = (size_t)NBUCK * CAP * 4;  // 16.0 MB
  int*   csr_src    = (int*)carve(partBytes);
  int*   bucket_cnt = (int*)carve((size_t)NBUCK * 4);
  int*   row_start  = (int*)carve((size_t)n * 4);
  int*   row_end    = (int*)carve((size_t)n * 4);
  float* dinv       = (float*)carve((size_t)n * 4);
  // part (dead after bucket2csr) aliases xws1 ((n+1)*64*2 = 12.8MB < 16MB)
  char*  regionP    = (char*)carve(partBytes);
  int*   part       = (int*)regionP;
  unsigned short* xws1 = (unsigned short*)regionP;
  unsigned short* xws2 = (unsigned short*)carve((size_t)(n + 1) * 32 * 2);
  unsigned short* xws3 = (unsigned short*)carve((size_t)(n + 1) * 16 * 2);

  hipMemsetAsync(bucket_cnt, 0, (size_t)NBUCK * 4, stream);
  partition_kernel<<<(E + EPB - 1) / EPB, 256, 0, stream>>>(srcA, dstA,
                                                            bucket_cnt, part, E);
  bucket2csr_kernel<<<NBUCK, 256, 0, stream>>>(bucket_cnt, part, csr_src,
                                               row_start, row_end, dinv, n);
  // zero-row sentinels (row n of each gather table)
  hipMemsetAsync(xws1 + (size_t)n * 64, 0, 64 * 2, stream);
  hipMemsetAsync(xws2 + (size_t)n * 32, 0, 32 * 2, stream);
  hipMemsetAsync(xws3 + (size_t)n * 16, 0, 16 * 2, stream);

  // layer 1 GEMM (fp16 MFMA): xws1 = dinv .* (x @ w1)   [128 -> 64]
  gemm1_mfma_kernel<<<(n + 63) / 64, 256, 0, stream>>>(x, w1, dinv, xws1, n);
  // layer 1 agg + layer 2 GEMM fused: h1 -> xws2   [agg 64, gemm 64->32]
  agg_gemm_kernel<64, 32><<<(n + 15) / 16, 256, 0, stream>>>(
      xws1, row_start, row_end, csr_src, dinv, b1, w2, xws2, n);
  // layer 2 agg + layer 3 GEMM fused: h2 -> xws3   [agg 32, gemm 32->16]
  agg_gemm_kernel<32, 16><<<(n + 31) / 32, 256, 0, stream>>>(
      xws2, row_start, row_end, csr_src, dinv, b2, w3, xws3, n);
  // layer 3 agg + head fused
  agg_head_kernel<<<(n + 63) / 64, 256, 0, stream>>>(
      xws3, row_start, row_end, csr_src, dinv, b3, out, w_out, b_out, n);
}

// Round 9
// 198.143 us; speedup vs baseline: 3.8581x; 1.0877x over previous
//
#include <hip/hip_runtime.h>
#include <hip/hip_bf16.h>

// ---------------------------------------------------------------------------
// GCN forward: 3x GCNConv(relu) + linear head.
// R8->R9: CSR build rewritten to kill uncoalesced store transactions (R6/R8
// invariant: ~53us partition regardless of grid/pass structure; 3.2M per-lane
// scattered 4B appends = transaction wall). partition: in-LDS counting sort
// per 4096-edge tile -> contiguous per-bucket run writes. bucket2csr: build
// sorted+padded bucket in LDS -> single coalesced int4 copy out.
// Agg/GEMM pipeline unchanged from R8 (bf16 tables, dual-sub gathers).
// ---------------------------------------------------------------------------

#define NBUCK 391    // ceil(100000 / 256)
#define BSHIFT 8     // 256 nodes per bucket
#define CAP 10240    // per-bucket capacity; padded mean ~9.1K, +12 sigma
#define TILE 4096    // edges per partition block

typedef __attribute__((ext_vector_type(2))) unsigned short ushort2v;
typedef __attribute__((ext_vector_type(4))) unsigned short ushort4v;
typedef __attribute__((ext_vector_type(8))) unsigned short ushort8v;
typedef __attribute__((ext_vector_type(8))) _Float16 half8;
typedef __attribute__((ext_vector_type(4))) float f32x4;

__device__ __forceinline__ float bf2f(unsigned short u) {
  union { unsigned int i; float f; } v;
  v.i = ((unsigned int)u) << 16;
  return v.f;
}
__device__ __forceinline__ unsigned short f2bf(float f) {
  union { float f; unsigned int i; } v;
  v.f = f;
  unsigned int r = v.i + 0x7FFF + ((v.i >> 16) & 1);  // RNE
  return (unsigned short)(r >> 16);
}

// In-LDS counting sort of a 4096-edge tile by bucket (dst>>8), then each
// thread writes its buckets' contiguous runs to part[] (write-combined).
// packed value = ((dst&255)<<17) | src   (src < 2^17).
static __global__ __launch_bounds__(256) void partition_kernel(
    const int* __restrict__ src, const int* __restrict__ dst,
    int* __restrict__ bucket_cnt, int* __restrict__ part, int E) {
  __shared__ int sorted[TILE];     // 16 KB
  __shared__ int hist[512];
  __shared__ int lstart[512];
  __shared__ int cur[512];
  __shared__ int gbase[512];
  __shared__ int sdata[256];
  const int t = threadIdx.x;
  const int base0 = blockIdx.x * TILE;
  hist[t] = 0;
  hist[t + 256] = 0;
  __syncthreads();
  // pass 1: histogram (coalesced int4 loads of dst)
  for (int i = t * 4; i < TILE; i += 1024) {
    int gi = base0 + i;
    if (gi + 4 <= E) {
      int4 d = *(const int4*)&dst[gi];
      atomicAdd(&hist[d.x >> BSHIFT], 1);
      atomicAdd(&hist[d.y >> BSHIFT], 1);
      atomicAdd(&hist[d.z >> BSHIFT], 1);
      atomicAdd(&hist[d.w >> BSHIFT], 1);
    } else {
      for (int k = 0; k < 4 && gi + k < E; ++k)
        atomicAdd(&hist[dst[gi + k] >> BSHIFT], 1);
    }
  }
  __syncthreads();
  // scan (2 buckets/thread over 512) -> lstart; global bases; reset cursors
  const int v0 = hist[2 * t], v1 = hist[2 * t + 1];
  const int s = v0 + v1;
  sdata[t] = s;
  __syncthreads();
  int incl = s;
  for (int off = 1; off < 256; off <<= 1) {
    int y = (t >= off) ? sdata[t - off] : 0;
    __syncthreads();
    incl += y;
    sdata[t] = incl;
    __syncthreads();
  }
  const int excl = incl - s;
  lstart[2 * t] = excl;
  lstart[2 * t + 1] = excl + v0;
  cur[2 * t] = 0;
  cur[2 * t + 1] = 0;
  if (2 * t < NBUCK && v0) gbase[2 * t] = atomicAdd(&bucket_cnt[2 * t], v0);
  if (2 * t + 1 < NBUCK && v1)
    gbase[2 * t + 1] = atomicAdd(&bucket_cnt[2 * t + 1], v1);
  __syncthreads();
  // pass 2: re-read (L2-hot) and insert into LDS sorted[]
  for (int i = t * 4; i < TILE; i += 1024) {
    int gi = base0 + i;
    if (gi + 4 <= E) {
      int4 d = *(const int4*)&dst[gi];
      int4 sc = *(const int4*)&src[gi];
      int b0 = d.x >> BSHIFT, b1 = d.y >> BSHIFT;
      int b2 = d.z >> BSHIFT, b3 = d.w >> BSHIFT;
      int p0 = lstart[b0] + atomicAdd(&cur[b0], 1);
      sorted[p0] = ((d.x & 255) << 17) | sc.x;
      int p1 = lstart[b1] + atomicAdd(&cur[b1], 1);
      sorted[p1] = ((d.y & 255) << 17) | sc.y;
      int p2 = lstart[b2] + atomicAdd(&cur[b2], 1);
      sorted[p2] = ((d.z & 255) << 17) | sc.z;
      int p3 = lstart[b3] + atomicAdd(&cur[b3], 1);
      sorted[p3] = ((d.w & 255) << 17) | sc.w;
    } else {
      for (int k = 0; k < 4 && gi + k < E; ++k) {
        int d = dst[gi + k], sc = src[gi + k];
        int b = d >> BSHIFT;
        int pos = lstart[b] + atomicAdd(&cur[b], 1);
        sorted[pos] = ((d & 255) << 17) | sc;
      }
    }
  }
  __syncthreads();
  // write-out: thread t owns buckets t, t+256; runs are contiguous ints.
  for (int b = t; b < NBUCK; b += 256) {
    int h = hist[b];
    if (!h) continue;
    int gb = gbase[b];
    int lim = CAP - gb;
    if (lim > h) lim = h;
    const int ls = lstart[b];
    int* dstp = &part[(size_t)b * CAP + gb];
    for (int k = 0; k < lim; ++k) dstp[k] = sorted[ls + k];
  }
}

// One block per bucket. part read twice (2nd L2-hot): hist -> padded scan ->
// row_start/row_end/dinv -> insert into LDS sorted[] (+sentinel pads) ->
// single coalesced int4 copy LDS -> csr_src.
static __global__ __launch_bounds__(256) void bucket2csr_kernel(
    const int* __restrict__ bucket_cnt, const int* __restrict__ part,
    int* __restrict__ csr_src, int* __restrict__ row_start,
    int* __restrict__ row_end, float* __restrict__ dinv, int n) {
  __shared__ int sorted[CAP];  // 40 KB
  __shared__ int hist[256];
  __shared__ int cursor[256];
  __shared__ int sdata[256];
  const int b = blockIdx.x;
  const int t = threadIdx.x;
  const int base = b * CAP;
  int cnt = bucket_cnt[b];
  if (cnt > CAP) cnt = CAP;
  hist[t] = 0;
  __syncthreads();
  // pass 1: node histogram
  int i = t * 4;
  for (; i + 4 <= cnt; i += 1024) {
    int4 v = *(const int4*)&part[base + i];
    atomicAdd(&hist[v.x >> 17], 1);
    atomicAdd(&hist[v.y >> 17], 1);
    atomicAdd(&hist[v.z >> 17], 1);
    atomicAdd(&hist[v.w >> 17], 1);
  }
  for (int k = i; k < cnt && k < i + 4; ++k)
    atomicAdd(&hist[part[base + k] >> 17], 1);
  __syncthreads();
  const int v = hist[t];
  const int pd = (v + 7) & ~7;  // padded length
  sdata[t] = pd;
  __syncthreads();
  int incl = pd;
  for (int off = 1; off < 256; off <<= 1) {
    int y = (t >= off) ? sdata[t - off] : 0;
    __syncthreads();
    incl += y;
    sdata[t] = incl;
    __syncthreads();
  }
  const int excl = incl - pd;
  const int ptot = sdata[255];  // padded total (multiple of 8)
  cursor[t] = excl;
  const int node = b * 256 + t;
  if (node < n) {
    row_start[node] = base + excl;
    row_end[node] = base + excl + pd;
    dinv[node] = rsqrtf((float)(v + 1));  // true degree +1 self loop
  }
  __syncthreads();
  // pass 2: insert into LDS sorted[] by node
  i = t * 4;
  for (; i + 4 <= cnt; i += 1024) {
    int4 pv = *(const int4*)&part[base + i];
    int p0 = atomicAdd(&cursor[pv.x >> 17], 1);
    sorted[p0] = pv.x & 0x1FFFF;
    int p1 = atomicAdd(&cursor[pv.y >> 17], 1);
    sorted[p1] = pv.y & 0x1FFFF;
    int p2 = atomicAdd(&cursor[pv.z >> 17], 1);
    sorted[p2] = pv.z & 0x1FFFF;
    int p3 = atomicAdd(&cursor[pv.w >> 17], 1);
    sorted[p3] = pv.w & 0x1FFFF;
  }
  for (int k = i; k < cnt && k < i + 4; ++k) {
    int pv = part[base + k];
    int pos = atomicAdd(&cursor[pv >> 17], 1);
    sorted[pos] = pv & 0x1FFFF;
  }
  // sentinel pads (slots [excl+v, excl+pd) — disjoint from inserts)
  for (int k = v; k < pd; ++k) sorted[excl + k] = n;
  __syncthreads();
  // coalesced copy out
  for (int j = t * 4; j + 4 <= ptot; j += 1024)
    *(int4*)&csr_src[base + j] = *(const int4*)&sorted[j];
}

// Layer-1 GEMM via fp16 MFMA: xws1(bf16) = dinv .* (x @ w1), fp32 accum.
// Block = 64 nodes x 64 outs, 4 waves. LDS XOR-swizzled: byte ^= (row&7)<<4.
static __global__ __launch_bounds__(256) void gemm1_mfma_kernel(
    const float* __restrict__ x, const float* __restrict__ w1,
    const float* __restrict__ dinv, unsigned short* __restrict__ xws, int n) {
  __shared__ _Float16 xa[64 * 128];  // x tile [node][k]
  __shared__ _Float16 wt[64 * 128];  // w1^T   [o][k]
  const int t = threadIdx.x;
  const int base = blockIdx.x * 64;
  for (int i = t; i < 64 * 16; i += 256) {
    int r = i >> 4, k8 = i & 15;
    int node = base + r;
    float4 a = {0.f, 0.f, 0.f, 0.f}, b = {0.f, 0.f, 0.f, 0.f};
    if (node < n) {
      a = *(const float4*)&x[(size_t)node * 128 + k8 * 8];
      b = *(const float4*)&x[(size_t)node * 128 + k8 * 8 + 4];
    }
    half8 h = {(_Float16)a.x, (_Float16)a.y, (_Float16)a.z, (_Float16)a.w,
               (_Float16)b.x, (_Float16)b.y, (_Float16)b.z, (_Float16)b.w};
    int byte = (r * 256 + k8 * 16) ^ ((r & 7) << 4);
    *(half8*)((char*)xa + byte) = h;
  }
  for (int i = t; i < 128 * 64; i += 256) {
    int k = i >> 6, o = i & 63;
    _Float16 v = (_Float16)w1[i];
    int byte = (o * 256 + k * 2) ^ ((o & 7) << 4);
    *(_Float16*)((char*)wt + byte) = v;
  }
  __syncthreads();
  const int wv = t >> 6;
  const int lane = t & 63;
  const int m = lane & 15;
  const int kg = lane >> 4;
  const int arow = wv * 16 + m;
  f32x4 acc[4] = {{0.f, 0.f, 0.f, 0.f}, {0.f, 0.f, 0.f, 0.f},
                  {0.f, 0.f, 0.f, 0.f}, {0.f, 0.f, 0.f, 0.f}};
#pragma unroll
  for (int ks = 0; ks < 4; ++ks) {
    int k0 = ks * 32 + kg * 8;
    int abyte = (arow * 256 + k0 * 2) ^ ((arow & 7) << 4);
    half8 af = *(const half8*)((const char*)xa + abyte);
#pragma unroll
    for (int nt = 0; nt < 4; ++nt) {
      int o = nt * 16 + m;
      int bbyte = (o * 256 + k0 * 2) ^ ((o & 7) << 4);
      half8 bf = *(const half8*)((const char*)wt + bbyte);
      acc[nt] = __builtin_amdgcn_mfma_f32_16x16x32_f16(af, bf, acc[nt], 0, 0, 0);
    }
  }
#pragma unroll
  for (int r = 0; r < 4; ++r) {
    int node = base + wv * 16 + kg * 4 + r;
    if (node < n) {
      float dv = dinv[node];
#pragma unroll
      for (int nt = 0; nt < 4; ++nt)
        xws[(size_t)node * 64 + nt * 16 + m] = f2bf(dv * acc[nt][r]);
    }
  }
}

// Fused: h = relu(dinv*(gather-sum + self) + bias); xws_next = bf16(dinv*(h@W)).
// LPN = F/4 lanes per node = 2 sub-groups x GC(=F/8) feat-lanes. Sub s takes
// 8-edge chunks s, s+2, s+4, ... -> 16 gathers in flight, every iteration
// fully 8-unrolled (segments padded to mult-of-8). Combine via shfl_xor(GC).
template <int F, int FOUT>
static __global__ __launch_bounds__(256) void agg_gemm_kernel(
    const unsigned short* __restrict__ xws, const int* __restrict__ row_start,
    const int* __restrict__ row_end, const int* __restrict__ csr_src,
    const float* __restrict__ dinv, const float* __restrict__ bias,
    const float* __restrict__ W, unsigned short* __restrict__ xws_next, int n) {
  constexpr int GC = F / 8;        // feat-lanes per sub-group
  constexpr int LPN = F / 4;       // lanes per node
  constexpr int NODES = 256 / LPN;
  constexpr int OUTS = FOUT / LPN; // epilogue outputs per thread (=2)
  __shared__ float ws[F * FOUT];
  __shared__ float hs[NODES][F + 1];
  const int t = threadIdx.x;
  for (int i = t; i < F * FOUT / 4; i += 256)
    *(float4*)&ws[i * 4] = *(const float4*)&W[i * 4];
  const int nl = t / LPN;
  const int l = t % LPN;
  const int c = l % GC;
  const int sub = l / GC;
  const int node = blockIdx.x * NODES + nl;
  const bool valid = node < n;
  const int safe = valid ? node : 0;
  const int start = valid ? row_start[safe] : 0;
  const int end = valid ? row_end[safe] : 0;
  float acc[8] = {0.f, 0.f, 0.f, 0.f, 0.f, 0.f, 0.f, 0.f};
  for (int e = start + sub * 8; e < end; e += 16) {
    int4 sa = *(const int4*)&csr_src[e];
    int4 sb = *(const int4*)&csr_src[e + 4];
    ushort8v v0 = *(const ushort8v*)&xws[(size_t)sa.x * F + c * 8];
    ushort8v v1 = *(const ushort8v*)&xws[(size_t)sa.y * F + c * 8];
    ushort8v v2 = *(const ushort8v*)&xws[(size_t)sa.z * F + c * 8];
    ushort8v v3 = *(const ushort8v*)&xws[(size_t)sa.w * F + c * 8];
    ushort8v v4 = *(const ushort8v*)&xws[(size_t)sb.x * F + c * 8];
    ushort8v v5 = *(const ushort8v*)&xws[(size_t)sb.y * F + c * 8];
    ushort8v v6 = *(const ushort8v*)&xws[(size_t)sb.z * F + c * 8];
    ushort8v v7 = *(const ushort8v*)&xws[(size_t)sb.w * F + c * 8];
#pragma unroll
    for (int j = 0; j < 8; ++j)
      acc[j] += ((bf2f(v0[j]) + bf2f(v1[j])) + (bf2f(v2[j]) + bf2f(v3[j]))) +
                ((bf2f(v4[j]) + bf2f(v5[j])) + (bf2f(v6[j]) + bf2f(v7[j])));
  }
  // combine the two sub-groups (partner lane = l ^ GC, within the node)
#pragma unroll
  for (int j = 0; j < 8; ++j) acc[j] += __shfl_xor(acc[j], GC);
  const float dv = dinv[safe];
  if (sub == 0) {
    ushort8v sv = *(const ushort8v*)&xws[(size_t)safe * F + c * 8];
#pragma unroll
    for (int j = 0; j < 8; ++j)
      hs[nl][c * 8 + j] =
          fmaxf(dv * (acc[j] + bf2f(sv[j])) + bias[c * 8 + j], 0.f);
  }
  __syncthreads();
  // epilogue GEMM: LPN lanes x OUTS outputs per node
  float o[OUTS];
#pragma unroll
  for (int j = 0; j < OUTS; ++j) o[j] = 0.f;
#pragma unroll 4
  for (int k = 0; k < F; ++k) {
    float hv = hs[nl][k];
#pragma unroll
    for (int j = 0; j < OUTS; ++j) o[j] += hv * ws[k * FOUT + l * OUTS + j];
  }
  if (valid) {
    ushort2v r = {f2bf(dv * o[0]), f2bf(dv * o[1])};
    *(ushort2v*)&xws_next[(size_t)node * FOUT + l * OUTS] = r;
  }
}

// Final layer: h = relu(dinv*(gather+self)+b3); out[n] = h . w_out + b_out.
// 4 lanes/node = 2 subs x 2 feat-lanes; chunk-interleaved like agg_gemm.
static __global__ __launch_bounds__(256) void agg_head_kernel(
    const unsigned short* __restrict__ xws, const int* __restrict__ row_start,
    const int* __restrict__ row_end, const int* __restrict__ csr_src,
    const float* __restrict__ dinv, const float* __restrict__ bias,
    float* __restrict__ out, const float* __restrict__ w_out,
    const float* __restrict__ b_out, int n) {
  constexpr int F = 16, NODES = 64;
  const int t = threadIdx.x;
  const int nl = t >> 2;
  const int l = t & 3;
  const int c = l & 1;
  const int sub = l >> 1;
  const int node = blockIdx.x * NODES + nl;
  if (node >= n) return;
  const int start = row_start[node], end = row_end[node];
  float acc[8] = {0.f, 0.f, 0.f, 0.f, 0.f, 0.f, 0.f, 0.f};
  for (int e = start + sub * 8; e < end; e += 16) {
    int4 sa = *(const int4*)&csr_src[e];
    int4 sb = *(const int4*)&csr_src[e + 4];
    ushort8v v0 = *(const ushort8v*)&xws[(size_t)sa.x * F + c * 8];
    ushort8v v1 = *(const ushort8v*)&xws[(size_t)sa.y * F + c * 8];
    ushort8v v2 = *(const ushort8v*)&xws[(size_t)sa.z * F + c * 8];
    ushort8v v3 = *(const ushort8v*)&xws[(size_t)sa.w * F + c * 8];
    ushort8v v4 = *(const ushort8v*)&xws[(size_t)sb.x * F + c * 8];
    ushort8v v5 = *(const ushort8v*)&xws[(size_t)sb.y * F + c * 8];
    ushort8v v6 = *(const ushort8v*)&xws[(size_t)sb.z * F + c * 8];
    ushort8v v7 = *(const ushort8v*)&xws[(size_t)sb.w * F + c * 8];
#pragma unroll
    for (int j = 0; j < 8; ++j)
      acc[j] += ((bf2f(v0[j]) + bf2f(v1[j])) + (bf2f(v2[j]) + bf2f(v3[j]))) +
                ((bf2f(v4[j]) + bf2f(v5[j])) + (bf2f(v6[j]) + bf2f(v7[j])));
  }
#pragma unroll
  for (int j = 0; j < 8; ++j) acc[j] += __shfl_xor(acc[j], 2);
  ushort8v sv = *(const ushort8v*)&xws[(size_t)node * F + c * 8];
  float dv = dinv[node];
  float p = 0.f;
#pragma unroll
  for (int j = 0; j < 8; ++j) {
    float r = fmaxf(dv * (acc[j] + bf2f(sv[j])) + bias[c * 8 + j], 0.f);
    p += r * w_out[c * 8 + j];
  }
  p += __shfl_xor(p, 1);  // combine the two feat-lanes
  if (l == 0) out[node] = p + b_out[0];
}

extern "C" void kernel_launch(void* const* d_in, const int* in_sizes, int n_in,
                              void* d_out, int out_size, void* d_ws, size_t ws_size,
                              hipStream_t stream) {
  const float* x     = (const float*)d_in[0];
  const int*   ei    = (const int*)d_in[1];
  const float* w1    = (const float*)d_in[2];
  const float* b1    = (const float*)d_in[3];
  const float* w2    = (const float*)d_in[4];
  const float* b2    = (const float*)d_in[5];
  const float* w3    = (const float*)d_in[6];
  const float* b3    = (const float*)d_in[7];
  const float* w_out = (const float*)d_in[8];
  const float* b_out = (const float*)d_in[9];
  float* out = (float*)d_out;

  const int n = in_sizes[0] / 128;   // 100000
  const int E = in_sizes[1] / 2;     // 3200000
  const int* srcA = ei;
  const int* dstA = ei + E;

  char* p = (char*)d_ws;
  auto carve = [&](size_t bytes) {
    void* r = (void*)p;
    p += (bytes + 255) & ~(size_t)255;
    return r;
  };
  const size_t partBytes = (size_t)NBUCK * CAP * 4;  // 16.0 MB
  int*   csr_src    = (int*)carve(partBytes);
  int*   bucket_cnt = (int*)carve((size_t)NBUCK * 4);
  int*   row_start  = (int*)carve((size_t)n * 4);
  int*   row_end    = (int*)carve((size_t)n * 4);
  float* dinv       = (float*)carve((size_t)n * 4);
  // part (dead after bucket2csr) aliases xws1 ((n+1)*64*2 = 12.8MB < 16MB)
  char*  regionP    = (char*)carve(partBytes);
  int*   part       = (int*)regionP;
  unsigned short* xws1 = (unsigned short*)regionP;
  unsigned short* xws2 = (unsigned short*)carve((size_t)(n + 1) * 32 * 2);
  unsigned short* xws3 = (unsigned short*)carve((size_t)(n + 1) * 16 * 2);

  hipMemsetAsync(bucket_cnt, 0, (size_t)NBUCK * 4, stream);
  partition_kernel<<<(E + TILE - 1) / TILE, 256, 0, stream>>>(srcA, dstA,
                                                              bucket_cnt, part, E);
  bucket2csr_kernel<<<NBUCK, 256, 0, stream>>>(bucket_cnt, part, csr_src,
                                               row_start, row_end, dinv, n);
  // zero-row sentinels (row n of each gather table)
  hipMemsetAsync(xws1 + (size_t)n * 64, 0, 64 * 2, stream);
  hipMemsetAsync(xws2 + (size_t)n * 32, 0, 32 * 2, stream);
  hipMemsetAsync(xws3 + (size_t)n * 16, 0, 16 * 2, stream);

  // layer 1 GEMM (fp16 MFMA): xws1 = dinv .* (x @ w1)   [128 -> 64]
  gemm1_mfma_kernel<<<(n + 63) / 64, 256, 0, stream>>>(x, w1, dinv, xws1, n);
  // layer 1 agg + layer 2 GEMM fused: h1 -> xws2   [agg 64, gemm 64->32]
  agg_gemm_kernel<64, 32><<<(n + 15) / 16, 256, 0, stream>>>(
      xws1, row_start, row_end, csr_src, dinv, b1, w2, xws2, n);
  // layer 2 agg + layer 3 GEMM fused: h2 -> xws3   [agg 32, gemm 32->16]
  agg_gemm_kernel<32, 16><<<(n + 31) / 32, 256, 0, stream>>>(
      xws2, row_start, row_end, csr_src, dinv, b2, w3, xws3, n);
  // layer 3 agg + head fused
  agg_head_kernel<<<(n + 63) / 64, 256, 0, stream>>>(
      xws3, row_start, row_end, csr_src, dinv, b3, out, w_out, b_out, n);
}

// Round 10
// 190.182 us; speedup vs baseline: 4.0196x; 1.0419x over previous
//
#include <hip/hip_runtime.h>
#include <hip/hip_bf16.h>

// ---------------------------------------------------------------------------
// GCN forward: 3x GCNConv(relu) + linear head.
// R9->R10: (a) all agg kernels use 4 sub-groups/node (alternating 8-edge
// chunks, 2-level shfl_xor combine) -> 32 gathers in flight; (b) partition
// holds its 16 edges/thread in registers (edge list read once); (c) sentinel
// zero-rows written by producer kernels (3 memsets deleted).
// Gather tables bf16, accumulation fp32. fp8 ruled out by error analysis
// (gather error does not average down; worst-node ~1.3e-3 vs thr 1.494e-3).
// ---------------------------------------------------------------------------

#define NBUCK 391    // ceil(100000 / 256)
#define BSHIFT 8     // 256 nodes per bucket
#define CAP 10240    // per-bucket capacity; padded mean ~9.1K, +12 sigma
#define TILE 4096    // edges per partition block

typedef __attribute__((ext_vector_type(2))) unsigned short ushort2v;
typedef __attribute__((ext_vector_type(4))) unsigned short ushort4v;
typedef __attribute__((ext_vector_type(8))) unsigned short ushort8v;
typedef __attribute__((ext_vector_type(8))) _Float16 half8;
typedef __attribute__((ext_vector_type(4))) float f32x4;

__device__ __forceinline__ float bf2f(unsigned short u) {
  union { unsigned int i; float f; } v;
  v.i = ((unsigned int)u) << 16;
  return v.f;
}
__device__ __forceinline__ unsigned short f2bf(float f) {
  union { float f; unsigned int i; } v;
  v.f = f;
  unsigned int r = v.i + 0x7FFF + ((v.i >> 16) & 1);  // RNE
  return (unsigned short)(r >> 16);
}

// In-LDS counting sort of a 4096-edge tile by bucket (dst>>8). Edges held in
// REGISTERS between histogram and insert (edge list read once). Each thread
// then writes its buckets' contiguous runs to part[] (write-combined).
// packed value = ((dst&255)<<17) | src   (src < 2^17).
static __global__ __launch_bounds__(256) void partition_kernel(
    const int* __restrict__ src, const int* __restrict__ dst,
    int* __restrict__ bucket_cnt, int* __restrict__ part, int E) {
  __shared__ int sorted[TILE];     // 16 KB
  __shared__ int hist[512];
  __shared__ int lstart[512];
  __shared__ int cur[512];
  __shared__ int gbase[512];
  __shared__ int sdata[256];
  const int t = threadIdx.x;
  const int base0 = blockIdx.x * TILE;
  hist[t] = 0;
  hist[t + 256] = 0;
  __syncthreads();
  // load 16 edges/thread into registers (4 x int4 pairs), histogram from regs
  int4 sv[4], dv[4];
#pragma unroll
  for (int j = 0; j < 4; ++j) {
    int gi = base0 + t * 4 + j * 1024;
    if (gi + 4 <= E) {
      sv[j] = *(const int4*)&src[gi];
      dv[j] = *(const int4*)&dst[gi];
    } else {
      sv[j].x = (gi + 0 < E) ? src[gi + 0] : -1;
      sv[j].y = (gi + 1 < E) ? src[gi + 1] : -1;
      sv[j].z = (gi + 2 < E) ? src[gi + 2] : -1;
      sv[j].w = (gi + 3 < E) ? src[gi + 3] : -1;
      dv[j].x = (gi + 0 < E) ? dst[gi + 0] : 0;
      dv[j].y = (gi + 1 < E) ? dst[gi + 1] : 0;
      dv[j].z = (gi + 2 < E) ? dst[gi + 2] : 0;
      dv[j].w = (gi + 3 < E) ? dst[gi + 3] : 0;
    }
    if (sv[j].x >= 0) atomicAdd(&hist[dv[j].x >> BSHIFT], 1);
    if (sv[j].y >= 0) atomicAdd(&hist[dv[j].y >> BSHIFT], 1);
    if (sv[j].z >= 0) atomicAdd(&hist[dv[j].z >> BSHIFT], 1);
    if (sv[j].w >= 0) atomicAdd(&hist[dv[j].w >> BSHIFT], 1);
  }
  __syncthreads();
  // scan (2 buckets/thread) -> lstart; global bases; reset cursors
  const int v0 = hist[2 * t], v1 = hist[2 * t + 1];
  const int s = v0 + v1;
  sdata[t] = s;
  __syncthreads();
  int incl = s;
  for (int off = 1; off < 256; off <<= 1) {
    int y = (t >= off) ? sdata[t - off] : 0;
    __syncthreads();
    incl += y;
    sdata[t] = incl;
    __syncthreads();
  }
  const int excl = incl - s;
  lstart[2 * t] = excl;
  lstart[2 * t + 1] = excl + v0;
  cur[2 * t] = 0;
  cur[2 * t + 1] = 0;
  if (2 * t < NBUCK && v0) gbase[2 * t] = atomicAdd(&bucket_cnt[2 * t], v0);
  if (2 * t + 1 < NBUCK && v1)
    gbase[2 * t + 1] = atomicAdd(&bucket_cnt[2 * t + 1], v1);
  __syncthreads();
  // insert from registers into LDS sorted[]
#pragma unroll
  for (int j = 0; j < 4; ++j) {
    if (sv[j].x >= 0) {
      int b = dv[j].x >> BSHIFT;
      sorted[lstart[b] + atomicAdd(&cur[b], 1)] = ((dv[j].x & 255) << 17) | sv[j].x;
    }
    if (sv[j].y >= 0) {
      int b = dv[j].y >> BSHIFT;
      sorted[lstart[b] + atomicAdd(&cur[b], 1)] = ((dv[j].y & 255) << 17) | sv[j].y;
    }
    if (sv[j].z >= 0) {
      int b = dv[j].z >> BSHIFT;
      sorted[lstart[b] + atomicAdd(&cur[b], 1)] = ((dv[j].z & 255) << 17) | sv[j].z;
    }
    if (sv[j].w >= 0) {
      int b = dv[j].w >> BSHIFT;
      sorted[lstart[b] + atomicAdd(&cur[b], 1)] = ((dv[j].w & 255) << 17) | sv[j].w;
    }
  }
  __syncthreads();
  // write-out: thread t owns buckets t, t+256; runs are contiguous ints.
  for (int b = t; b < NBUCK; b += 256) {
    int h = hist[b];
    if (!h) continue;
    int gb = gbase[b];
    int lim = CAP - gb;
    if (lim > h) lim = h;
    const int ls = lstart[b];
    int* dstp = &part[(size_t)b * CAP + gb];
    for (int k = 0; k < lim; ++k) dstp[k] = sorted[ls + k];
  }
}

// One block per bucket. hist -> padded scan -> row_start/row_end/dinv ->
// insert into LDS sorted[] (+sentinel pads) -> coalesced int4 copy out.
static __global__ __launch_bounds__(256) void bucket2csr_kernel(
    const int* __restrict__ bucket_cnt, const int* __restrict__ part,
    int* __restrict__ csr_src, int* __restrict__ row_start,
    int* __restrict__ row_end, float* __restrict__ dinv, int n) {
  __shared__ int sorted[CAP];  // 40 KB
  __shared__ int hist[256];
  __shared__ int cursor[256];
  __shared__ int sdata[256];
  const int b = blockIdx.x;
  const int t = threadIdx.x;
  const int base = b * CAP;
  int cnt = bucket_cnt[b];
  if (cnt > CAP) cnt = CAP;
  hist[t] = 0;
  __syncthreads();
  int i = t * 4;
  for (; i + 4 <= cnt; i += 1024) {
    int4 v = *(const int4*)&part[base + i];
    atomicAdd(&hist[v.x >> 17], 1);
    atomicAdd(&hist[v.y >> 17], 1);
    atomicAdd(&hist[v.z >> 17], 1);
    atomicAdd(&hist[v.w >> 17], 1);
  }
  for (int k = i; k < cnt && k < i + 4; ++k)
    atomicAdd(&hist[part[base + k] >> 17], 1);
  __syncthreads();
  const int v = hist[t];
  const int pd = (v + 7) & ~7;  // padded length
  sdata[t] = pd;
  __syncthreads();
  int incl = pd;
  for (int off = 1; off < 256; off <<= 1) {
    int y = (t >= off) ? sdata[t - off] : 0;
    __syncthreads();
    incl += y;
    sdata[t] = incl;
    __syncthreads();
  }
  const int excl = incl - pd;
  const int ptot = sdata[255];  // padded total (multiple of 8)
  cursor[t] = excl;
  const int node = b * 256 + t;
  if (node < n) {
    row_start[node] = base + excl;
    row_end[node] = base + excl + pd;
    dinv[node] = rsqrtf((float)(v + 1));  // true degree +1 self loop
  }
  __syncthreads();
  i = t * 4;
  for (; i + 4 <= cnt; i += 1024) {
    int4 pv = *(const int4*)&part[base + i];
    int p0 = atomicAdd(&cursor[pv.x >> 17], 1);
    sorted[p0] = pv.x & 0x1FFFF;
    int p1 = atomicAdd(&cursor[pv.y >> 17], 1);
    sorted[p1] = pv.y & 0x1FFFF;
    int p2 = atomicAdd(&cursor[pv.z >> 17], 1);
    sorted[p2] = pv.z & 0x1FFFF;
    int p3 = atomicAdd(&cursor[pv.w >> 17], 1);
    sorted[p3] = pv.w & 0x1FFFF;
  }
  for (int k = i; k < cnt && k < i + 4; ++k) {
    int pv = part[base + k];
    int pos = atomicAdd(&cursor[pv >> 17], 1);
    sorted[pos] = pv & 0x1FFFF;
  }
  for (int k = v; k < pd; ++k) sorted[excl + k] = n;
  __syncthreads();
  for (int j = t * 4; j + 4 <= ptot; j += 1024)
    *(int4*)&csr_src[base + j] = *(const int4*)&sorted[j];
}

// Layer-1 GEMM via fp16 MFMA: xws1(bf16) = dinv .* (x @ w1), fp32 accum.
// Block = 64 nodes x 64 outs, 4 waves. LDS XOR-swizzled: byte ^= (row&7)<<4.
// Block 0 also zeroes the sentinel row n of xws1.
static __global__ __launch_bounds__(256) void gemm1_mfma_kernel(
    const float* __restrict__ x, const float* __restrict__ w1,
    const float* __restrict__ dinv, unsigned short* __restrict__ xws, int n) {
  __shared__ _Float16 xa[64 * 128];  // x tile [node][k]
  __shared__ _Float16 wt[64 * 128];  // w1^T   [o][k]
  const int t = threadIdx.x;
  const int base = blockIdx.x * 64;
  if (blockIdx.x == 0 && t < 8) {
    ushort8v z = {0, 0, 0, 0, 0, 0, 0, 0};
    *(ushort8v*)&xws[(size_t)n * 64 + t * 8] = z;
  }
  for (int i = t; i < 64 * 16; i += 256) {
    int r = i >> 4, k8 = i & 15;
    int node = base + r;
    float4 a = {0.f, 0.f, 0.f, 0.f}, b = {0.f, 0.f, 0.f, 0.f};
    if (node < n) {
      a = *(const float4*)&x[(size_t)node * 128 + k8 * 8];
      b = *(const float4*)&x[(size_t)node * 128 + k8 * 8 + 4];
    }
    half8 h = {(_Float16)a.x, (_Float16)a.y, (_Float16)a.z, (_Float16)a.w,
               (_Float16)b.x, (_Float16)b.y, (_Float16)b.z, (_Float16)b.w};
    int byte = (r * 256 + k8 * 16) ^ ((r & 7) << 4);
    *(half8*)((char*)xa + byte) = h;
  }
  for (int i = t; i < 128 * 64; i += 256) {
    int k = i >> 6, o = i & 63;
    _Float16 v = (_Float16)w1[i];
    int byte = (o * 256 + k * 2) ^ ((o & 7) << 4);
    *(_Float16*)((char*)wt + byte) = v;
  }
  __syncthreads();
  const int wv = t >> 6;
  const int lane = t & 63;
  const int m = lane & 15;
  const int kg = lane >> 4;
  const int arow = wv * 16 + m;
  f32x4 acc[4] = {{0.f, 0.f, 0.f, 0.f}, {0.f, 0.f, 0.f, 0.f},
                  {0.f, 0.f, 0.f, 0.f}, {0.f, 0.f, 0.f, 0.f}};
#pragma unroll
  for (int ks = 0; ks < 4; ++ks) {
    int k0 = ks * 32 + kg * 8;
    int abyte = (arow * 256 + k0 * 2) ^ ((arow & 7) << 4);
    half8 af = *(const half8*)((const char*)xa + abyte);
#pragma unroll
    for (int nt = 0; nt < 4; ++nt) {
      int o = nt * 16 + m;
      int bbyte = (o * 256 + k0 * 2) ^ ((o & 7) << 4);
      half8 bf = *(const half8*)((const char*)wt + bbyte);
      acc[nt] = __builtin_amdgcn_mfma_f32_16x16x32_f16(af, bf, acc[nt], 0, 0, 0);
    }
  }
#pragma unroll
  for (int r = 0; r < 4; ++r) {
    int node = base + wv * 16 + kg * 4 + r;
    if (node < n) {
      float dv = dinv[node];
#pragma unroll
      for (int nt = 0; nt < 4; ++nt)
        xws[(size_t)node * 64 + nt * 16 + m] = f2bf(dv * acc[nt][r]);
    }
  }
}

// Fused: h = relu(dinv*(gather-sum + self) + bias); xws_next = bf16(dinv*(h@W)).
// 4 sub-groups per node (LPN = F/2 lanes) on alternating 8-edge chunks ->
// 32 gathers in flight; combine via 2-level shfl_xor. OUTS = FOUT/LPN = 1.
// Block 0 zeroes the sentinel row n of xws_next.
template <int F, int FOUT>
static __global__ __launch_bounds__(256) void agg_gemm_kernel(
    const unsigned short* __restrict__ xws, const int* __restrict__ row_start,
    const int* __restrict__ row_end, const int* __restrict__ csr_src,
    const float* __restrict__ dinv, const float* __restrict__ bias,
    const float* __restrict__ W, unsigned short* __restrict__ xws_next, int n) {
  constexpr int GC = F / 8;        // feat-lanes per sub-group
  constexpr int LPN = F / 2;       // lanes per node (4 sub-groups)
  constexpr int NODES = 256 / LPN;
  static_assert(FOUT == LPN, "epilogue writes 1 out per lane");
  __shared__ float ws[F * FOUT];
  __shared__ float hs[NODES][F + 1];
  const int t = threadIdx.x;
  if (blockIdx.x == 0 && t < FOUT / 8) {
    ushort8v z = {0, 0, 0, 0, 0, 0, 0, 0};
    *(ushort8v*)&xws_next[(size_t)n * FOUT + t * 8] = z;
  }
  for (int i = t; i < F * FOUT / 4; i += 256)
    *(float4*)&ws[i * 4] = *(const float4*)&W[i * 4];
  const int nl = t / LPN;
  const int l = t % LPN;
  const int c = l % GC;
  const int sub = l / GC;
  const int node = blockIdx.x * NODES + nl;
  const bool valid = node < n;
  const int safe = valid ? node : 0;
  const int start = valid ? row_start[safe] : 0;
  const int end = valid ? row_end[safe] : 0;
  float acc[8] = {0.f, 0.f, 0.f, 0.f, 0.f, 0.f, 0.f, 0.f};
  for (int e = start + sub * 8; e < end; e += 32) {
    int4 sa = *(const int4*)&csr_src[e];
    int4 sb = *(const int4*)&csr_src[e + 4];
    ushort8v v0 = *(const ushort8v*)&xws[(size_t)sa.x * F + c * 8];
    ushort8v v1 = *(const ushort8v*)&xws[(size_t)sa.y * F + c * 8];
    ushort8v v2 = *(const ushort8v*)&xws[(size_t)sa.z * F + c * 8];
    ushort8v v3 = *(const ushort8v*)&xws[(size_t)sa.w * F + c * 8];
    ushort8v v4 = *(const ushort8v*)&xws[(size_t)sb.x * F + c * 8];
    ushort8v v5 = *(const ushort8v*)&xws[(size_t)sb.y * F + c * 8];
    ushort8v v6 = *(const ushort8v*)&xws[(size_t)sb.z * F + c * 8];
    ushort8v v7 = *(const ushort8v*)&xws[(size_t)sb.w * F + c * 8];
#pragma unroll
    for (int j = 0; j < 8; ++j)
      acc[j] += ((bf2f(v0[j]) + bf2f(v1[j])) + (bf2f(v2[j]) + bf2f(v3[j]))) +
                ((bf2f(v4[j]) + bf2f(v5[j])) + (bf2f(v6[j]) + bf2f(v7[j])));
  }
  // combine the 4 sub-groups: xor GC then xor 2*GC (within the node's lanes)
#pragma unroll
  for (int j = 0; j < 8; ++j) {
    acc[j] += __shfl_xor(acc[j], GC);
    acc[j] += __shfl_xor(acc[j], 2 * GC);
  }
  const float dv = dinv[safe];
  if (sub == 0) {
    ushort8v sv = *(const ushort8v*)&xws[(size_t)safe * F + c * 8];
#pragma unroll
    for (int j = 0; j < 8; ++j)
      hs[nl][c * 8 + j] =
          fmaxf(dv * (acc[j] + bf2f(sv[j])) + bias[c * 8 + j], 0.f);
  }
  __syncthreads();
  // epilogue GEMM: LPN lanes x 1 output per node
  float o = 0.f;
#pragma unroll 4
  for (int k = 0; k < F; ++k) o += hs[nl][k] * ws[k * FOUT + l];
  if (valid) xws_next[(size_t)node * FOUT + l] = f2bf(dv * o);
}

// Final layer: h = relu(dinv*(gather+self)+b3); out[n] = h . w_out + b_out.
// 8 lanes/node = 4 subs x 2 feat-lanes; chunk-interleaved.
static __global__ __launch_bounds__(256) void agg_head_kernel(
    const unsigned short* __restrict__ xws, const int* __restrict__ row_start,
    const int* __restrict__ row_end, const int* __restrict__ csr_src,
    const float* __restrict__ dinv, const float* __restrict__ bias,
    float* __restrict__ out, const float* __restrict__ w_out,
    const float* __restrict__ b_out, int n) {
  constexpr int F = 16, NODES = 32;
  const int t = threadIdx.x;
  const int nl = t >> 3;
  const int l = t & 7;
  const int c = l & 1;
  const int sub = l >> 1;
  const int node = blockIdx.x * NODES + nl;
  if (node >= n) return;
  const int start = row_start[node], end = row_end[node];
  float acc[8] = {0.f, 0.f, 0.f, 0.f, 0.f, 0.f, 0.f, 0.f};
  for (int e = start + sub * 8; e < end; e += 32) {
    int4 sa = *(const int4*)&csr_src[e];
    int4 sb = *(const int4*)&csr_src[e + 4];
    ushort8v v0 = *(const ushort8v*)&xws[(size_t)sa.x * F + c * 8];
    ushort8v v1 = *(const ushort8v*)&xws[(size_t)sa.y * F + c * 8];
    ushort8v v2 = *(const ushort8v*)&xws[(size_t)sa.z * F + c * 8];
    ushort8v v3 = *(const ushort8v*)&xws[(size_t)sa.w * F + c * 8];
    ushort8v v4 = *(const ushort8v*)&xws[(size_t)sb.x * F + c * 8];
    ushort8v v5 = *(const ushort8v*)&xws[(size_t)sb.y * F + c * 8];
    ushort8v v6 = *(const ushort8v*)&xws[(size_t)sb.z * F + c * 8];
    ushort8v v7 = *(const ushort8v*)&xws[(size_t)sb.w * F + c * 8];
#pragma unroll
    for (int j = 0; j < 8; ++j)
      acc[j] += ((bf2f(v0[j]) + bf2f(v1[j])) + (bf2f(v2[j]) + bf2f(v3[j]))) +
                ((bf2f(v4[j]) + bf2f(v5[j])) + (bf2f(v6[j]) + bf2f(v7[j])));
  }
#pragma unroll
  for (int j = 0; j < 8; ++j) {
    acc[j] += __shfl_xor(acc[j], 2);
    acc[j] += __shfl_xor(acc[j], 4);
  }
  ushort8v sv = *(const ushort8v*)&xws[(size_t)node * F + c * 8];
  float dv = dinv[node];
  float p = 0.f;
#pragma unroll
  for (int j = 0; j < 8; ++j) {
    float r = fmaxf(dv * (acc[j] + bf2f(sv[j])) + bias[c * 8 + j], 0.f);
    p += r * w_out[c * 8 + j];
  }
  p += __shfl_xor(p, 1);  // combine the two feat-lanes
  if (l == 0) out[node] = p + b_out[0];
}

extern "C" void kernel_launch(void* const* d_in, const int* in_sizes, int n_in,
                              void* d_out, int out_size, void* d_ws, size_t ws_size,
                              hipStream_t stream) {
  const float* x     = (const float*)d_in[0];
  const int*   ei    = (const int*)d_in[1];
  const float* w1    = (const float*)d_in[2];
  const float* b1    = (const float*)d_in[3];
  const float* w2    = (const float*)d_in[4];
  const float* b2    = (const float*)d_in[5];
  const float* w3    = (const float*)d_in[6];
  const float* b3    = (const float*)d_in[7];
  const float* w_out = (const float*)d_in[8];
  const float* b_out = (const float*)d_in[9];
  float* out = (float*)d_out;

  const int n = in_sizes[0] / 128;   // 100000
  const int E = in_sizes[1] / 2;     // 3200000
  const int* srcA = ei;
  const int* dstA = ei + E;

  char* p = (char*)d_ws;
  auto carve = [&](size_t bytes) {
    void* r = (void*)p;
    p += (bytes + 255) & ~(size_t)255;
    return r;
  };
  const size_t partBytes = (size_t)NBUCK * CAP * 4;  // 16.0 MB
  int*   csr_src    = (int*)carve(partBytes);
  int*   bucket_cnt = (int*)carve((size_t)NBUCK * 4);
  int*   row_start  = (int*)carve((size_t)n * 4);
  int*   row_end    = (int*)carve((size_t)n * 4);
  float* dinv       = (float*)carve((size_t)n * 4);
  // part (dead after bucket2csr) aliases xws1 ((n+1)*64*2 = 12.8MB < 16MB)
  char*  regionP    = (char*)carve(partBytes);
  int*   part       = (int*)regionP;
  unsigned short* xws1 = (unsigned short*)regionP;
  unsigned short* xws2 = (unsigned short*)carve((size_t)(n + 1) * 32 * 2);
  unsigned short* xws3 = (unsigned short*)carve((size_t)(n + 1) * 16 * 2);

  hipMemsetAsync(bucket_cnt, 0, (size_t)NBUCK * 4, stream);
  partition_kernel<<<(E + TILE - 1) / TILE, 256, 0, stream>>>(srcA, dstA,
                                                              bucket_cnt, part, E);
  bucket2csr_kernel<<<NBUCK, 256, 0, stream>>>(bucket_cnt, part, csr_src,
                                               row_start, row_end, dinv, n);

  // layer 1 GEMM (fp16 MFMA): xws1 = dinv .* (x @ w1)   [128 -> 64]
  gemm1_mfma_kernel<<<(n + 63) / 64, 256, 0, stream>>>(x, w1, dinv, xws1, n);
  // layer 1 agg + layer 2 GEMM fused: h1 -> xws2   [agg 64, gemm 64->32]
  agg_gemm_kernel<64, 32><<<(n + 7) / 8, 256, 0, stream>>>(
      xws1, row_start, row_end, csr_src, dinv, b1, w2, xws2, n);
  // layer 2 agg + layer 3 GEMM fused: h2 -> xws3   [agg 32, gemm 32->16]
  agg_gemm_kernel<32, 16><<<(n + 15) / 16, 256, 0, stream>>>(
      xws2, row_start, row_end, csr_src, dinv, b2, w3, xws3, n);
  // layer 3 agg + head fused
  agg_head_kernel<<<(n + 31) / 32, 256, 0, stream>>>(
      xws3, row_start, row_end, csr_src, dinv, b3, out, w_out, b_out, n);
}

// Round 11
// 187.205 us; speedup vs baseline: 4.0835x; 1.0159x over previous
//
#include <hip/hip_runtime.h>
#include <hip/hip_bf16.h>

// ---------------------------------------------------------------------------
// GCN forward: 3x GCNConv(relu) + linear head.
// R10->R11: agg_gemm<64,32> reverted to 2 sub-groups/node (R10's 4-sub A/B:
// 51.2->55.4us, VALUBusy 45->65% — gather service saturated at ~3.3TB/s, more
// MLP only adds VALU cost). agg<32,16> and head keep 4-sub (smaller, more
// L2-resident tables; 4-sub helped there). SUBS is now a template param.
// Gather tables bf16, accumulation fp32; fp8 closed by error analysis.
// ---------------------------------------------------------------------------

#define NBUCK 391    // ceil(100000 / 256)
#define BSHIFT 8     // 256 nodes per bucket
#define CAP 10240    // per-bucket capacity; padded mean ~9.1K, +12 sigma
#define TILE 4096    // edges per partition block

typedef __attribute__((ext_vector_type(2))) unsigned short ushort2v;
typedef __attribute__((ext_vector_type(4))) unsigned short ushort4v;
typedef __attribute__((ext_vector_type(8))) unsigned short ushort8v;
typedef __attribute__((ext_vector_type(8))) _Float16 half8;
typedef __attribute__((ext_vector_type(4))) float f32x4;

__device__ __forceinline__ float bf2f(unsigned short u) {
  union { unsigned int i; float f; } v;
  v.i = ((unsigned int)u) << 16;
  return v.f;
}
__device__ __forceinline__ unsigned short f2bf(float f) {
  union { float f; unsigned int i; } v;
  v.f = f;
  unsigned int r = v.i + 0x7FFF + ((v.i >> 16) & 1);  // RNE
  return (unsigned short)(r >> 16);
}

// In-LDS counting sort of a 4096-edge tile by bucket (dst>>8). Edges held in
// REGISTERS between histogram and insert (edge list read once). Each thread
// then writes its buckets' contiguous runs to part[] (write-combined).
// packed value = ((dst&255)<<17) | src   (src < 2^17).
static __global__ __launch_bounds__(256) void partition_kernel(
    const int* __restrict__ src, const int* __restrict__ dst,
    int* __restrict__ bucket_cnt, int* __restrict__ part, int E) {
  __shared__ int sorted[TILE];     // 16 KB
  __shared__ int hist[512];
  __shared__ int lstart[512];
  __shared__ int cur[512];
  __shared__ int gbase[512];
  __shared__ int sdata[256];
  const int t = threadIdx.x;
  const int base0 = blockIdx.x * TILE;
  hist[t] = 0;
  hist[t + 256] = 0;
  __syncthreads();
  int4 sv[4], dv[4];
#pragma unroll
  for (int j = 0; j < 4; ++j) {
    int gi = base0 + t * 4 + j * 1024;
    if (gi + 4 <= E) {
      sv[j] = *(const int4*)&src[gi];
      dv[j] = *(const int4*)&dst[gi];
    } else {
      sv[j].x = (gi + 0 < E) ? src[gi + 0] : -1;
      sv[j].y = (gi + 1 < E) ? src[gi + 1] : -1;
      sv[j].z = (gi + 2 < E) ? src[gi + 2] : -1;
      sv[j].w = (gi + 3 < E) ? src[gi + 3] : -1;
      dv[j].x = (gi + 0 < E) ? dst[gi + 0] : 0;
      dv[j].y = (gi + 1 < E) ? dst[gi + 1] : 0;
      dv[j].z = (gi + 2 < E) ? dst[gi + 2] : 0;
      dv[j].w = (gi + 3 < E) ? dst[gi + 3] : 0;
    }
    if (sv[j].x >= 0) atomicAdd(&hist[dv[j].x >> BSHIFT], 1);
    if (sv[j].y >= 0) atomicAdd(&hist[dv[j].y >> BSHIFT], 1);
    if (sv[j].z >= 0) atomicAdd(&hist[dv[j].z >> BSHIFT], 1);
    if (sv[j].w >= 0) atomicAdd(&hist[dv[j].w >> BSHIFT], 1);
  }
  __syncthreads();
  const int v0 = hist[2 * t], v1 = hist[2 * t + 1];
  const int s = v0 + v1;
  sdata[t] = s;
  __syncthreads();
  int incl = s;
  for (int off = 1; off < 256; off <<= 1) {
    int y = (t >= off) ? sdata[t - off] : 0;
    __syncthreads();
    incl += y;
    sdata[t] = incl;
    __syncthreads();
  }
  const int excl = incl - s;
  lstart[2 * t] = excl;
  lstart[2 * t + 1] = excl + v0;
  cur[2 * t] = 0;
  cur[2 * t + 1] = 0;
  if (2 * t < NBUCK && v0) gbase[2 * t] = atomicAdd(&bucket_cnt[2 * t], v0);
  if (2 * t + 1 < NBUCK && v1)
    gbase[2 * t + 1] = atomicAdd(&bucket_cnt[2 * t + 1], v1);
  __syncthreads();
#pragma unroll
  for (int j = 0; j < 4; ++j) {
    if (sv[j].x >= 0) {
      int b = dv[j].x >> BSHIFT;
      sorted[lstart[b] + atomicAdd(&cur[b], 1)] = ((dv[j].x & 255) << 17) | sv[j].x;
    }
    if (sv[j].y >= 0) {
      int b = dv[j].y >> BSHIFT;
      sorted[lstart[b] + atomicAdd(&cur[b], 1)] = ((dv[j].y & 255) << 17) | sv[j].y;
    }
    if (sv[j].z >= 0) {
      int b = dv[j].z >> BSHIFT;
      sorted[lstart[b] + atomicAdd(&cur[b], 1)] = ((dv[j].z & 255) << 17) | sv[j].z;
    }
    if (sv[j].w >= 0) {
      int b = dv[j].w >> BSHIFT;
      sorted[lstart[b] + atomicAdd(&cur[b], 1)] = ((dv[j].w & 255) << 17) | sv[j].w;
    }
  }
  __syncthreads();
  for (int b = t; b < NBUCK; b += 256) {
    int h = hist[b];
    if (!h) continue;
    int gb = gbase[b];
    int lim = CAP - gb;
    if (lim > h) lim = h;
    const int ls = lstart[b];
    int* dstp = &part[(size_t)b * CAP + gb];
    for (int k = 0; k < lim; ++k) dstp[k] = sorted[ls + k];
  }
}

// One block per bucket. hist -> padded scan -> row_start/row_end/dinv ->
// insert into LDS sorted[] (+sentinel pads) -> coalesced int4 copy out.
static __global__ __launch_bounds__(256) void bucket2csr_kernel(
    const int* __restrict__ bucket_cnt, const int* __restrict__ part,
    int* __restrict__ csr_src, int* __restrict__ row_start,
    int* __restrict__ row_end, float* __restrict__ dinv, int n) {
  __shared__ int sorted[CAP];  // 40 KB
  __shared__ int hist[256];
  __shared__ int cursor[256];
  __shared__ int sdata[256];
  const int b = blockIdx.x;
  const int t = threadIdx.x;
  const int base = b * CAP;
  int cnt = bucket_cnt[b];
  if (cnt > CAP) cnt = CAP;
  hist[t] = 0;
  __syncthreads();
  int i = t * 4;
  for (; i + 4 <= cnt; i += 1024) {
    int4 v = *(const int4*)&part[base + i];
    atomicAdd(&hist[v.x >> 17], 1);
    atomicAdd(&hist[v.y >> 17], 1);
    atomicAdd(&hist[v.z >> 17], 1);
    atomicAdd(&hist[v.w >> 17], 1);
  }
  for (int k = i; k < cnt && k < i + 4; ++k)
    atomicAdd(&hist[part[base + k] >> 17], 1);
  __syncthreads();
  const int v = hist[t];
  const int pd = (v + 7) & ~7;  // padded length
  sdata[t] = pd;
  __syncthreads();
  int incl = pd;
  for (int off = 1; off < 256; off <<= 1) {
    int y = (t >= off) ? sdata[t - off] : 0;
    __syncthreads();
    incl += y;
    sdata[t] = incl;
    __syncthreads();
  }
  const int excl = incl - pd;
  const int ptot = sdata[255];  // padded total (multiple of 8)
  cursor[t] = excl;
  const int node = b * 256 + t;
  if (node < n) {
    row_start[node] = base + excl;
    row_end[node] = base + excl + pd;
    dinv[node] = rsqrtf((float)(v + 1));  // true degree +1 self loop
  }
  __syncthreads();
  i = t * 4;
  for (; i + 4 <= cnt; i += 1024) {
    int4 pv = *(const int4*)&part[base + i];
    int p0 = atomicAdd(&cursor[pv.x >> 17], 1);
    sorted[p0] = pv.x & 0x1FFFF;
    int p1 = atomicAdd(&cursor[pv.y >> 17], 1);
    sorted[p1] = pv.y & 0x1FFFF;
    int p2 = atomicAdd(&cursor[pv.z >> 17], 1);
    sorted[p2] = pv.z & 0x1FFFF;
    int p3 = atomicAdd(&cursor[pv.w >> 17], 1);
    sorted[p3] = pv.w & 0x1FFFF;
  }
  for (int k = i; k < cnt && k < i + 4; ++k) {
    int pv = part[base + k];
    int pos = atomicAdd(&cursor[pv >> 17], 1);
    sorted[pos] = pv & 0x1FFFF;
  }
  for (int k = v; k < pd; ++k) sorted[excl + k] = n;
  __syncthreads();
  for (int j = t * 4; j + 4 <= ptot; j += 1024)
    *(int4*)&csr_src[base + j] = *(const int4*)&sorted[j];
}

// Layer-1 GEMM via fp16 MFMA: xws1(bf16) = dinv .* (x @ w1), fp32 accum.
// Block = 64 nodes x 64 outs, 4 waves. LDS XOR-swizzled: byte ^= (row&7)<<4.
// Block 0 also zeroes the sentinel row n of xws1.
static __global__ __launch_bounds__(256) void gemm1_mfma_kernel(
    const float* __restrict__ x, const float* __restrict__ w1,
    const float* __restrict__ dinv, unsigned short* __restrict__ xws, int n) {
  __shared__ _Float16 xa[64 * 128];  // x tile [node][k]
  __shared__ _Float16 wt[64 * 128];  // w1^T   [o][k]
  const int t = threadIdx.x;
  const int base = blockIdx.x * 64;
  if (blockIdx.x == 0 && t < 8) {
    ushort8v z = {0, 0, 0, 0, 0, 0, 0, 0};
    *(ushort8v*)&xws[(size_t)n * 64 + t * 8] = z;
  }
  for (int i = t; i < 64 * 16; i += 256) {
    int r = i >> 4, k8 = i & 15;
    int node = base + r;
    float4 a = {0.f, 0.f, 0.f, 0.f}, b = {0.f, 0.f, 0.f, 0.f};
    if (node < n) {
      a = *(const float4*)&x[(size_t)node * 128 + k8 * 8];
      b = *(const float4*)&x[(size_t)node * 128 + k8 * 8 + 4];
    }
    half8 h = {(_Float16)a.x, (_Float16)a.y, (_Float16)a.z, (_Float16)a.w,
               (_Float16)b.x, (_Float16)b.y, (_Float16)b.z, (_Float16)b.w};
    int byte = (r * 256 + k8 * 16) ^ ((r & 7) << 4);
    *(half8*)((char*)xa + byte) = h;
  }
  for (int i = t; i < 128 * 64; i += 256) {
    int k = i >> 6, o = i & 63;
    _Float16 v = (_Float16)w1[i];
    int byte = (o * 256 + k * 2) ^ ((o & 7) << 4);
    *(_Float16*)((char*)wt + byte) = v;
  }
  __syncthreads();
  const int wv = t >> 6;
  const int lane = t & 63;
  const int m = lane & 15;
  const int kg = lane >> 4;
  const int arow = wv * 16 + m;
  f32x4 acc[4] = {{0.f, 0.f, 0.f, 0.f}, {0.f, 0.f, 0.f, 0.f},
                  {0.f, 0.f, 0.f, 0.f}, {0.f, 0.f, 0.f, 0.f}};
#pragma unroll
  for (int ks = 0; ks < 4; ++ks) {
    int k0 = ks * 32 + kg * 8;
    int abyte = (arow * 256 + k0 * 2) ^ ((arow & 7) << 4);
    half8 af = *(const half8*)((const char*)xa + abyte);
#pragma unroll
    for (int nt = 0; nt < 4; ++nt) {
      int o = nt * 16 + m;
      int bbyte = (o * 256 + k0 * 2) ^ ((o & 7) << 4);
      half8 bf = *(const half8*)((const char*)wt + bbyte);
      acc[nt] = __builtin_amdgcn_mfma_f32_16x16x32_f16(af, bf, acc[nt], 0, 0, 0);
    }
  }
#pragma unroll
  for (int r = 0; r < 4; ++r) {
    int node = base + wv * 16 + kg * 4 + r;
    if (node < n) {
      float dv = dinv[node];
#pragma unroll
      for (int nt = 0; nt < 4; ++nt)
        xws[(size_t)node * 64 + nt * 16 + m] = f2bf(dv * acc[nt][r]);
    }
  }
}

// Fused: h = relu(dinv*(gather-sum + self) + bias); xws_next = bf16(dinv*(h@W)).
// SUBS sub-groups per node (LPN = GC*SUBS lanes) on alternating 8-edge
// chunks; combine via log2(SUBS)-level shfl_xor. Segments padded to mult-8.
// Block 0 zeroes the sentinel row n of xws_next.
template <int F, int FOUT, int SUBS>
static __global__ __launch_bounds__(256) void agg_gemm_kernel(
    const unsigned short* __restrict__ xws, const int* __restrict__ row_start,
    const int* __restrict__ row_end, const int* __restrict__ csr_src,
    const float* __restrict__ dinv, const float* __restrict__ bias,
    const float* __restrict__ W, unsigned short* __restrict__ xws_next, int n) {
  constexpr int GC = F / 8;          // feat-lanes per sub-group
  constexpr int LPN = GC * SUBS;     // lanes per node
  constexpr int NODES = 256 / LPN;
  constexpr int OUTS = FOUT / LPN;   // epilogue outputs per thread
  __shared__ float ws[F * FOUT];
  __shared__ float hs[NODES][F + 1];
  const int t = threadIdx.x;
  if (blockIdx.x == 0 && t < FOUT / 8) {
    ushort8v z = {0, 0, 0, 0, 0, 0, 0, 0};
    *(ushort8v*)&xws_next[(size_t)n * FOUT + t * 8] = z;
  }
  for (int i = t; i < F * FOUT / 4; i += 256)
    *(float4*)&ws[i * 4] = *(const float4*)&W[i * 4];
  const int nl = t / LPN;
  const int l = t % LPN;
  const int c = l % GC;
  const int sub = l / GC;
  const int node = blockIdx.x * NODES + nl;
  const bool valid = node < n;
  const int safe = valid ? node : 0;
  const int start = valid ? row_start[safe] : 0;
  const int end = valid ? row_end[safe] : 0;
  float acc[8] = {0.f, 0.f, 0.f, 0.f, 0.f, 0.f, 0.f, 0.f};
  for (int e = start + sub * 8; e < end; e += SUBS * 8) {
    int4 sa = *(const int4*)&csr_src[e];
    int4 sb = *(const int4*)&csr_src[e + 4];
    ushort8v v0 = *(const ushort8v*)&xws[(size_t)sa.x * F + c * 8];
    ushort8v v1 = *(const ushort8v*)&xws[(size_t)sa.y * F + c * 8];
    ushort8v v2 = *(const ushort8v*)&xws[(size_t)sa.z * F + c * 8];
    ushort8v v3 = *(const ushort8v*)&xws[(size_t)sa.w * F + c * 8];
    ushort8v v4 = *(const ushort8v*)&xws[(size_t)sb.x * F + c * 8];
    ushort8v v5 = *(const ushort8v*)&xws[(size_t)sb.y * F + c * 8];
    ushort8v v6 = *(const ushort8v*)&xws[(size_t)sb.z * F + c * 8];
    ushort8v v7 = *(const ushort8v*)&xws[(size_t)sb.w * F + c * 8];
#pragma unroll
    for (int j = 0; j < 8; ++j)
      acc[j] += ((bf2f(v0[j]) + bf2f(v1[j])) + (bf2f(v2[j]) + bf2f(v3[j]))) +
                ((bf2f(v4[j]) + bf2f(v5[j])) + (bf2f(v6[j]) + bf2f(v7[j])));
  }
  // combine sub-groups: xor GC, 2GC, ... within the node's LPN lanes
#pragma unroll
  for (int m = GC; m < LPN; m <<= 1)
#pragma unroll
    for (int j = 0; j < 8; ++j) acc[j] += __shfl_xor(acc[j], m);
  const float dv = dinv[safe];
  if (sub == 0) {
    ushort8v svv = *(const ushort8v*)&xws[(size_t)safe * F + c * 8];
#pragma unroll
    for (int j = 0; j < 8; ++j)
      hs[nl][c * 8 + j] =
          fmaxf(dv * (acc[j] + bf2f(svv[j])) + bias[c * 8 + j], 0.f);
  }
  __syncthreads();
  // epilogue GEMM: LPN lanes x OUTS outputs per node
  float o[OUTS];
#pragma unroll
  for (int j = 0; j < OUTS; ++j) o[j] = 0.f;
#pragma unroll 4
  for (int k = 0; k < F; ++k) {
    float hv = hs[nl][k];
#pragma unroll
    for (int j = 0; j < OUTS; ++j) o[j] += hv * ws[k * FOUT + l * OUTS + j];
  }
  if (valid) {
    if constexpr (OUTS == 2) {
      ushort2v r = {f2bf(dv * o[0]), f2bf(dv * o[1])};
      *(ushort2v*)&xws_next[(size_t)node * FOUT + l * 2] = r;
    } else {
      xws_next[(size_t)node * FOUT + l] = f2bf(dv * o[0]);
    }
  }
}

// Final layer: h = relu(dinv*(gather+self)+b3); out[n] = h . w_out + b_out.
// 8 lanes/node = 4 subs x 2 feat-lanes; chunk-interleaved.
static __global__ __launch_bounds__(256) void agg_head_kernel(
    const unsigned short* __restrict__ xws, const int* __restrict__ row_start,
    const int* __restrict__ row_end, const int* __restrict__ csr_src,
    const float* __restrict__ dinv, const float* __restrict__ bias,
    float* __restrict__ out, const float* __restrict__ w_out,
    const float* __restrict__ b_out, int n) {
  constexpr int F = 16, NODES = 32;
  const int t = threadIdx.x;
  const int nl = t >> 3;
  const int l = t & 7;
  const int c = l & 1;
  const int sub = l >> 1;
  const int node = blockIdx.x * NODES + nl;
  if (node >= n) return;
  const int start = row_start[node], end = row_end[node];
  float acc[8] = {0.f, 0.f, 0.f, 0.f, 0.f, 0.f, 0.f, 0.f};
  for (int e = start + sub * 8; e < end; e += 32) {
    int4 sa = *(const int4*)&csr_src[e];
    int4 sb = *(const int4*)&csr_src[e + 4];
    ushort8v v0 = *(const ushort8v*)&xws[(size_t)sa.x * F + c * 8];
    ushort8v v1 = *(const ushort8v*)&xws[(size_t)sa.y * F + c * 8];
    ushort8v v2 = *(const ushort8v*)&xws[(size_t)sa.z * F + c * 8];
    ushort8v v3 = *(const ushort8v*)&xws[(size_t)sa.w * F + c * 8];
    ushort8v v4 = *(const ushort8v*)&xws[(size_t)sb.x * F + c * 8];
    ushort8v v5 = *(const ushort8v*)&xws[(size_t)sb.y * F + c * 8];
    ushort8v v6 = *(const ushort8v*)&xws[(size_t)sb.z * F + c * 8];
    ushort8v v7 = *(const ushort8v*)&xws[(size_t)sb.w * F + c * 8];
#pragma unroll
    for (int j = 0; j < 8; ++j)
      acc[j] += ((bf2f(v0[j]) + bf2f(v1[j])) + (bf2f(v2[j]) + bf2f(v3[j]))) +
                ((bf2f(v4[j]) + bf2f(v5[j])) + (bf2f(v6[j]) + bf2f(v7[j])));
  }
#pragma unroll
  for (int j = 0; j < 8; ++j) {
    acc[j] += __shfl_xor(acc[j], 2);
    acc[j] += __shfl_xor(acc[j], 4);
  }
  ushort8v sv = *(const ushort8v*)&xws[(size_t)node * F + c * 8];
  float dv = dinv[node];
  float p = 0.f;
#pragma unroll
  for (int j = 0; j < 8; ++j) {
    float r = fmaxf(dv * (acc[j] + bf2f(sv[j])) + bias[c * 8 + j], 0.f);
    p += r * w_out[c * 8 + j];
  }
  p += __shfl_xor(p, 1);  // combine the two feat-lanes
  if (l == 0) out[node] = p + b_out[0];
}

extern "C" void kernel_launch(void* const* d_in, const int* in_sizes, int n_in,
                              void* d_out, int out_size, void* d_ws, size_t ws_size,
                              hipStream_t stream) {
  const float* x     = (const float*)d_in[0];
  const int*   ei    = (const int*)d_in[1];
  const float* w1    = (const float*)d_in[2];
  const float* b1    = (const float*)d_in[3];
  const float* w2    = (const float*)d_in[4];
  const float* b2    = (const float*)d_in[5];
  const float* w3    = (const float*)d_in[6];
  const float* b3    = (const float*)d_in[7];
  const float* w_out = (const float*)d_in[8];
  const float* b_out = (const float*)d_in[9];
  float* out = (float*)d_out;

  const int n = in_sizes[0] / 128;   // 100000
  const int E = in_sizes[1] / 2;     // 3200000
  const int* srcA = ei;
  const int* dstA = ei + E;

  char* p = (char*)d_ws;
  auto carve = [&](size_t bytes) {
    void* r = (void*)p;
    p += (bytes + 255) & ~(size_t)255;
    return r;
  };
  const size_t partBytes = (size_t)NBUCK * CAP * 4;  // 16.0 MB
  int*   csr_src    = (int*)carve(partBytes);
  int*   bucket_cnt = (int*)carve((size_t)NBUCK * 4);
  int*   row_start  = (int*)carve((size_t)n * 4);
  int*   row_end    = (int*)carve((size_t)n * 4);
  float* dinv       = (float*)carve((size_t)n * 4);
  // part (dead after bucket2csr) aliases xws1 ((n+1)*64*2 = 12.8MB < 16MB)
  char*  regionP    = (char*)carve(partBytes);
  int*   part       = (int*)regionP;
  unsigned short* xws1 = (unsigned short*)regionP;
  unsigned short* xws2 = (unsigned short*)carve((size_t)(n + 1) * 32 * 2);
  unsigned short* xws3 = (unsigned short*)carve((size_t)(n + 1) * 16 * 2);

  hipMemsetAsync(bucket_cnt, 0, (size_t)NBUCK * 4, stream);
  partition_kernel<<<(E + TILE - 1) / TILE, 256, 0, stream>>>(srcA, dstA,
                                                              bucket_cnt, part, E);
  bucket2csr_kernel<<<NBUCK, 256, 0, stream>>>(bucket_cnt, part, csr_src,
                                               row_start, row_end, dinv, n);

  // layer 1 GEMM (fp16 MFMA): xws1 = dinv .* (x @ w1)   [128 -> 64]
  gemm1_mfma_kernel<<<(n + 63) / 64, 256, 0, stream>>>(x, w1, dinv, xws1, n);
  // layer 1 agg + layer 2 GEMM fused: h1 -> xws2   [agg 64, 2-sub]
  agg_gemm_kernel<64, 32, 2><<<(n + 15) / 16, 256, 0, stream>>>(
      xws1, row_start, row_end, csr_src, dinv, b1, w2, xws2, n);
  // layer 2 agg + layer 3 GEMM fused: h2 -> xws3   [agg 32, 4-sub]
  agg_gemm_kernel<32, 16, 4><<<(n + 15) / 16, 256, 0, stream>>>(
      xws2, row_start, row_end, csr_src, dinv, b2, w3, xws3, n);
  // layer 3 agg + head fused   [4-sub]
  agg_head_kernel<<<(n + 31) / 32, 256, 0, stream>>>(
      xws3, row_start, row_end, csr_src, dinv, b3, out, w_out, b_out, n);
}